// Round 3
// baseline (1089.454 us; speedup 1.0000x reference)
//
#include <hip/hip_runtime.h>
#include <cstddef>

#define HW 192
#define NP 36864          // H*W
#define CH 256
#define EDGES 294912
#define KSIG 289
#define SLOPE 0.01f
#define BNEPS 1e-5f

typedef unsigned short u16;
typedef __attribute__((ext_vector_type(8))) short bf16x8;
typedef __attribute__((ext_vector_type(4))) float f32x4;

__device__ __forceinline__ float leaky(float x) { return x >= 0.f ? x : SLOPE * x; }
__device__ __forceinline__ u16 f2bf(float x) {
  unsigned u = __float_as_uint(x);
  unsigned r = (u + 0x7fffu + ((u >> 16) & 1u)) >> 16;
  return (u16)r;
}
__device__ __forceinline__ float bf2f(unsigned h) { return __uint_as_float(h << 16); }
// inline BN scale/shift from raw sums
__device__ __forceinline__ void bnss(const float* sums, const float* sqs,
                                     const float* g, const float* b, int k,
                                     float& s, float& h) {
  float mean = sums[k] * (1.f / NP);
  float var = sqs[k] * (1.f / NP) - mean * mean;
  s = g[k] * rsqrtf(var + BNEPS);
  h = b[k] - mean * s;
}

// ---------------- generic 32x32 tiled transpose: src (R x S) -> dst (S x R) ----
__global__ __launch_bounds__(256) void k_transpose(const float* __restrict__ src,
                                                   float* __restrict__ dst, int R, int S) {
  __shared__ float tile[32][33];
  int s0 = blockIdx.x * 32, r0 = blockIdx.y * 32;
  int tx = threadIdx.x & 31, ty = threadIdx.x >> 5;
#pragma unroll
  for (int j = 0; j < 4; j++) {
    int r = r0 + ty + 8 * j;
    tile[ty + 8 * j][tx] = src[(size_t)r * S + s0 + tx];
  }
  __syncthreads();
#pragma unroll
  for (int j = 0; j < 4; j++) {
    int s = s0 + ty + 8 * j;
    dst[(size_t)s * R + r0 + tx] = tile[tx][ty + 8 * j];
  }
}

// ---------------- weight fp32 -> bf16 converter (dw2 zero-padded to 384 rows) --
__global__ __launch_bounds__(256) void k_cvtW(const float* __restrict__ pw1,
                                              const float* __restrict__ f1w0,
                                              const float* __restrict__ f1w1,
                                              const float* __restrict__ dw1,
                                              const float* __restrict__ dw2,
                                              const float* __restrict__ f2w1,
                                              u16* __restrict__ out) {
  int i = blockIdx.x * 256 + threadIdx.x;   // 0..622591
  float v;
  if (i < 65536) v = pw1[i];
  else if (i < 131072) v = f1w0[i - 65536];
  else if (i < 196608) v = f1w1[i - 131072];
  else if (i < 262144) v = dw1[i - 196608];
  else if (i < 360448) { int j = i - 262144; v = (j < KSIG * 256) ? dw2[j] : 0.f; }
  else v = f2w1[i - 360448];
  out[i] = f2bf(v);
}

// ---- fp32 (M x NP) -> bf16 transposed (NP x M), mode 0: identity --------------
__global__ __launch_bounds__(256) void k_cvtT(const float* __restrict__ in,
                                              u16* __restrict__ outT, int M) {
  __shared__ float tile[32][65];
  int n0 = blockIdx.x * 64, k0 = blockIdx.y * 32;
  int t = threadIdx.x;
#pragma unroll
  for (int i = 0; i < 2; i++) {
    int ci = i * 256 + t;
    int k = ci >> 4, cg = (ci & 15) * 4;
    float4 v = *(const float4*)&in[(size_t)(k0 + k) * NP + n0 + cg];
    tile[k][cg] = v.x; tile[k][cg + 1] = v.y; tile[k][cg + 2] = v.z; tile[k][cg + 3] = v.w;
  }
  __syncthreads();
  int n = t >> 2, kg = (t & 3) * 8;
  uint4 o;
  o.x = (unsigned)f2bf(tile[kg + 0][n]) | ((unsigned)f2bf(tile[kg + 1][n]) << 16);
  o.y = (unsigned)f2bf(tile[kg + 2][n]) | ((unsigned)f2bf(tile[kg + 3][n]) << 16);
  o.z = (unsigned)f2bf(tile[kg + 4][n]) | ((unsigned)f2bf(tile[kg + 5][n]) << 16);
  o.w = (unsigned)f2bf(tile[kg + 6][n]) | ((unsigned)f2bf(tile[kg + 7][n]) << 16);
  *(uint4*)&outT[(size_t)(n0 + n) * M + k0 + kg] = o;
}

// ---- fp32 (M x NP) -> bf16 transposed, f = leaky(bn(x)) with inline stats -----
__global__ __launch_bounds__(256) void k_cvtTs(const float* __restrict__ in,
                                               u16* __restrict__ outT,
                                               const float* __restrict__ sums,
                                               const float* __restrict__ sqs,
                                               const float* __restrict__ g,
                                               const float* __restrict__ b, int M) {
  __shared__ float tile[32][65];
  int n0 = blockIdx.x * 64, k0 = blockIdx.y * 32;
  int t = threadIdx.x;
#pragma unroll
  for (int i = 0; i < 2; i++) {
    int ci = i * 256 + t;
    int k = ci >> 4, cg = (ci & 15) * 4;
    float s, h; bnss(sums, sqs, g, b, k0 + k, s, h);
    float4 v = *(const float4*)&in[(size_t)(k0 + k) * NP + n0 + cg];
    tile[k][cg]     = leaky(fmaf(v.x, s, h));
    tile[k][cg + 1] = leaky(fmaf(v.y, s, h));
    tile[k][cg + 2] = leaky(fmaf(v.z, s, h));
    tile[k][cg + 3] = leaky(fmaf(v.w, s, h));
  }
  __syncthreads();
  int n = t >> 2, kg = (t & 3) * 8;
  uint4 o;
  o.x = (unsigned)f2bf(tile[kg + 0][n]) | ((unsigned)f2bf(tile[kg + 1][n]) << 16);
  o.y = (unsigned)f2bf(tile[kg + 2][n]) | ((unsigned)f2bf(tile[kg + 3][n]) << 16);
  o.z = (unsigned)f2bf(tile[kg + 4][n]) | ((unsigned)f2bf(tile[kg + 5][n]) << 16);
  o.w = (unsigned)f2bf(tile[kg + 6][n]) | ((unsigned)f2bf(tile[kg + 7][n]) << 16);
  *(uint4*)&outT[(size_t)(n0 + n) * M + k0 + kg] = o;
}

// ---- bf16 (1024 x NP) -> bf16 transposed (NP x 1024), leaky(bn(x)) inline -----
__global__ __launch_bounds__(256) void k_cvtT_bf(const u16* __restrict__ in,
                                                 u16* __restrict__ outT,
                                                 const float* __restrict__ sums,
                                                 const float* __restrict__ sqs,
                                                 const float* __restrict__ g,
                                                 const float* __restrict__ b, int M) {
  __shared__ float tile[32][65];
  int n0 = blockIdx.x * 64, k0 = blockIdx.y * 32;
  int t = threadIdx.x;
  int k = t >> 3, cg = (t & 7) * 8;
  float s, h; bnss(sums, sqs, g, b, k0 + k, s, h);
  uint4 v = *(const uint4*)&in[(size_t)(k0 + k) * NP + n0 + cg];
  unsigned w[4] = {v.x, v.y, v.z, v.w};
#pragma unroll
  for (int j = 0; j < 4; j++) {
    tile[k][cg + 2 * j]     = leaky(fmaf(bf2f(w[j] & 0xffffu), s, h));
    tile[k][cg + 2 * j + 1] = leaky(fmaf(bf2f(w[j] >> 16), s, h));
  }
  __syncthreads();
  int n = t >> 2, kg = (t & 3) * 8;
  uint4 o;
  o.x = (unsigned)f2bf(tile[kg + 0][n]) | ((unsigned)f2bf(tile[kg + 1][n]) << 16);
  o.y = (unsigned)f2bf(tile[kg + 2][n]) | ((unsigned)f2bf(tile[kg + 3][n]) << 16);
  o.z = (unsigned)f2bf(tile[kg + 4][n]) | ((unsigned)f2bf(tile[kg + 5][n]) << 16);
  o.w = (unsigned)f2bf(tile[kg + 6][n]) | ((unsigned)f2bf(tile[kg + 7][n]) << 16);
  *(uint4*)&outT[(size_t)(n0 + n) * M + k0 + kg] = o;
}

// ---- fuse1: img2 = img + bn(raw1); write img2 fp32 (CxN) + leaky(img2) bf16 T --
__global__ __launch_bounds__(256) void k_fuse1(const float* __restrict__ base,
                                               const float* __restrict__ raw,
                                               const float* __restrict__ sums,
                                               const float* __restrict__ sqs,
                                               const float* __restrict__ g,
                                               const float* __restrict__ b,
                                               float* __restrict__ img2,
                                               u16* __restrict__ outT) {
  __shared__ float tile[32][65];
  int n0 = blockIdx.x * 64, k0 = blockIdx.y * 32;
  int t = threadIdx.x;
#pragma unroll
  for (int i = 0; i < 2; i++) {
    int ci = i * 256 + t;
    int k = ci >> 4, cg = (ci & 15) * 4;
    float s, h; bnss(sums, sqs, g, b, k0 + k, s, h);
    size_t idx = (size_t)(k0 + k) * NP + n0 + cg;
    float4 bv = *(const float4*)&base[idx];
    float4 rv = *(const float4*)&raw[idx];
    float4 o;
    o.x = bv.x + fmaf(rv.x, s, h); o.y = bv.y + fmaf(rv.y, s, h);
    o.z = bv.z + fmaf(rv.z, s, h); o.w = bv.w + fmaf(rv.w, s, h);
    *(float4*)&img2[idx] = o;
    tile[k][cg]     = leaky(o.x);
    tile[k][cg + 1] = leaky(o.y);
    tile[k][cg + 2] = leaky(o.z);
    tile[k][cg + 3] = leaky(o.w);
  }
  __syncthreads();
  int n = t >> 2, kg = (t & 3) * 8;
  uint4 o;
  o.x = (unsigned)f2bf(tile[kg + 0][n]) | ((unsigned)f2bf(tile[kg + 1][n]) << 16);
  o.y = (unsigned)f2bf(tile[kg + 2][n]) | ((unsigned)f2bf(tile[kg + 3][n]) << 16);
  o.z = (unsigned)f2bf(tile[kg + 4][n]) | ((unsigned)f2bf(tile[kg + 5][n]) << 16);
  o.w = (unsigned)f2bf(tile[kg + 6][n]) | ((unsigned)f2bf(tile[kg + 7][n]) << 16);
  *(uint4*)&outT[(size_t)(n0 + n) * CH + k0 + kg] = o;
}

// ---- fuse2: Xn = img2 + bn(raw3); write Xn fp32 (NxC) + Xn bf16 (NxC) ---------
__global__ __launch_bounds__(256) void k_fuse2(const float* __restrict__ base,
                                               const float* __restrict__ raw,
                                               const float* __restrict__ sums,
                                               const float* __restrict__ sqs,
                                               const float* __restrict__ g,
                                               const float* __restrict__ b,
                                               float* __restrict__ XnT,
                                               u16* __restrict__ outT) {
  __shared__ float tile[32][65];
  int n0 = blockIdx.x * 64, k0 = blockIdx.y * 32;
  int t = threadIdx.x;
#pragma unroll
  for (int i = 0; i < 2; i++) {
    int ci = i * 256 + t;
    int k = ci >> 4, cg = (ci & 15) * 4;
    float s, h; bnss(sums, sqs, g, b, k0 + k, s, h);
    size_t idx = (size_t)(k0 + k) * NP + n0 + cg;
    float4 bv = *(const float4*)&base[idx];
    float4 rv = *(const float4*)&raw[idx];
    tile[k][cg]     = bv.x + fmaf(rv.x, s, h);
    tile[k][cg + 1] = bv.y + fmaf(rv.y, s, h);
    tile[k][cg + 2] = bv.z + fmaf(rv.z, s, h);
    tile[k][cg + 3] = bv.w + fmaf(rv.w, s, h);
  }
  __syncthreads();
  int n = t >> 2, kg = (t & 3) * 8;
  float4 f0 = {tile[kg + 0][n], tile[kg + 1][n], tile[kg + 2][n], tile[kg + 3][n]};
  float4 f1 = {tile[kg + 4][n], tile[kg + 5][n], tile[kg + 6][n], tile[kg + 7][n]};
  *(float4*)&XnT[(size_t)(n0 + n) * CH + k0 + kg] = f0;
  *(float4*)&XnT[(size_t)(n0 + n) * CH + k0 + kg + 4] = f1;
  uint4 o;
  o.x = (unsigned)f2bf(f0.x) | ((unsigned)f2bf(f0.y) << 16);
  o.y = (unsigned)f2bf(f0.z) | ((unsigned)f2bf(f0.w) << 16);
  o.z = (unsigned)f2bf(f1.x) | ((unsigned)f2bf(f1.y) << 16);
  o.w = (unsigned)f2bf(f1.z) | ((unsigned)f2bf(f1.w) << 16);
  *(uint4*)&outT[(size_t)(n0 + n) * CH + k0 + kg] = o;
}

// ---------------- MFMA GEMM: Out(Mstore x NP) = A(Mt x K) @ Bt(NP x K)^T -------
// optional fused per-row stats (sum, sumsq) via wave shuffles + atomics
__global__ __launch_bounds__(256) void k_mgemm(const u16* __restrict__ A,
                                               const u16* __restrict__ Bt,
                                               float* __restrict__ Out,
                                               const float* __restrict__ bias,
                                               float* __restrict__ sums,
                                               float* __restrict__ sqs,
                                               int K, int Mstore, int actout) {
  __shared__ u16 As[128 * 32];
  __shared__ u16 Bs[128 * 32];
  int t = threadIdx.x;
  int lane = t & 63, wave = t >> 6;
  int wm = (wave >> 1) * 64, wn = (wave & 1) * 64;
  int m0 = blockIdx.y * 128, n0 = blockIdx.x * 128;
  int r = lane & 15, q = lane >> 4;
  f32x4 acc[4][4];
#pragma unroll
  for (int a = 0; a < 4; a++)
#pragma unroll
    for (int b = 0; b < 4; b++) acc[a][b] = (f32x4){0.f, 0.f, 0.f, 0.f};

  for (int k0 = 0; k0 < K; k0 += 32) {
#pragma unroll
    for (int i = 0; i < 2; i++) {
      int cc = t + i * 256;
      int mm = cc >> 2, kq = (cc & 3) * 8;
      uint4 av = *(const uint4*)&A[(size_t)(m0 + mm) * K + k0 + kq];
      uint4 bv = *(const uint4*)&Bt[(size_t)(n0 + mm) * K + k0 + kq];
      *(uint4*)&As[mm * 32 + kq] = av;
      *(uint4*)&Bs[mm * 32 + kq] = bv;
    }
    __syncthreads();
    bf16x8 af[4], bfr[4];
#pragma unroll
    for (int mt = 0; mt < 4; mt++)
      af[mt] = *(const bf16x8*)&As[(wm + mt * 16 + r) * 32 + q * 8];
#pragma unroll
    for (int nt = 0; nt < 4; nt++)
      bfr[nt] = *(const bf16x8*)&Bs[(wn + nt * 16 + r) * 32 + q * 8];
#pragma unroll
    for (int mt = 0; mt < 4; mt++)
#pragma unroll
      for (int nt = 0; nt < 4; nt++)
        acc[mt][nt] = __builtin_amdgcn_mfma_f32_16x16x32_bf16(af[mt], bfr[nt], acc[mt][nt], 0, 0, 0);
    __syncthreads();
  }
#pragma unroll
  for (int mt = 0; mt < 4; mt++) {
    int mrow = m0 + wm + mt * 16 + q * 4;
#pragma unroll
    for (int i = 0; i < 4; i++) {
      int m = mrow + i;
      if (m >= Mstore) continue;
      float bs = bias ? bias[m] : 0.f;
#pragma unroll
      for (int nt = 0; nt < 4; nt++) {
        float v = acc[mt][nt][i] + bs;
        if (actout) v = leaky(v);
        Out[(size_t)m * NP + n0 + wn + nt * 16 + r] = v;
      }
    }
  }
  if (sums) {
#pragma unroll
    for (int mt = 0; mt < 4; mt++)
#pragma unroll
      for (int i = 0; i < 4; i++) {
        float s = acc[mt][0][i] + acc[mt][1][i] + acc[mt][2][i] + acc[mt][3][i];
        float qv = acc[mt][0][i] * acc[mt][0][i] + acc[mt][1][i] * acc[mt][1][i] +
                   acc[mt][2][i] * acc[mt][2][i] + acc[mt][3][i] * acc[mt][3][i];
#pragma unroll
        for (int d = 1; d < 16; d <<= 1) {
          s += __shfl_xor(s, d, 64);
          qv += __shfl_xor(qv, d, 64);
        }
        if (r == 0) {
          int m = m0 + wm + mt * 16 + q * 4 + i;
          atomicAdd(&sums[m], s);
          atomicAdd(&sqs[m], qv);
        }
      }
  }
}

// ---------------- depthwise 17x17 conv, pad 8, leaky on input, fused stats -----
// 64x64 tile per block, 4x4 outputs per thread, LDS 80x84 padded
__global__ __launch_bounds__(256) void k_dwconv17(const float* __restrict__ in,
                                                  const float* __restrict__ w,
                                                  float* __restrict__ out,
                                                  float* __restrict__ sums,
                                                  float* __restrict__ sqs) {
  int c = blockIdx.y;
  int tile = blockIdx.x;                  // 0..8
  int ty0 = (tile / 3) * 64, tx0 = (tile % 3) * 64;
  __shared__ __align__(16) float sm[80 * 84];
  const float* inc = in + (size_t)c * NP;
  for (int i = threadIdx.x; i < 80 * 80; i += 256) {
    int r = i / 80, cc = i - r * 80;
    int gy = ty0 + r - 8, gx = tx0 + cc - 8;
    float v = 0.f;
    if (gy >= 0 && gy < HW && gx >= 0 && gx < HW) v = leaky(inc[gy * HW + gx]);
    sm[r * 84 + cc] = v;
  }
  __syncthreads();
  int tr = threadIdx.x >> 4, tc = threadIdx.x & 15;
  float acc[4][4];
#pragma unroll
  for (int oy = 0; oy < 4; oy++)
#pragma unroll
    for (int j = 0; j < 4; j++) acc[oy][j] = 0.f;
  const float* wc = w + c * 289;
  for (int iy = 0; iy < 20; iy++) {
    const float* rowp = &sm[(4 * tr + iy) * 84 + 4 * tc];
    float win[20];
#pragma unroll
    for (int i = 0; i < 5; i++) {
      float4 v = *(const float4*)(rowp + 4 * i);
      win[4 * i] = v.x; win[4 * i + 1] = v.y; win[4 * i + 2] = v.z; win[4 * i + 3] = v.w;
    }
    int lo = iy - 16; if (lo < 0) lo = 0;
    int hi = iy; if (hi > 3) hi = 3;
#pragma unroll
    for (int oy = 0; oy < 4; oy++) {
      if (oy < lo || oy > hi) continue;
      const float* wr = wc + (iy - oy) * 17;
#pragma unroll
      for (int kx = 0; kx < 17; kx++) {
        float wv = wr[kx];
        acc[oy][0] = fmaf(wv, win[kx + 0], acc[oy][0]);
        acc[oy][1] = fmaf(wv, win[kx + 1], acc[oy][1]);
        acc[oy][2] = fmaf(wv, win[kx + 2], acc[oy][2]);
        acc[oy][3] = fmaf(wv, win[kx + 3], acc[oy][3]);
      }
    }
  }
  float s = 0.f, qv = 0.f;
#pragma unroll
  for (int oy = 0; oy < 4; oy++) {
    float4 o = {acc[oy][0], acc[oy][1], acc[oy][2], acc[oy][3]};
    *(float4*)(out + (size_t)c * NP + (ty0 + 4 * tr + oy) * HW + tx0 + 4 * tc) = o;
    s += o.x + o.y + o.z + o.w;
    qv += o.x * o.x + o.y * o.y + o.z * o.z + o.w * o.w;
  }
#pragma unroll
  for (int d = 1; d < 64; d <<= 1) {
    s += __shfl_xor(s, d, 64);
    qv += __shfl_xor(qv, d, 64);
  }
  if ((threadIdx.x & 63) == 0) {
    atomicAdd(&sums[c], s);
    atomicAdd(&sqs[c], qv);
  }
}

// ---------------- grouped 3x3 conv -> bf16 output + fused stats ----------------
__global__ __launch_bounds__(256) void k_conv3x4(const float* __restrict__ in,
                                                 const float* __restrict__ w,
                                                 u16* __restrict__ out,
                                                 float* __restrict__ sums,
                                                 float* __restrict__ sqs) {
  int c = blockIdx.y;
  int tile = blockIdx.x;
  int ty0 = (tile / 6) * 32, tx0 = (tile % 6) * 32;
  __shared__ __align__(16) float sm[34 * 36];
  const float* inc = in + (size_t)c * NP;
  for (int i = threadIdx.x; i < 34 * 34; i += 256) {
    int r = i / 34, cc = i - r * 34;
    int gy = ty0 + r - 1, gx = tx0 + cc - 1;
    float v = 0.f;
    if (gy >= 0 && gy < HW && gx >= 0 && gx < HW) v = leaky(inc[gy * HW + gx]);
    sm[r * 36 + cc] = v;
  }
  float wr[4][9];
#pragma unroll
  for (int oc = 0; oc < 4; oc++)
#pragma unroll
    for (int k = 0; k < 9; k++) wr[oc][k] = w[(size_t)(4 * c + oc) * 9 + k];
  __syncthreads();
  int r = threadIdx.x >> 3;
  int c4 = (threadIdx.x & 7) * 4;
  float acc[4][4];
#pragma unroll
  for (int oc = 0; oc < 4; oc++)
#pragma unroll
    for (int j = 0; j < 4; j++) acc[oc][j] = 0.f;
  for (int ky = 0; ky < 3; ky++) {
    int base = (r + ky) * 36 + c4;
    float win[6];
    float4 v4 = *(const float4*)&sm[base];
    win[0] = v4.x; win[1] = v4.y; win[2] = v4.z; win[3] = v4.w;
    win[4] = sm[base + 4]; win[5] = sm[base + 5];
#pragma unroll
    for (int oc = 0; oc < 4; oc++)
#pragma unroll
      for (int kx = 0; kx < 3; kx++) {
        float wv = wr[oc][ky * 3 + kx];
#pragma unroll
        for (int j = 0; j < 4; j++) acc[oc][j] = fmaf(wv, win[kx + j], acc[oc][j]);
      }
  }
#pragma unroll
  for (int oc = 0; oc < 4; oc++) {
    uint2 o;
    o.x = (unsigned)f2bf(acc[oc][0]) | ((unsigned)f2bf(acc[oc][1]) << 16);
    o.y = (unsigned)f2bf(acc[oc][2]) | ((unsigned)f2bf(acc[oc][3]) << 16);
    *(uint2*)(out + (size_t)(4 * c + oc) * NP + (ty0 + r) * HW + tx0 + c4) = o;
    float s = acc[oc][0] + acc[oc][1] + acc[oc][2] + acc[oc][3];
    float qv = acc[oc][0] * acc[oc][0] + acc[oc][1] * acc[oc][1] +
               acc[oc][2] * acc[oc][2] + acc[oc][3] * acc[oc][3];
#pragma unroll
    for (int d = 1; d < 64; d <<= 1) {
      s += __shfl_xor(s, d, 64);
      qv += __shfl_xor(qv, d, 64);
    }
    if ((threadIdx.x & 63) == 0) {
      atomicAdd(&sums[4 * c + oc], s);
      atomicAdd(&sqs[4 * c + oc], qv);
    }
  }
}

// ---------------- edge scores + dst histogram ----------------------------------
__global__ __launch_bounds__(256) void k_edge(const int* __restrict__ info,
                                              const float* __restrict__ msk,
                                              const float* __restrict__ sig,
                                              float* __restrict__ aij,
                                              int* __restrict__ counts) {
  int e = blockIdx.x * 256 + threadIdx.x;
  int4 ii = ((const int4*)info)[e];   // src, k1, dst, k2
  float s = sig[(size_t)ii.y * NP + ii.x] + sig[(size_t)ii.w * NP + ii.z];
  s = fminf(fmaxf(s, -5.f), 5.f);
  aij[e] = expf(s) * msk[e];
  atomicAdd(&counts[ii.z], 1);
}

// ---------------- counting-sort by dst -----------------------------------------
__global__ __launch_bounds__(256) void k_scan1(const int* __restrict__ counts,
                                               int* __restrict__ offsets,
                                               int* __restrict__ bsum) {
  __shared__ int sm[256];
  int t = threadIdx.x;
  int i = blockIdx.x * 256 + t;
  int v = counts[i];
  sm[t] = v;
  __syncthreads();
  for (int d = 1; d < 256; d <<= 1) {
    int add = (t >= d) ? sm[t - d] : 0;
    __syncthreads();
    sm[t] += add;
    __syncthreads();
  }
  offsets[i] = sm[t] - v;
  if (t == 255) bsum[blockIdx.x] = sm[255];
}
__global__ __launch_bounds__(256) void k_scan2(const int* __restrict__ bsum,
                                               int* __restrict__ boff) {
  __shared__ int sm[256];
  int t = threadIdx.x;
  int v = (t < 144) ? bsum[t] : 0;
  sm[t] = v;
  __syncthreads();
  for (int d = 1; d < 256; d <<= 1) {
    int add = (t >= d) ? sm[t - d] : 0;
    __syncthreads();
    sm[t] += add;
    __syncthreads();
  }
  boff[t] = sm[t] - v;
}
__global__ __launch_bounds__(256) void k_scan3(int* __restrict__ offsets,
                                               const int* __restrict__ boff,
                                               int* __restrict__ cursor) {
  int i = blockIdx.x * 256 + threadIdx.x;
  int o = offsets[i] + boff[blockIdx.x];
  offsets[i] = o;
  cursor[i] = o;
  if (i == 0) offsets[NP] = EDGES;
}
__global__ __launch_bounds__(256) void k_scatter(const int* __restrict__ info,
                                                 int* __restrict__ cursor,
                                                 int* __restrict__ sorted) {
  int e = blockIdx.x * 256 + threadIdx.x;
  int d = info[4 * e + 2];
  int pos = atomicAdd(&cursor[d], 1);
  sorted[pos] = e;
}

// ---------------- per-node aggregation (one wave per node, bf16 gather) --------
__global__ __launch_bounds__(256) void k_agg(const int* __restrict__ offsets,
                                             const int* __restrict__ sorted,
                                             const float* __restrict__ aij,
                                             const int* __restrict__ info,
                                             const u16* __restrict__ XnBf,
                                             float* __restrict__ Xtr) {
  int wave = threadIdx.x >> 6, lane = threadIdx.x & 63;
  int node = blockIdx.x * 4 + wave;
  int o0 = offsets[node], o1 = offsets[node + 1];
  float ax = 0.f, ay = 0.f, az = 0.f, aw = 0.f, asum = 0.f;
  for (int i = o0; i < o1; i++) {
    int e = sorted[i];
    float a = aij[e];
    int s = info[4 * e];
    uint2 v = ((const uint2*)(XnBf + (size_t)s * CH))[lane];
    ax = fmaf(a, bf2f(v.x & 0xffffu), ax);
    ay = fmaf(a, bf2f(v.x >> 16), ay);
    az = fmaf(a, bf2f(v.y & 0xffffu), az);
    aw = fmaf(a, bf2f(v.y >> 16), aw);
    asum += a;
  }
  float inv = 1.f / (asum + 1e-5f);
  float4 o = {ax * inv, ay * inv, az * inv, aw * inv};
  ((float4*)(Xtr + (size_t)node * CH))[lane] = o;
}

// ---------------- bn1d stats ----------------------------------------------------
__global__ __launch_bounds__(256) void k_colstats(const float* __restrict__ Xt,
                                                  float* __restrict__ sums,
                                                  float* __restrict__ sqs) {
  int c = threadIdx.x;
  float s = 0.f, q = 0.f;
  for (int n = blockIdx.x; n < NP; n += gridDim.x) {
    float v = Xt[(size_t)n * CH + c];
    s += v; q += v * v;
  }
  atomicAdd(&sums[c], s);
  atomicAdd(&sqs[c], q);
}

// ---------------- img4 = transpose(Xn + bn1d(Xtr))  (N x C -> C x N) -----------
__global__ __launch_bounds__(256) void k_mkimg4(const float* __restrict__ Xn,
                                                const float* __restrict__ Xtr,
                                                const float* __restrict__ sums,
                                                const float* __restrict__ sqs,
                                                const float* __restrict__ g,
                                                const float* __restrict__ b,
                                                float* __restrict__ img4) {
  __shared__ float tile[32][33];
  int c0 = blockIdx.x * 32, n0 = blockIdx.y * 32;
  int tx = threadIdx.x & 31, ty = threadIdx.x >> 5;
  int c = c0 + tx;
  float s, h; bnss(sums, sqs, g, b, c, s, h);
#pragma unroll
  for (int j = 0; j < 4; j++) {
    size_t idx = (size_t)(n0 + ty + 8 * j) * CH + c;
    tile[ty + 8 * j][tx] = Xn[idx] + fmaf(Xtr[idx], s, h);
  }
  __syncthreads();
#pragma unroll
  for (int j = 0; j < 4; j++) {
    int cc = c0 + ty + 8 * j;
    img4[(size_t)cc * NP + n0 + tx] = tile[tx][ty + 8 * j];
  }
}

// ---------------- out(N x C) = transpose(bn(raw5) + img4), inline stats --------
__global__ __launch_bounds__(256) void k_final(const float* __restrict__ raw5,
                                               const float* __restrict__ img4,
                                               const float* __restrict__ sums,
                                               const float* __restrict__ sqs,
                                               const float* __restrict__ g,
                                               const float* __restrict__ b,
                                               float* __restrict__ out) {
  __shared__ float tile[32][33];
  int n0 = blockIdx.x * 32, c0 = blockIdx.y * 32;
  int tx = threadIdx.x & 31, ty = threadIdx.x >> 5;
#pragma unroll
  for (int j = 0; j < 4; j++) {
    int c = c0 + ty + 8 * j;
    float s, h; bnss(sums, sqs, g, b, c, s, h);
    size_t idx = (size_t)c * NP + n0 + tx;
    tile[ty + 8 * j][tx] = fmaf(raw5[idx], s, h) + img4[idx];
  }
  __syncthreads();
#pragma unroll
  for (int j = 0; j < 4; j++) {
    int n = n0 + ty + 8 * j;
    out[(size_t)n * CH + c0 + tx] = tile[tx][ty + 8 * j];
  }
}

extern "C" void kernel_launch(void* const* d_in, const int* in_sizes, int n_in,
                              void* d_out, int out_size, void* d_ws, size_t ws_size,
                              hipStream_t stream) {
  (void)in_sizes; (void)n_in; (void)out_size; (void)ws_size;
  const float* X    = (const float*)d_in[0];
  const int*   info = (const int*)d_in[1];
  const float* msk  = (const float*)d_in[2];
  const float* pw0  = (const float*)d_in[3];
  const float* pg0  = (const float*)d_in[4];
  const float* pb0  = (const float*)d_in[5];
  const float* pw1  = (const float*)d_in[6];
  const float* pg1  = (const float*)d_in[7];
  const float* pb1  = (const float*)d_in[8];
  const float* f1w0 = (const float*)d_in[9];
  const float* f1g0 = (const float*)d_in[10];
  const float* f1b0 = (const float*)d_in[11];
  const float* f1w1 = (const float*)d_in[12];
  const float* f1g1 = (const float*)d_in[13];
  const float* f1b1 = (const float*)d_in[14];
  const float* dw1  = (const float*)d_in[15];
  const float* db1  = (const float*)d_in[16];
  const float* dw2  = (const float*)d_in[17];
  const float* db2  = (const float*)d_in[18];
  const float* bng  = (const float*)d_in[19];
  const float* bnb  = (const float*)d_in[20];
  const float* f2w0 = (const float*)d_in[21];
  const float* f2g0 = (const float*)d_in[22];
  const float* f2b0 = (const float*)d_in[23];
  const float* f2w1 = (const float*)d_in[24];
  const float* f2g1 = (const float*)d_in[25];
  const float* f2b1 = (const float*)d_in[26];
  float* out = (float*)d_out;

  float* ws = (float*)d_ws;
  // stats slots (zeroed): [sum, sq] pairs
  float* sum0 = ws + 0;    float* sq0 = ws + 256;
  float* sum1 = ws + 512;  float* sq1 = ws + 768;
  float* sum2 = ws + 1024; float* sq2 = ws + 1280;
  float* sum3 = ws + 1536; float* sq3 = ws + 1792;
  float* sum5 = ws + 2048; float* sq5 = ws + 2304;
  float* sumT = ws + 2560; float* sqT = ws + 2816;
  float* sum4 = ws + 3072; float* sq4 = ws + 4096;  // 1024 each, ends at 5120
  int* counts  = (int*)(ws + 8192);
  int* offsets = (int*)(ws + 45056);
  int* cursor  = (int*)(ws + 82176);
  int* bsum    = (int*)(ws + 119296);
  int* boff    = (int*)(ws + 119552);
  int* sorted  = (int*)(ws + 131072);
  float* aij   = ws + 425984;
  const size_t S = (size_t)NP * CH;        // 9437184 words
  float* slotD = ws + 720896;
  float* slotB = slotD + S;
  float* slotA = slotB + S;
  float* slotC = slotA + S;
  u16* bfB  = (u16*)(slotC + S);           // NP x 256 bf16
  u16* bfH  = bfB + S;                     // NP x 256 bf16
  float* sigT = (float*)(bfH + S);         // KSIG x NP fp32
  u16* bfW  = (u16*)(sigT + (size_t)KSIG * NP);
  u16* raw4bf  = (u16*)slotB;              // 1024 x NP bf16, spans slotB+slotA
  u16* bfT1024 = bfB;                      // NP x 1024 bf16, spans bfB+bfH+part sigT

  hipMemsetAsync(ws, 0, 5120 * sizeof(float), stream);
  hipMemsetAsync(counts, 0, NP * sizeof(int), stream);

  dim3 b256(256);
  k_cvtW<<<2432, b256, 0, stream>>>(pw1, f1w0, f1w1, dw1, dw2, f2w1, bfW);
  // img = X^T  -> slotA
  k_transpose<<<dim3(CH / 32, NP / 32), b256, 0, stream>>>(X, slotA, NP, CH);
  // ppm depthwise -> slotB (raw0) + stats0
  k_dwconv17<<<dim3(9, CH), b256, 0, stream>>>(slotA, pw0, slotB, sum0, sq0);
  k_cvtTs<<<dim3(NP / 64, 8), b256, 0, stream>>>(slotB, bfB, sum0, sq0, pg0, pb0, CH);
  // ppm 1x1 -> slotC (raw1) + stats1
  k_mgemm<<<dim3(NP / 128, 2), b256, 0, stream>>>(bfW, bfB, slotC, nullptr, sum1, sq1, CH, CH, 0);
  // img2 = img + bn(raw1) -> slotD ; bfB = leaky(img2)^T
  k_fuse1<<<dim3(NP / 64, 8), b256, 0, stream>>>(slotA, slotC, sum1, sq1, pg1, pb1, slotD, bfB);
  // ffn1 conv0 -> slotB (raw2) + stats2
  k_mgemm<<<dim3(NP / 128, 2), b256, 0, stream>>>(bfW + 65536, bfB, slotB, nullptr, sum2, sq2, CH, CH, 0);
  k_cvtTs<<<dim3(NP / 64, 8), b256, 0, stream>>>(slotB, bfB, sum2, sq2, f1g0, f1b0, CH);
  // ffn1 conv1 -> slotC (raw3) + stats3
  k_mgemm<<<dim3(NP / 128, 2), b256, 0, stream>>>(bfW + 131072, bfB, slotC, nullptr, sum3, sq3, CH, CH, 0);
  // Xn = img2 + bn(raw3): fp32 N x C -> slotA ; bf16 N x C -> bfB
  k_fuse2<<<dim3(NP / 64, 8), b256, 0, stream>>>(slotD, slotC, sum3, sq3, f1g1, f1b1, slotA, bfB);
  // dis: h -> slotC (bias + leaky)
  k_mgemm<<<dim3(NP / 128, 2), b256, 0, stream>>>(bfW + 196608, bfB, slotC, db1, nullptr, nullptr, CH, CH, 1);
  k_cvtT<<<dim3(NP / 64, 8), b256, 0, stream>>>(slotC, bfH, CH);
  k_mgemm<<<dim3(NP / 128, 3), b256, 0, stream>>>(bfW + 262144, bfH, sigT, db2, nullptr, nullptr, CH, KSIG, 0);
  // edges
  k_edge<<<EDGES / 256, b256, 0, stream>>>(info, msk, sigT, aij, counts);
  k_scan1<<<NP / 256, b256, 0, stream>>>(counts, offsets, bsum);
  k_scan2<<<1, b256, 0, stream>>>(bsum, boff);
  k_scan3<<<NP / 256, b256, 0, stream>>>(offsets, boff, cursor);
  k_scatter<<<EDGES / 256, b256, 0, stream>>>(info, cursor, sorted);
  // Xtr -> slotD (img2 dead)
  k_agg<<<NP / 4, b256, 0, stream>>>(offsets, sorted, aij, info, bfB, slotD);
  k_colstats<<<288, b256, 0, stream>>>(slotD, sumT, sqT);
  // img4 -> slotC (raw3/h dead)
  k_mkimg4<<<dim3(CH / 32, NP / 32), b256, 0, stream>>>(slotA, slotD, sumT, sqT, bng, bnb, slotC);
  // ffn2 grouped 3x3 -> raw4bf (slotB+slotA) + stats4
  k_conv3x4<<<dim3(36, CH), b256, 0, stream>>>(slotC, f2w0, raw4bf, sum4, sq4);
  k_cvtT_bf<<<dim3(NP / 64, 32), b256, 0, stream>>>(raw4bf, bfT1024, sum4, sq4, f2g0, f2b0, 1024);
  // ffn2 1x1 -> slotD (raw5) + stats5
  k_mgemm<<<dim3(NP / 128, 2), b256, 0, stream>>>(bfW + 360448, bfT1024, slotD, nullptr, sum5, sq5, 1024, CH, 0);
  k_final<<<dim3(NP / 32, CH / 32), b256, 0, stream>>>(slotD, slotC, sum5, sq5, f2g1, f2b1, out);
}

// Round 4
// 736.989 us; speedup vs baseline: 1.4782x; 1.4782x over previous
//
#include <hip/hip_runtime.h>
#include <cstddef>

#define HW 192
#define NP 36864          // H*W
#define CH 256
#define EDGES 294912
#define KSIG 289
#define SLOPE 0.01f
#define BNEPS 1e-5f

typedef unsigned short u16;
typedef __attribute__((ext_vector_type(8))) short bf16x8;
typedef __attribute__((ext_vector_type(4))) float f32x4;

__device__ __forceinline__ float leaky(float x) { return x >= 0.f ? x : SLOPE * x; }
__device__ __forceinline__ u16 f2bf(float x) {
  unsigned u = __float_as_uint(x);
  unsigned r = (u + 0x7fffu + ((u >> 16) & 1u)) >> 16;
  return (u16)r;
}
__device__ __forceinline__ float bf2f(unsigned h) { return __uint_as_float(h << 16); }
// inline BN scale/shift from raw sums
__device__ __forceinline__ void bnss(const float* sums, const float* sqs,
                                     const float* g, const float* b, int k,
                                     float& s, float& h) {
  float mean = sums[k] * (1.f / NP);
  float var = sqs[k] * (1.f / NP) - mean * mean;
  s = g[k] * rsqrtf(var + BNEPS);
  h = b[k] - mean * s;
}

// ---------------- generic 32x32 tiled transpose: src (R x S) -> dst (S x R) ----
__global__ __launch_bounds__(256) void k_transpose(const float* __restrict__ src,
                                                   float* __restrict__ dst, int R, int S) {
  __shared__ float tile[32][33];
  int s0 = blockIdx.x * 32, r0 = blockIdx.y * 32;
  int tx = threadIdx.x & 31, ty = threadIdx.x >> 5;
#pragma unroll
  for (int j = 0; j < 4; j++) {
    int r = r0 + ty + 8 * j;
    tile[ty + 8 * j][tx] = src[(size_t)r * S + s0 + tx];
  }
  __syncthreads();
#pragma unroll
  for (int j = 0; j < 4; j++) {
    int s = s0 + ty + 8 * j;
    dst[(size_t)s * R + r0 + tx] = tile[tx][ty + 8 * j];
  }
}

// ---------------- weight fp32 -> bf16 converter (dw2 zero-padded to 384 rows) --
__global__ __launch_bounds__(256) void k_cvtW(const float* __restrict__ pw1,
                                              const float* __restrict__ f1w0,
                                              const float* __restrict__ f1w1,
                                              const float* __restrict__ dw1,
                                              const float* __restrict__ dw2,
                                              const float* __restrict__ f2w1,
                                              u16* __restrict__ out) {
  int i = blockIdx.x * 256 + threadIdx.x;   // 0..622591
  float v;
  if (i < 65536) v = pw1[i];
  else if (i < 131072) v = f1w0[i - 65536];
  else if (i < 196608) v = f1w1[i - 131072];
  else if (i < 262144) v = dw1[i - 196608];
  else if (i < 360448) { int j = i - 262144; v = (j < KSIG * 256) ? dw2[j] : 0.f; }
  else v = f2w1[i - 360448];
  out[i] = f2bf(v);
}

// ---------------- per-row stats: sums/sqs, fp32 input (one block per row) ------
__global__ __launch_bounds__(256) void k_stats_f32(const float* __restrict__ Xr,
                                                   float* __restrict__ sums,
                                                   float* __restrict__ sqs) {
  int row = blockIdx.x;
  int t = threadIdx.x;
  const float4* p = (const float4*)(Xr + (size_t)row * NP);
  float s = 0.f, q = 0.f;
  for (int i = t; i < NP / 4; i += 256) {
    float4 v = p[i];
    s += v.x + v.y + v.z + v.w;
    q += v.x * v.x + v.y * v.y + v.z * v.z + v.w * v.w;
  }
  __shared__ float ss[256], qq[256];
  ss[t] = s; qq[t] = q;
  __syncthreads();
  for (int d = 128; d > 0; d >>= 1) {
    if (t < d) { ss[t] += ss[t + d]; qq[t] += qq[t + d]; }
    __syncthreads();
  }
  if (t == 0) { sums[row] = ss[0]; sqs[row] = qq[0]; }
}

// ---------------- per-row stats, bf16 input ------------------------------------
__global__ __launch_bounds__(256) void k_stats_bf(const u16* __restrict__ Xr,
                                                  float* __restrict__ sums,
                                                  float* __restrict__ sqs) {
  int row = blockIdx.x;
  int t = threadIdx.x;
  const uint4* p = (const uint4*)(Xr + (size_t)row * NP);
  float s = 0.f, q = 0.f;
  for (int i = t; i < NP / 8; i += 256) {
    uint4 v = p[i];
    unsigned w[4] = {v.x, v.y, v.z, v.w};
#pragma unroll
    for (int j = 0; j < 4; j++) {
      float a = bf2f(w[j] & 0xffffu), c = bf2f(w[j] >> 16);
      s += a + c; q += a * a + c * c;
    }
  }
  __shared__ float ss[256], qq[256];
  ss[t] = s; qq[t] = q;
  __syncthreads();
  for (int d = 128; d > 0; d >>= 1) {
    if (t < d) { ss[t] += ss[t + d]; qq[t] += qq[t + d]; }
    __syncthreads();
  }
  if (t == 0) { sums[row] = ss[0]; sqs[row] = qq[0]; }
}

// ---- fp32 (M x NP) -> bf16 transposed (NP x M), mode 0: identity --------------
__global__ __launch_bounds__(256) void k_cvtT(const float* __restrict__ in,
                                              u16* __restrict__ outT, int M) {
  __shared__ float tile[32][65];
  int n0 = blockIdx.x * 64, k0 = blockIdx.y * 32;
  int t = threadIdx.x;
#pragma unroll
  for (int i = 0; i < 2; i++) {
    int ci = i * 256 + t;
    int k = ci >> 4, cg = (ci & 15) * 4;
    float4 v = *(const float4*)&in[(size_t)(k0 + k) * NP + n0 + cg];
    tile[k][cg] = v.x; tile[k][cg + 1] = v.y; tile[k][cg + 2] = v.z; tile[k][cg + 3] = v.w;
  }
  __syncthreads();
  int n = t >> 2, kg = (t & 3) * 8;
  uint4 o;
  o.x = (unsigned)f2bf(tile[kg + 0][n]) | ((unsigned)f2bf(tile[kg + 1][n]) << 16);
  o.y = (unsigned)f2bf(tile[kg + 2][n]) | ((unsigned)f2bf(tile[kg + 3][n]) << 16);
  o.z = (unsigned)f2bf(tile[kg + 4][n]) | ((unsigned)f2bf(tile[kg + 5][n]) << 16);
  o.w = (unsigned)f2bf(tile[kg + 6][n]) | ((unsigned)f2bf(tile[kg + 7][n]) << 16);
  *(uint4*)&outT[(size_t)(n0 + n) * M + k0 + kg] = o;
}

// ---- fp32 (M x NP) -> bf16 transposed, f = leaky(bn(x)) with inline stats -----
__global__ __launch_bounds__(256) void k_cvtTs(const float* __restrict__ in,
                                               u16* __restrict__ outT,
                                               const float* __restrict__ sums,
                                               const float* __restrict__ sqs,
                                               const float* __restrict__ g,
                                               const float* __restrict__ b, int M) {
  __shared__ float tile[32][65];
  int n0 = blockIdx.x * 64, k0 = blockIdx.y * 32;
  int t = threadIdx.x;
#pragma unroll
  for (int i = 0; i < 2; i++) {
    int ci = i * 256 + t;
    int k = ci >> 4, cg = (ci & 15) * 4;
    float s, h; bnss(sums, sqs, g, b, k0 + k, s, h);
    float4 v = *(const float4*)&in[(size_t)(k0 + k) * NP + n0 + cg];
    tile[k][cg]     = leaky(fmaf(v.x, s, h));
    tile[k][cg + 1] = leaky(fmaf(v.y, s, h));
    tile[k][cg + 2] = leaky(fmaf(v.z, s, h));
    tile[k][cg + 3] = leaky(fmaf(v.w, s, h));
  }
  __syncthreads();
  int n = t >> 2, kg = (t & 3) * 8;
  uint4 o;
  o.x = (unsigned)f2bf(tile[kg + 0][n]) | ((unsigned)f2bf(tile[kg + 1][n]) << 16);
  o.y = (unsigned)f2bf(tile[kg + 2][n]) | ((unsigned)f2bf(tile[kg + 3][n]) << 16);
  o.z = (unsigned)f2bf(tile[kg + 4][n]) | ((unsigned)f2bf(tile[kg + 5][n]) << 16);
  o.w = (unsigned)f2bf(tile[kg + 6][n]) | ((unsigned)f2bf(tile[kg + 7][n]) << 16);
  *(uint4*)&outT[(size_t)(n0 + n) * M + k0 + kg] = o;
}

// ---- bf16 (1024 x NP) -> bf16 transposed (NP x 1024), leaky(bn(x)) inline -----
__global__ __launch_bounds__(256) void k_cvtT_bf(const u16* __restrict__ in,
                                                 u16* __restrict__ outT,
                                                 const float* __restrict__ sums,
                                                 const float* __restrict__ sqs,
                                                 const float* __restrict__ g,
                                                 const float* __restrict__ b, int M) {
  __shared__ float tile[32][65];
  int n0 = blockIdx.x * 64, k0 = blockIdx.y * 32;
  int t = threadIdx.x;
  int k = t >> 3, cg = (t & 7) * 8;
  float s, h; bnss(sums, sqs, g, b, k0 + k, s, h);
  uint4 v = *(const uint4*)&in[(size_t)(k0 + k) * NP + n0 + cg];
  unsigned w[4] = {v.x, v.y, v.z, v.w};
#pragma unroll
  for (int j = 0; j < 4; j++) {
    tile[k][cg + 2 * j]     = leaky(fmaf(bf2f(w[j] & 0xffffu), s, h));
    tile[k][cg + 2 * j + 1] = leaky(fmaf(bf2f(w[j] >> 16), s, h));
  }
  __syncthreads();
  int n = t >> 2, kg = (t & 3) * 8;
  uint4 o;
  o.x = (unsigned)f2bf(tile[kg + 0][n]) | ((unsigned)f2bf(tile[kg + 1][n]) << 16);
  o.y = (unsigned)f2bf(tile[kg + 2][n]) | ((unsigned)f2bf(tile[kg + 3][n]) << 16);
  o.z = (unsigned)f2bf(tile[kg + 4][n]) | ((unsigned)f2bf(tile[kg + 5][n]) << 16);
  o.w = (unsigned)f2bf(tile[kg + 6][n]) | ((unsigned)f2bf(tile[kg + 7][n]) << 16);
  *(uint4*)&outT[(size_t)(n0 + n) * M + k0 + kg] = o;
}

// ---- fuse1: img2 = img + bn(raw1); write img2 fp32 (CxN) + leaky(img2) bf16 T --
__global__ __launch_bounds__(256) void k_fuse1(const float* __restrict__ base,
                                               const float* __restrict__ raw,
                                               const float* __restrict__ sums,
                                               const float* __restrict__ sqs,
                                               const float* __restrict__ g,
                                               const float* __restrict__ b,
                                               float* __restrict__ img2,
                                               u16* __restrict__ outT) {
  __shared__ float tile[32][65];
  int n0 = blockIdx.x * 64, k0 = blockIdx.y * 32;
  int t = threadIdx.x;
#pragma unroll
  for (int i = 0; i < 2; i++) {
    int ci = i * 256 + t;
    int k = ci >> 4, cg = (ci & 15) * 4;
    float s, h; bnss(sums, sqs, g, b, k0 + k, s, h);
    size_t idx = (size_t)(k0 + k) * NP + n0 + cg;
    float4 bv = *(const float4*)&base[idx];
    float4 rv = *(const float4*)&raw[idx];
    float4 o;
    o.x = bv.x + fmaf(rv.x, s, h); o.y = bv.y + fmaf(rv.y, s, h);
    o.z = bv.z + fmaf(rv.z, s, h); o.w = bv.w + fmaf(rv.w, s, h);
    *(float4*)&img2[idx] = o;
    tile[k][cg]     = leaky(o.x);
    tile[k][cg + 1] = leaky(o.y);
    tile[k][cg + 2] = leaky(o.z);
    tile[k][cg + 3] = leaky(o.w);
  }
  __syncthreads();
  int n = t >> 2, kg = (t & 3) * 8;
  uint4 o;
  o.x = (unsigned)f2bf(tile[kg + 0][n]) | ((unsigned)f2bf(tile[kg + 1][n]) << 16);
  o.y = (unsigned)f2bf(tile[kg + 2][n]) | ((unsigned)f2bf(tile[kg + 3][n]) << 16);
  o.z = (unsigned)f2bf(tile[kg + 4][n]) | ((unsigned)f2bf(tile[kg + 5][n]) << 16);
  o.w = (unsigned)f2bf(tile[kg + 6][n]) | ((unsigned)f2bf(tile[kg + 7][n]) << 16);
  *(uint4*)&outT[(size_t)(n0 + n) * CH + k0 + kg] = o;
}

// ---- fuse2: Xn = img2 + bn(raw3); write Xn fp32 (NxC) + Xn bf16 (NxC) ---------
__global__ __launch_bounds__(256) void k_fuse2(const float* __restrict__ base,
                                               const float* __restrict__ raw,
                                               const float* __restrict__ sums,
                                               const float* __restrict__ sqs,
                                               const float* __restrict__ g,
                                               const float* __restrict__ b,
                                               float* __restrict__ XnT,
                                               u16* __restrict__ outT) {
  __shared__ float tile[32][65];
  int n0 = blockIdx.x * 64, k0 = blockIdx.y * 32;
  int t = threadIdx.x;
#pragma unroll
  for (int i = 0; i < 2; i++) {
    int ci = i * 256 + t;
    int k = ci >> 4, cg = (ci & 15) * 4;
    float s, h; bnss(sums, sqs, g, b, k0 + k, s, h);
    size_t idx = (size_t)(k0 + k) * NP + n0 + cg;
    float4 bv = *(const float4*)&base[idx];
    float4 rv = *(const float4*)&raw[idx];
    tile[k][cg]     = bv.x + fmaf(rv.x, s, h);
    tile[k][cg + 1] = bv.y + fmaf(rv.y, s, h);
    tile[k][cg + 2] = bv.z + fmaf(rv.z, s, h);
    tile[k][cg + 3] = bv.w + fmaf(rv.w, s, h);
  }
  __syncthreads();
  int n = t >> 2, kg = (t & 3) * 8;
  float4 f0 = {tile[kg + 0][n], tile[kg + 1][n], tile[kg + 2][n], tile[kg + 3][n]};
  float4 f1 = {tile[kg + 4][n], tile[kg + 5][n], tile[kg + 6][n], tile[kg + 7][n]};
  *(float4*)&XnT[(size_t)(n0 + n) * CH + k0 + kg] = f0;
  *(float4*)&XnT[(size_t)(n0 + n) * CH + k0 + kg + 4] = f1;
  uint4 o;
  o.x = (unsigned)f2bf(f0.x) | ((unsigned)f2bf(f0.y) << 16);
  o.y = (unsigned)f2bf(f0.z) | ((unsigned)f2bf(f0.w) << 16);
  o.z = (unsigned)f2bf(f1.x) | ((unsigned)f2bf(f1.y) << 16);
  o.w = (unsigned)f2bf(f1.z) | ((unsigned)f2bf(f1.w) << 16);
  *(uint4*)&outT[(size_t)(n0 + n) * CH + k0 + kg] = o;
}

// ---------------- MFMA GEMM: Out(Mstore x NP) = A(Mt x K) @ Bt(NP x K)^T -------
__global__ __launch_bounds__(256) void k_mgemm(const u16* __restrict__ A,
                                               const u16* __restrict__ Bt,
                                               float* __restrict__ Out,
                                               const float* __restrict__ bias,
                                               int K, int Mstore, int actout) {
  __shared__ u16 As[128 * 32];
  __shared__ u16 Bs[128 * 32];
  int t = threadIdx.x;
  int lane = t & 63, wave = t >> 6;
  int wm = (wave >> 1) * 64, wn = (wave & 1) * 64;
  int m0 = blockIdx.y * 128, n0 = blockIdx.x * 128;
  int r = lane & 15, q = lane >> 4;
  f32x4 acc[4][4];
#pragma unroll
  for (int a = 0; a < 4; a++)
#pragma unroll
    for (int b = 0; b < 4; b++) acc[a][b] = (f32x4){0.f, 0.f, 0.f, 0.f};

  for (int k0 = 0; k0 < K; k0 += 32) {
#pragma unroll
    for (int i = 0; i < 2; i++) {
      int cc = t + i * 256;
      int mm = cc >> 2, kq = (cc & 3) * 8;
      uint4 av = *(const uint4*)&A[(size_t)(m0 + mm) * K + k0 + kq];
      uint4 bv = *(const uint4*)&Bt[(size_t)(n0 + mm) * K + k0 + kq];
      *(uint4*)&As[mm * 32 + kq] = av;
      *(uint4*)&Bs[mm * 32 + kq] = bv;
    }
    __syncthreads();
    bf16x8 af[4], bfr[4];
#pragma unroll
    for (int mt = 0; mt < 4; mt++)
      af[mt] = *(const bf16x8*)&As[(wm + mt * 16 + r) * 32 + q * 8];
#pragma unroll
    for (int nt = 0; nt < 4; nt++)
      bfr[nt] = *(const bf16x8*)&Bs[(wn + nt * 16 + r) * 32 + q * 8];
#pragma unroll
    for (int mt = 0; mt < 4; mt++)
#pragma unroll
      for (int nt = 0; nt < 4; nt++)
        acc[mt][nt] = __builtin_amdgcn_mfma_f32_16x16x32_bf16(af[mt], bfr[nt], acc[mt][nt], 0, 0, 0);
    __syncthreads();
  }
#pragma unroll
  for (int mt = 0; mt < 4; mt++) {
    int mrow = m0 + wm + mt * 16 + q * 4;
#pragma unroll
    for (int i = 0; i < 4; i++) {
      int m = mrow + i;
      if (m >= Mstore) continue;
      float bs = bias ? bias[m] : 0.f;
#pragma unroll
      for (int nt = 0; nt < 4; nt++) {
        float v = acc[mt][nt][i] + bs;
        if (actout) v = leaky(v);
        Out[(size_t)m * NP + n0 + wn + nt * 16 + r] = v;
      }
    }
  }
}

// ---------------- depthwise 17x17 conv, pad 8, leaky on input ------------------
// 64x64 tile per block, 4x4 outputs per thread, LDS 80x84 padded
__global__ __launch_bounds__(256) void k_dwconv17(const float* __restrict__ in,
                                                  const float* __restrict__ w,
                                                  float* __restrict__ out) {
  int c = blockIdx.y;
  int tile = blockIdx.x;                  // 0..8
  int ty0 = (tile / 3) * 64, tx0 = (tile % 3) * 64;
  __shared__ __align__(16) float sm[80 * 84];
  const float* inc = in + (size_t)c * NP;
  for (int i = threadIdx.x; i < 80 * 80; i += 256) {
    int r = i / 80, cc = i - r * 80;
    int gy = ty0 + r - 8, gx = tx0 + cc - 8;
    float v = 0.f;
    if (gy >= 0 && gy < HW && gx >= 0 && gx < HW) v = leaky(inc[gy * HW + gx]);
    sm[r * 84 + cc] = v;
  }
  __syncthreads();
  int tr = threadIdx.x >> 4, tc = threadIdx.x & 15;
  float acc[4][4];
#pragma unroll
  for (int oy = 0; oy < 4; oy++)
#pragma unroll
    for (int j = 0; j < 4; j++) acc[oy][j] = 0.f;
  const float* wc = w + c * 289;
  for (int iy = 0; iy < 20; iy++) {
    const float* rowp = &sm[(4 * tr + iy) * 84 + 4 * tc];
    float win[20];
#pragma unroll
    for (int i = 0; i < 5; i++) {
      float4 v = *(const float4*)(rowp + 4 * i);
      win[4 * i] = v.x; win[4 * i + 1] = v.y; win[4 * i + 2] = v.z; win[4 * i + 3] = v.w;
    }
    int lo = iy - 16; if (lo < 0) lo = 0;
    int hi = iy; if (hi > 3) hi = 3;
#pragma unroll
    for (int oy = 0; oy < 4; oy++) {
      if (oy < lo || oy > hi) continue;
      const float* wr = wc + (iy - oy) * 17;
#pragma unroll
      for (int kx = 0; kx < 17; kx++) {
        float wv = wr[kx];
        acc[oy][0] = fmaf(wv, win[kx + 0], acc[oy][0]);
        acc[oy][1] = fmaf(wv, win[kx + 1], acc[oy][1]);
        acc[oy][2] = fmaf(wv, win[kx + 2], acc[oy][2]);
        acc[oy][3] = fmaf(wv, win[kx + 3], acc[oy][3]);
      }
    }
  }
#pragma unroll
  for (int oy = 0; oy < 4; oy++) {
    float4 o = {acc[oy][0], acc[oy][1], acc[oy][2], acc[oy][3]};
    *(float4*)(out + (size_t)c * NP + (ty0 + 4 * tr + oy) * HW + tx0 + 4 * tc) = o;
  }
}

// ---------------- grouped 3x3 conv, row-sliding, no LDS, no barrier ------------
// one wave per (channel, row); lane covers x = {lane, 64+lane, 128+lane}
__global__ __launch_bounds__(256) void k_conv3x4(const float* __restrict__ in,
                                                 const float* __restrict__ w,
                                                 u16* __restrict__ out) {
  int wave = threadIdx.x >> 6, lane = threadIdx.x & 63;
  int c = blockIdx.y;
  int y = blockIdx.x * 4 + wave;
  const float* wc = w + (size_t)(4 * c) * 9;
  float wr[36];
#pragma unroll
  for (int k = 0; k < 36; k++) wr[k] = wc[k];    // uniform -> scalar loads
  float acc[4][3];
#pragma unroll
  for (int oc = 0; oc < 4; oc++)
#pragma unroll
    for (int s = 0; s < 3; s++) acc[oc][s] = 0.f;
  const float* base = in + (size_t)c * NP;
#pragma unroll
  for (int ky = 0; ky < 3; ky++) {
    int ry = y + ky - 1;
    if (ry < 0 || ry >= HW) continue;            // wave-uniform branch
    const float* rp = base + ry * HW;
    float a0 = leaky(rp[lane]);
    float a1 = leaky(rp[64 + lane]);
    float a2 = leaky(rp[128 + lane]);
    float e0 = __shfl(a0, 63), e1 = __shfl(a1, 63);
    float b1 = __shfl(a1, 0),  b2 = __shfl(a2, 0);
    float l0 = __shfl_up(a0, 1); if (lane == 0) l0 = 0.f;
    float l1 = __shfl_up(a1, 1); if (lane == 0) l1 = e0;
    float l2 = __shfl_up(a2, 1); if (lane == 0) l2 = e1;
    float r0 = __shfl_down(a0, 1); if (lane == 63) r0 = b1;
    float r1 = __shfl_down(a1, 1); if (lane == 63) r1 = b2;
    float r2 = __shfl_down(a2, 1); if (lane == 63) r2 = 0.f;
#pragma unroll
    for (int oc = 0; oc < 4; oc++) {
      float w0 = wr[oc * 9 + ky * 3], w1 = wr[oc * 9 + ky * 3 + 1], w2 = wr[oc * 9 + ky * 3 + 2];
      acc[oc][0] = fmaf(w0, l0, fmaf(w1, a0, fmaf(w2, r0, acc[oc][0])));
      acc[oc][1] = fmaf(w0, l1, fmaf(w1, a1, fmaf(w2, r1, acc[oc][1])));
      acc[oc][2] = fmaf(w0, l2, fmaf(w1, a2, fmaf(w2, r2, acc[oc][2])));
    }
  }
  size_t ob = (size_t)(4 * c) * NP + (size_t)y * HW + lane;
#pragma unroll
  for (int oc = 0; oc < 4; oc++) {
    out[ob + (size_t)oc * NP]       = f2bf(acc[oc][0]);
    out[ob + (size_t)oc * NP + 64]  = f2bf(acc[oc][1]);
    out[ob + (size_t)oc * NP + 128] = f2bf(acc[oc][2]);
  }
}

// ---------------- edge scores + dst histogram ----------------------------------
__global__ __launch_bounds__(256) void k_edge(const int* __restrict__ info,
                                              const float* __restrict__ msk,
                                              const float* __restrict__ sig,
                                              float* __restrict__ aij,
                                              int* __restrict__ counts) {
  int e = blockIdx.x * 256 + threadIdx.x;
  int4 ii = ((const int4*)info)[e];   // src, k1, dst, k2
  float s = sig[(size_t)ii.y * NP + ii.x] + sig[(size_t)ii.w * NP + ii.z];
  s = fminf(fmaxf(s, -5.f), 5.f);
  aij[e] = expf(s) * msk[e];
  atomicAdd(&counts[ii.z], 1);
}

// ---------------- counting-sort by dst -----------------------------------------
__global__ __launch_bounds__(256) void k_scan1(const int* __restrict__ counts,
                                               int* __restrict__ offsets,
                                               int* __restrict__ bsum) {
  __shared__ int sm[256];
  int t = threadIdx.x;
  int i = blockIdx.x * 256 + t;
  int v = counts[i];
  sm[t] = v;
  __syncthreads();
  for (int d = 1; d < 256; d <<= 1) {
    int add = (t >= d) ? sm[t - d] : 0;
    __syncthreads();
    sm[t] += add;
    __syncthreads();
  }
  offsets[i] = sm[t] - v;
  if (t == 255) bsum[blockIdx.x] = sm[255];
}
__global__ __launch_bounds__(256) void k_scan2(const int* __restrict__ bsum,
                                               int* __restrict__ boff) {
  __shared__ int sm[256];
  int t = threadIdx.x;
  int v = (t < 144) ? bsum[t] : 0;
  sm[t] = v;
  __syncthreads();
  for (int d = 1; d < 256; d <<= 1) {
    int add = (t >= d) ? sm[t - d] : 0;
    __syncthreads();
    sm[t] += add;
    __syncthreads();
  }
  boff[t] = sm[t] - v;
}
__global__ __launch_bounds__(256) void k_scan3(int* __restrict__ offsets,
                                               const int* __restrict__ boff,
                                               int* __restrict__ cursor) {
  int i = blockIdx.x * 256 + threadIdx.x;
  int o = offsets[i] + boff[blockIdx.x];
  offsets[i] = o;
  cursor[i] = o;
  if (i == 0) offsets[NP] = EDGES;
}
__global__ __launch_bounds__(256) void k_scatter(const int* __restrict__ info,
                                                 int* __restrict__ cursor,
                                                 int* __restrict__ sorted) {
  int e = blockIdx.x * 256 + threadIdx.x;
  int d = info[4 * e + 2];
  int pos = atomicAdd(&cursor[d], 1);
  sorted[pos] = e;
}

// ---------------- per-node aggregation (one wave per node, bf16 gather) --------
__global__ __launch_bounds__(256) void k_agg(const int* __restrict__ offsets,
                                             const int* __restrict__ sorted,
                                             const float* __restrict__ aij,
                                             const int* __restrict__ info,
                                             const u16* __restrict__ XnBf,
                                             float* __restrict__ Xtr) {
  int wave = threadIdx.x >> 6, lane = threadIdx.x & 63;
  int node = blockIdx.x * 4 + wave;
  int o0 = offsets[node], o1 = offsets[node + 1];
  float ax = 0.f, ay = 0.f, az = 0.f, aw = 0.f, asum = 0.f;
  for (int i = o0; i < o1; i++) {
    int e = sorted[i];
    float a = aij[e];
    int s = info[4 * e];
    uint2 v = ((const uint2*)(XnBf + (size_t)s * CH))[lane];
    ax = fmaf(a, bf2f(v.x & 0xffffu), ax);
    ay = fmaf(a, bf2f(v.x >> 16), ay);
    az = fmaf(a, bf2f(v.y & 0xffffu), az);
    aw = fmaf(a, bf2f(v.y >> 16), aw);
    asum += a;
  }
  float inv = 1.f / (asum + 1e-5f);
  float4 o = {ax * inv, ay * inv, az * inv, aw * inv};
  ((float4*)(Xtr + (size_t)node * CH))[lane] = o;
}

// ---------------- bn1d stats ----------------------------------------------------
__global__ __launch_bounds__(256) void k_colstats(const float* __restrict__ Xt,
                                                  float* __restrict__ sums,
                                                  float* __restrict__ sqs) {
  int c = threadIdx.x;
  float s = 0.f, q = 0.f;
  for (int n = blockIdx.x; n < NP; n += gridDim.x) {
    float v = Xt[(size_t)n * CH + c];
    s += v; q += v * v;
  }
  atomicAdd(&sums[c], s);
  atomicAdd(&sqs[c], q);
}

// ---------------- img4 = transpose(Xn + bn1d(Xtr))  (N x C -> C x N) -----------
__global__ __launch_bounds__(256) void k_mkimg4(const float* __restrict__ Xn,
                                                const float* __restrict__ Xtr,
                                                const float* __restrict__ sums,
                                                const float* __restrict__ sqs,
                                                const float* __restrict__ g,
                                                const float* __restrict__ b,
                                                float* __restrict__ img4) {
  __shared__ float tile[32][33];
  int c0 = blockIdx.x * 32, n0 = blockIdx.y * 32;
  int tx = threadIdx.x & 31, ty = threadIdx.x >> 5;
  int c = c0 + tx;
  float s, h; bnss(sums, sqs, g, b, c, s, h);
#pragma unroll
  for (int j = 0; j < 4; j++) {
    size_t idx = (size_t)(n0 + ty + 8 * j) * CH + c;
    tile[ty + 8 * j][tx] = Xn[idx] + fmaf(Xtr[idx], s, h);
  }
  __syncthreads();
#pragma unroll
  for (int j = 0; j < 4; j++) {
    int cc = c0 + ty + 8 * j;
    img4[(size_t)cc * NP + n0 + tx] = tile[tx][ty + 8 * j];
  }
}

// ---------------- out(N x C) = transpose(bn(raw5) + img4), inline stats --------
__global__ __launch_bounds__(256) void k_final(const float* __restrict__ raw5,
                                               const float* __restrict__ img4,
                                               const float* __restrict__ sums,
                                               const float* __restrict__ sqs,
                                               const float* __restrict__ g,
                                               const float* __restrict__ b,
                                               float* __restrict__ out) {
  __shared__ float tile[32][33];
  int n0 = blockIdx.x * 32, c0 = blockIdx.y * 32;
  int tx = threadIdx.x & 31, ty = threadIdx.x >> 5;
#pragma unroll
  for (int j = 0; j < 4; j++) {
    int c = c0 + ty + 8 * j;
    float s, h; bnss(sums, sqs, g, b, c, s, h);
    size_t idx = (size_t)c * NP + n0 + tx;
    tile[ty + 8 * j][tx] = fmaf(raw5[idx], s, h) + img4[idx];
  }
  __syncthreads();
#pragma unroll
  for (int j = 0; j < 4; j++) {
    int n = n0 + ty + 8 * j;
    out[(size_t)n * CH + c0 + tx] = tile[tx][ty + 8 * j];
  }
}

extern "C" void kernel_launch(void* const* d_in, const int* in_sizes, int n_in,
                              void* d_out, int out_size, void* d_ws, size_t ws_size,
                              hipStream_t stream) {
  (void)in_sizes; (void)n_in; (void)out_size; (void)ws_size;
  const float* X    = (const float*)d_in[0];
  const int*   info = (const int*)d_in[1];
  const float* msk  = (const float*)d_in[2];
  const float* pw0  = (const float*)d_in[3];
  const float* pg0  = (const float*)d_in[4];
  const float* pb0  = (const float*)d_in[5];
  const float* pw1  = (const float*)d_in[6];
  const float* pg1  = (const float*)d_in[7];
  const float* pb1  = (const float*)d_in[8];
  const float* f1w0 = (const float*)d_in[9];
  const float* f1g0 = (const float*)d_in[10];
  const float* f1b0 = (const float*)d_in[11];
  const float* f1w1 = (const float*)d_in[12];
  const float* f1g1 = (const float*)d_in[13];
  const float* f1b1 = (const float*)d_in[14];
  const float* dw1  = (const float*)d_in[15];
  const float* db1  = (const float*)d_in[16];
  const float* dw2  = (const float*)d_in[17];
  const float* db2  = (const float*)d_in[18];
  const float* bng  = (const float*)d_in[19];
  const float* bnb  = (const float*)d_in[20];
  const float* f2w0 = (const float*)d_in[21];
  const float* f2g0 = (const float*)d_in[22];
  const float* f2b0 = (const float*)d_in[23];
  const float* f2w1 = (const float*)d_in[24];
  const float* f2g1 = (const float*)d_in[25];
  const float* f2b1 = (const float*)d_in[26];
  float* out = (float*)d_out;

  float* ws = (float*)d_ws;
  // stats slots: [sum, sq] pairs
  float* sum0 = ws + 0;    float* sq0 = ws + 256;
  float* sum1 = ws + 512;  float* sq1 = ws + 768;
  float* sum2 = ws + 1024; float* sq2 = ws + 1280;
  float* sum3 = ws + 1536; float* sq3 = ws + 1792;
  float* sum5 = ws + 2048; float* sq5 = ws + 2304;
  float* sumT = ws + 2560; float* sqT = ws + 2816;   // atomic targets, zeroed
  float* sum4 = ws + 3072; float* sq4 = ws + 4096;   // 1024 each
  int* counts  = (int*)(ws + 8192);
  int* offsets = (int*)(ws + 45056);
  int* cursor  = (int*)(ws + 82176);
  int* bsum    = (int*)(ws + 119296);
  int* boff    = (int*)(ws + 119552);
  int* sorted  = (int*)(ws + 131072);
  float* aij   = ws + 425984;
  const size_t S = (size_t)NP * CH;        // 9437184 words
  float* slotD = ws + 720896;
  float* slotB = slotD + S;
  float* slotA = slotB + S;
  float* slotC = slotA + S;
  u16* bfB  = (u16*)(slotC + S);           // NP x 256 bf16
  u16* bfH  = bfB + S;                     // NP x 256 bf16
  float* sigT = (float*)(bfH + S);         // KSIG x NP fp32
  u16* bfW  = (u16*)(sigT + (size_t)KSIG * NP);
  u16* raw4bf  = (u16*)slotB;              // 1024 x NP bf16, spans slotB+slotA
  u16* bfT1024 = bfB;                      // NP x 1024 bf16, spans bfB+bfH+part sigT

  hipMemsetAsync(ws, 0, 5120 * sizeof(float), stream);
  hipMemsetAsync(counts, 0, NP * sizeof(int), stream);

  dim3 b256(256);
  k_cvtW<<<2432, b256, 0, stream>>>(pw1, f1w0, f1w1, dw1, dw2, f2w1, bfW);
  // img = X^T  -> slotA
  k_transpose<<<dim3(CH / 32, NP / 32), b256, 0, stream>>>(X, slotA, NP, CH);
  // ppm depthwise -> slotB (raw0)
  k_dwconv17<<<dim3(9, CH), b256, 0, stream>>>(slotA, pw0, slotB);
  k_stats_f32<<<CH, b256, 0, stream>>>(slotB, sum0, sq0);
  k_cvtTs<<<dim3(NP / 64, 8), b256, 0, stream>>>(slotB, bfB, sum0, sq0, pg0, pb0, CH);
  // ppm 1x1 -> slotC (raw1)
  k_mgemm<<<dim3(NP / 128, 2), b256, 0, stream>>>(bfW, bfB, slotC, nullptr, CH, CH, 0);
  k_stats_f32<<<CH, b256, 0, stream>>>(slotC, sum1, sq1);
  // img2 = img + bn(raw1) -> slotD ; bfB = leaky(img2)^T
  k_fuse1<<<dim3(NP / 64, 8), b256, 0, stream>>>(slotA, slotC, sum1, sq1, pg1, pb1, slotD, bfB);
  // ffn1 conv0 -> slotB (raw2)
  k_mgemm<<<dim3(NP / 128, 2), b256, 0, stream>>>(bfW + 65536, bfB, slotB, nullptr, CH, CH, 0);
  k_stats_f32<<<CH, b256, 0, stream>>>(slotB, sum2, sq2);
  k_cvtTs<<<dim3(NP / 64, 8), b256, 0, stream>>>(slotB, bfB, sum2, sq2, f1g0, f1b0, CH);
  // ffn1 conv1 -> slotC (raw3)
  k_mgemm<<<dim3(NP / 128, 2), b256, 0, stream>>>(bfW + 131072, bfB, slotC, nullptr, CH, CH, 0);
  k_stats_f32<<<CH, b256, 0, stream>>>(slotC, sum3, sq3);
  // Xn = img2 + bn(raw3): fp32 N x C -> slotA ; bf16 N x C -> bfB
  k_fuse2<<<dim3(NP / 64, 8), b256, 0, stream>>>(slotD, slotC, sum3, sq3, f1g1, f1b1, slotA, bfB);
  // dis: h -> slotC (bias + leaky)
  k_mgemm<<<dim3(NP / 128, 2), b256, 0, stream>>>(bfW + 196608, bfB, slotC, db1, CH, CH, 1);
  k_cvtT<<<dim3(NP / 64, 8), b256, 0, stream>>>(slotC, bfH, CH);
  k_mgemm<<<dim3(NP / 128, 3), b256, 0, stream>>>(bfW + 262144, bfH, sigT, db2, CH, KSIG, 0);
  // edges
  k_edge<<<EDGES / 256, b256, 0, stream>>>(info, msk, sigT, aij, counts);
  k_scan1<<<NP / 256, b256, 0, stream>>>(counts, offsets, bsum);
  k_scan2<<<1, b256, 0, stream>>>(bsum, boff);
  k_scan3<<<NP / 256, b256, 0, stream>>>(offsets, boff, cursor);
  k_scatter<<<EDGES / 256, b256, 0, stream>>>(info, cursor, sorted);
  // Xtr -> slotD (img2 dead)
  k_agg<<<NP / 4, b256, 0, stream>>>(offsets, sorted, aij, info, bfB, slotD);
  k_colstats<<<288, b256, 0, stream>>>(slotD, sumT, sqT);
  // img4 -> slotC (raw3/h dead)
  k_mkimg4<<<dim3(CH / 32, NP / 32), b256, 0, stream>>>(slotA, slotD, sumT, sqT, bng, bnb, slotC);
  // ffn2 grouped 3x3 -> raw4bf (slotB+slotA)
  k_conv3x4<<<dim3(48, CH), b256, 0, stream>>>(slotC, f2w0, raw4bf);
  k_stats_bf<<<1024, b256, 0, stream>>>(raw4bf, sum4, sq4);
  k_cvtT_bf<<<dim3(NP / 64, 32), b256, 0, stream>>>(raw4bf, bfT1024, sum4, sq4, f2g0, f2b0, 1024);
  // ffn2 1x1 -> slotD (raw5)
  k_mgemm<<<dim3(NP / 128, 2), b256, 0, stream>>>(bfW + 360448, bfT1024, slotD, nullptr, 1024, CH, 0);
  k_stats_f32<<<CH, b256, 0, stream>>>(slotD, sum5, sq5);
  k_final<<<dim3(NP / 32, CH / 32), b256, 0, stream>>>(slotD, slotC, sum5, sq5, f2g1, f2b1, out);
}

// Round 5
// 710.554 us; speedup vs baseline: 1.5332x; 1.0372x over previous
//
#include <hip/hip_runtime.h>
#include <cstddef>

#define HW 192
#define NP 36864          // H*W
#define CH 256
#define EDGES 294912
#define KSIG 289
#define SLOPE 0.01f
#define BNEPS 1e-5f

typedef unsigned short u16;
typedef __attribute__((ext_vector_type(8))) short bf16x8;
typedef __attribute__((ext_vector_type(4))) float f32x4;

__device__ __forceinline__ float leaky(float x) { return x >= 0.f ? x : SLOPE * x; }
__device__ __forceinline__ u16 f2bf(float x) {
  unsigned u = __float_as_uint(x);
  unsigned r = (u + 0x7fffu + ((u >> 16) & 1u)) >> 16;
  return (u16)r;
}
__device__ __forceinline__ float bf2f(unsigned h) { return __uint_as_float(h << 16); }
// inline BN scale/shift from raw sums
__device__ __forceinline__ void bnss(const float* sums, const float* sqs,
                                     const float* g, const float* b, int k,
                                     float& s, float& h) {
  float mean = sums[k] * (1.f / NP);
  float var = sqs[k] * (1.f / NP) - mean * mean;
  s = g[k] * rsqrtf(var + BNEPS);
  h = b[k] - mean * s;
}

// ---------------- generic 32x32 tiled transpose: src (R x S) -> dst (S x R) ----
__global__ __launch_bounds__(256) void k_transpose(const float* __restrict__ src,
                                                   float* __restrict__ dst, int R, int S) {
  __shared__ float tile[32][33];
  int s0 = blockIdx.x * 32, r0 = blockIdx.y * 32;
  int tx = threadIdx.x & 31, ty = threadIdx.x >> 5;
#pragma unroll
  for (int j = 0; j < 4; j++) {
    int r = r0 + ty + 8 * j;
    tile[ty + 8 * j][tx] = src[(size_t)r * S + s0 + tx];
  }
  __syncthreads();
#pragma unroll
  for (int j = 0; j < 4; j++) {
    int s = s0 + ty + 8 * j;
    dst[(size_t)s * R + r0 + tx] = tile[tx][ty + 8 * j];
  }
}

// ---------------- weight fp32 -> bf16 converter (dw2 zero-padded to 384 rows) --
__global__ __launch_bounds__(256) void k_cvtW(const float* __restrict__ pw1,
                                              const float* __restrict__ f1w0,
                                              const float* __restrict__ f1w1,
                                              const float* __restrict__ dw1,
                                              const float* __restrict__ dw2,
                                              const float* __restrict__ f2w1,
                                              u16* __restrict__ out) {
  int i = blockIdx.x * 256 + threadIdx.x;   // 0..622591
  float v;
  if (i < 65536) v = pw1[i];
  else if (i < 131072) v = f1w0[i - 65536];
  else if (i < 196608) v = f1w1[i - 131072];
  else if (i < 262144) v = dw1[i - 196608];
  else if (i < 360448) { int j = i - 262144; v = (j < KSIG * 256) ? dw2[j] : 0.f; }
  else v = f2w1[i - 360448];
  out[i] = f2bf(v);
}

// ---------------- per-row stats: sums/sqs, fp32 input (one block per row) ------
__global__ __launch_bounds__(256) void k_stats_f32(const float* __restrict__ Xr,
                                                   float* __restrict__ sums,
                                                   float* __restrict__ sqs) {
  int row = blockIdx.x;
  int t = threadIdx.x;
  const float4* p = (const float4*)(Xr + (size_t)row * NP);
  float s = 0.f, q = 0.f;
  for (int i = t; i < NP / 4; i += 256) {
    float4 v = p[i];
    s += v.x + v.y + v.z + v.w;
    q += v.x * v.x + v.y * v.y + v.z * v.z + v.w * v.w;
  }
  __shared__ float ss[256], qq[256];
  ss[t] = s; qq[t] = q;
  __syncthreads();
  for (int d = 128; d > 0; d >>= 1) {
    if (t < d) { ss[t] += ss[t + d]; qq[t] += qq[t + d]; }
    __syncthreads();
  }
  if (t == 0) { sums[row] = ss[0]; sqs[row] = qq[0]; }
}

// ---------------- per-row stats, bf16 input ------------------------------------
__global__ __launch_bounds__(256) void k_stats_bf(const u16* __restrict__ Xr,
                                                  float* __restrict__ sums,
                                                  float* __restrict__ sqs) {
  int row = blockIdx.x;
  int t = threadIdx.x;
  const uint4* p = (const uint4*)(Xr + (size_t)row * NP);
  float s = 0.f, q = 0.f;
  for (int i = t; i < NP / 8; i += 256) {
    uint4 v = p[i];
    unsigned w[4] = {v.x, v.y, v.z, v.w};
#pragma unroll
    for (int j = 0; j < 4; j++) {
      float a = bf2f(w[j] & 0xffffu), c = bf2f(w[j] >> 16);
      s += a + c; q += a * a + c * c;
    }
  }
  __shared__ float ss[256], qq[256];
  ss[t] = s; qq[t] = q;
  __syncthreads();
  for (int d = 128; d > 0; d >>= 1) {
    if (t < d) { ss[t] += ss[t + d]; qq[t] += qq[t + d]; }
    __syncthreads();
  }
  if (t == 0) { sums[row] = ss[0]; sqs[row] = qq[0]; }
}

// ---- fp32 (M x NP) -> bf16 transposed (NP x M), mode 0: identity --------------
__global__ __launch_bounds__(256) void k_cvtT(const float* __restrict__ in,
                                              u16* __restrict__ outT, int M) {
  __shared__ float tile[32][65];
  int n0 = blockIdx.x * 64, k0 = blockIdx.y * 32;
  int t = threadIdx.x;
#pragma unroll
  for (int i = 0; i < 2; i++) {
    int ci = i * 256 + t;
    int k = ci >> 4, cg = (ci & 15) * 4;
    float4 v = *(const float4*)&in[(size_t)(k0 + k) * NP + n0 + cg];
    tile[k][cg] = v.x; tile[k][cg + 1] = v.y; tile[k][cg + 2] = v.z; tile[k][cg + 3] = v.w;
  }
  __syncthreads();
  int n = t >> 2, kg = (t & 3) * 8;
  uint4 o;
  o.x = (unsigned)f2bf(tile[kg + 0][n]) | ((unsigned)f2bf(tile[kg + 1][n]) << 16);
  o.y = (unsigned)f2bf(tile[kg + 2][n]) | ((unsigned)f2bf(tile[kg + 3][n]) << 16);
  o.z = (unsigned)f2bf(tile[kg + 4][n]) | ((unsigned)f2bf(tile[kg + 5][n]) << 16);
  o.w = (unsigned)f2bf(tile[kg + 6][n]) | ((unsigned)f2bf(tile[kg + 7][n]) << 16);
  *(uint4*)&outT[(size_t)(n0 + n) * M + k0 + kg] = o;
}

// ---- fp32 (M x NP) -> bf16 transposed, f = leaky(bn(x)) with inline stats -----
__global__ __launch_bounds__(256) void k_cvtTs(const float* __restrict__ in,
                                               u16* __restrict__ outT,
                                               const float* __restrict__ sums,
                                               const float* __restrict__ sqs,
                                               const float* __restrict__ g,
                                               const float* __restrict__ b, int M) {
  __shared__ float tile[32][65];
  int n0 = blockIdx.x * 64, k0 = blockIdx.y * 32;
  int t = threadIdx.x;
#pragma unroll
  for (int i = 0; i < 2; i++) {
    int ci = i * 256 + t;
    int k = ci >> 4, cg = (ci & 15) * 4;
    float s, h; bnss(sums, sqs, g, b, k0 + k, s, h);
    float4 v = *(const float4*)&in[(size_t)(k0 + k) * NP + n0 + cg];
    tile[k][cg]     = leaky(fmaf(v.x, s, h));
    tile[k][cg + 1] = leaky(fmaf(v.y, s, h));
    tile[k][cg + 2] = leaky(fmaf(v.z, s, h));
    tile[k][cg + 3] = leaky(fmaf(v.w, s, h));
  }
  __syncthreads();
  int n = t >> 2, kg = (t & 3) * 8;
  uint4 o;
  o.x = (unsigned)f2bf(tile[kg + 0][n]) | ((unsigned)f2bf(tile[kg + 1][n]) << 16);
  o.y = (unsigned)f2bf(tile[kg + 2][n]) | ((unsigned)f2bf(tile[kg + 3][n]) << 16);
  o.z = (unsigned)f2bf(tile[kg + 4][n]) | ((unsigned)f2bf(tile[kg + 5][n]) << 16);
  o.w = (unsigned)f2bf(tile[kg + 6][n]) | ((unsigned)f2bf(tile[kg + 7][n]) << 16);
  *(uint4*)&outT[(size_t)(n0 + n) * M + k0 + kg] = o;
}

// ---- bf16 (1024 x NP) -> bf16 transposed (NP x 1024), leaky(bn(x)) inline -----
__global__ __launch_bounds__(256) void k_cvtT_bf(const u16* __restrict__ in,
                                                 u16* __restrict__ outT,
                                                 const float* __restrict__ sums,
                                                 const float* __restrict__ sqs,
                                                 const float* __restrict__ g,
                                                 const float* __restrict__ b, int M) {
  __shared__ float tile[32][65];
  int n0 = blockIdx.x * 64, k0 = blockIdx.y * 32;
  int t = threadIdx.x;
  int k = t >> 3, cg = (t & 7) * 8;
  float s, h; bnss(sums, sqs, g, b, k0 + k, s, h);
  uint4 v = *(const uint4*)&in[(size_t)(k0 + k) * NP + n0 + cg];
  unsigned w[4] = {v.x, v.y, v.z, v.w};
#pragma unroll
  for (int j = 0; j < 4; j++) {
    tile[k][cg + 2 * j]     = leaky(fmaf(bf2f(w[j] & 0xffffu), s, h));
    tile[k][cg + 2 * j + 1] = leaky(fmaf(bf2f(w[j] >> 16), s, h));
  }
  __syncthreads();
  int n = t >> 2, kg = (t & 3) * 8;
  uint4 o;
  o.x = (unsigned)f2bf(tile[kg + 0][n]) | ((unsigned)f2bf(tile[kg + 1][n]) << 16);
  o.y = (unsigned)f2bf(tile[kg + 2][n]) | ((unsigned)f2bf(tile[kg + 3][n]) << 16);
  o.z = (unsigned)f2bf(tile[kg + 4][n]) | ((unsigned)f2bf(tile[kg + 5][n]) << 16);
  o.w = (unsigned)f2bf(tile[kg + 6][n]) | ((unsigned)f2bf(tile[kg + 7][n]) << 16);
  *(uint4*)&outT[(size_t)(n0 + n) * M + k0 + kg] = o;
}

// ---- fuse1: img2 = img + bn(raw1); write img2 fp32 (CxN) + leaky(img2) bf16 T --
__global__ __launch_bounds__(256) void k_fuse1(const float* __restrict__ base,
                                               const float* __restrict__ raw,
                                               const float* __restrict__ sums,
                                               const float* __restrict__ sqs,
                                               const float* __restrict__ g,
                                               const float* __restrict__ b,
                                               float* __restrict__ img2,
                                               u16* __restrict__ outT) {
  __shared__ float tile[32][65];
  int n0 = blockIdx.x * 64, k0 = blockIdx.y * 32;
  int t = threadIdx.x;
#pragma unroll
  for (int i = 0; i < 2; i++) {
    int ci = i * 256 + t;
    int k = ci >> 4, cg = (ci & 15) * 4;
    float s, h; bnss(sums, sqs, g, b, k0 + k, s, h);
    size_t idx = (size_t)(k0 + k) * NP + n0 + cg;
    float4 bv = *(const float4*)&base[idx];
    float4 rv = *(const float4*)&raw[idx];
    float4 o;
    o.x = bv.x + fmaf(rv.x, s, h); o.y = bv.y + fmaf(rv.y, s, h);
    o.z = bv.z + fmaf(rv.z, s, h); o.w = bv.w + fmaf(rv.w, s, h);
    *(float4*)&img2[idx] = o;
    tile[k][cg]     = leaky(o.x);
    tile[k][cg + 1] = leaky(o.y);
    tile[k][cg + 2] = leaky(o.z);
    tile[k][cg + 3] = leaky(o.w);
  }
  __syncthreads();
  int n = t >> 2, kg = (t & 3) * 8;
  uint4 o;
  o.x = (unsigned)f2bf(tile[kg + 0][n]) | ((unsigned)f2bf(tile[kg + 1][n]) << 16);
  o.y = (unsigned)f2bf(tile[kg + 2][n]) | ((unsigned)f2bf(tile[kg + 3][n]) << 16);
  o.z = (unsigned)f2bf(tile[kg + 4][n]) | ((unsigned)f2bf(tile[kg + 5][n]) << 16);
  o.w = (unsigned)f2bf(tile[kg + 6][n]) | ((unsigned)f2bf(tile[kg + 7][n]) << 16);
  *(uint4*)&outT[(size_t)(n0 + n) * CH + k0 + kg] = o;
}

// ---- fuse2: Xn = img2 + bn(raw3); write Xn fp32 (NxC) + Xn bf16 (NxC) ---------
__global__ __launch_bounds__(256) void k_fuse2(const float* __restrict__ base,
                                               const float* __restrict__ raw,
                                               const float* __restrict__ sums,
                                               const float* __restrict__ sqs,
                                               const float* __restrict__ g,
                                               const float* __restrict__ b,
                                               float* __restrict__ XnT,
                                               u16* __restrict__ outT) {
  __shared__ float tile[32][65];
  int n0 = blockIdx.x * 64, k0 = blockIdx.y * 32;
  int t = threadIdx.x;
#pragma unroll
  for (int i = 0; i < 2; i++) {
    int ci = i * 256 + t;
    int k = ci >> 4, cg = (ci & 15) * 4;
    float s, h; bnss(sums, sqs, g, b, k0 + k, s, h);
    size_t idx = (size_t)(k0 + k) * NP + n0 + cg;
    float4 bv = *(const float4*)&base[idx];
    float4 rv = *(const float4*)&raw[idx];
    tile[k][cg]     = bv.x + fmaf(rv.x, s, h);
    tile[k][cg + 1] = bv.y + fmaf(rv.y, s, h);
    tile[k][cg + 2] = bv.z + fmaf(rv.z, s, h);
    tile[k][cg + 3] = bv.w + fmaf(rv.w, s, h);
  }
  __syncthreads();
  int n = t >> 2, kg = (t & 3) * 8;
  float4 f0 = {tile[kg + 0][n], tile[kg + 1][n], tile[kg + 2][n], tile[kg + 3][n]};
  float4 f1 = {tile[kg + 4][n], tile[kg + 5][n], tile[kg + 6][n], tile[kg + 7][n]};
  *(float4*)&XnT[(size_t)(n0 + n) * CH + k0 + kg] = f0;
  *(float4*)&XnT[(size_t)(n0 + n) * CH + k0 + kg + 4] = f1;
  uint4 o;
  o.x = (unsigned)f2bf(f0.x) | ((unsigned)f2bf(f0.y) << 16);
  o.y = (unsigned)f2bf(f0.z) | ((unsigned)f2bf(f0.w) << 16);
  o.z = (unsigned)f2bf(f1.x) | ((unsigned)f2bf(f1.y) << 16);
  o.w = (unsigned)f2bf(f1.z) | ((unsigned)f2bf(f1.w) << 16);
  *(uint4*)&outT[(size_t)(n0 + n) * CH + k0 + kg] = o;
}

// ---------------- MFMA GEMM: Out(Mstore x NP) = A(Mt x K) @ Bt(NP x K)^T -------
__global__ __launch_bounds__(256) void k_mgemm(const u16* __restrict__ A,
                                               const u16* __restrict__ Bt,
                                               float* __restrict__ Out,
                                               const float* __restrict__ bias,
                                               int K, int Mstore, int actout) {
  __shared__ u16 As[128 * 32];
  __shared__ u16 Bs[128 * 32];
  int t = threadIdx.x;
  int lane = t & 63, wave = t >> 6;
  int wm = (wave >> 1) * 64, wn = (wave & 1) * 64;
  int m0 = blockIdx.y * 128, n0 = blockIdx.x * 128;
  int r = lane & 15, q = lane >> 4;
  f32x4 acc[4][4];
#pragma unroll
  for (int a = 0; a < 4; a++)
#pragma unroll
    for (int b = 0; b < 4; b++) acc[a][b] = (f32x4){0.f, 0.f, 0.f, 0.f};

  for (int k0 = 0; k0 < K; k0 += 32) {
#pragma unroll
    for (int i = 0; i < 2; i++) {
      int cc = t + i * 256;
      int mm = cc >> 2, kq = (cc & 3) * 8;
      uint4 av = *(const uint4*)&A[(size_t)(m0 + mm) * K + k0 + kq];
      uint4 bv = *(const uint4*)&Bt[(size_t)(n0 + mm) * K + k0 + kq];
      *(uint4*)&As[mm * 32 + kq] = av;
      *(uint4*)&Bs[mm * 32 + kq] = bv;
    }
    __syncthreads();
    bf16x8 af[4], bfr[4];
#pragma unroll
    for (int mt = 0; mt < 4; mt++)
      af[mt] = *(const bf16x8*)&As[(wm + mt * 16 + r) * 32 + q * 8];
#pragma unroll
    for (int nt = 0; nt < 4; nt++)
      bfr[nt] = *(const bf16x8*)&Bs[(wn + nt * 16 + r) * 32 + q * 8];
#pragma unroll
    for (int mt = 0; mt < 4; mt++)
#pragma unroll
      for (int nt = 0; nt < 4; nt++)
        acc[mt][nt] = __builtin_amdgcn_mfma_f32_16x16x32_bf16(af[mt], bfr[nt], acc[mt][nt], 0, 0, 0);
    __syncthreads();
  }
#pragma unroll
  for (int mt = 0; mt < 4; mt++) {
    int mrow = m0 + wm + mt * 16 + q * 4;
#pragma unroll
    for (int i = 0; i < 4; i++) {
      int m = mrow + i;
      if (m >= Mstore) continue;
      float bs = bias ? bias[m] : 0.f;
#pragma unroll
      for (int nt = 0; nt < 4; nt++) {
        float v = acc[mt][nt][i] + bs;
        if (actout) v = leaky(v);
        Out[(size_t)m * NP + n0 + wn + nt * 16 + r] = v;
      }
    }
  }
}

// ---------------- depthwise 17x17 conv via MFMA (Toeplitz), pad 8 --------------
// 64x64 output tile per block; A = bf16 input rows (16 x 32 window),
// B = Toeplitz T_ky(32x16), T[k][n] = w[ky][k-n]; C += A@B over 17 ky.
__global__ __launch_bounds__(256) void k_dwconv17(const float* __restrict__ in,
                                                  const float* __restrict__ w,
                                                  float* __restrict__ out) {
  int c = blockIdx.y;
  int tile = blockIdx.x;                  // 0..8
  int ty0 = (tile / 3) * 64, tx0 = (tile % 3) * 64;
  __shared__ u16 smIn[80 * 88];           // rows 0..79 = y-8..y+71, cols 0..79
  __shared__ u16 smT[17 * 16 * 40];       // [ky][n][k], stride 40
  const float* inc = in + (size_t)c * NP;
  for (int i = threadIdx.x; i < 80 * 80; i += 256) {
    int r = i / 80, cc = i - r * 80;
    int gy = ty0 + r - 8, gx = tx0 + cc - 8;
    float v = 0.f;
    if (gy >= 0 && gy < HW && gx >= 0 && gx < HW) v = leaky(inc[gy * HW + gx]);
    smIn[r * 88 + cc] = f2bf(v);
  }
  const float* wc = w + c * 289;
  for (int i = threadIdx.x; i < 17 * 16 * 32; i += 256) {
    int ky = i >> 9;              // /512
    int rem = i & 511;
    int n = rem >> 5, kk = rem & 31;
    int kx = kk - n;
    float v = (kx >= 0 && kx < 17) ? wc[ky * 17 + kx] : 0.f;
    smT[(ky * 16 + n) * 40 + kk] = f2bf(v);
  }
  __syncthreads();
  int lane = threadIdx.x & 63, wave = threadIdx.x >> 6;
  int wy = wave * 16;
  int r = lane & 15, q = lane >> 4;
  f32x4 acc[4];
#pragma unroll
  for (int xt = 0; xt < 4; xt++) acc[xt] = (f32x4){0.f, 0.f, 0.f, 0.f};
#pragma unroll
  for (int ky = 0; ky < 17; ky++) {
    bf16x8 bfrag = *(const bf16x8*)&smT[(ky * 16 + r) * 40 + q * 8];
    int rowA = wy + r + ky;               // 0..79
#pragma unroll
    for (int xt = 0; xt < 4; xt++) {
      bf16x8 afrag = *(const bf16x8*)&smIn[rowA * 88 + xt * 16 + q * 8];
      acc[xt] = __builtin_amdgcn_mfma_f32_16x16x32_bf16(afrag, bfrag, acc[xt], 0, 0, 0);
    }
  }
  float* oc = out + (size_t)c * NP;
#pragma unroll
  for (int xt = 0; xt < 4; xt++) {
    int x = tx0 + xt * 16 + r;
#pragma unroll
    for (int i = 0; i < 4; i++) {
      int y = ty0 + wy + q * 4 + i;
      oc[y * HW + x] = acc[xt][i];
    }
  }
}

// ---------------- grouped 3x3 conv, row-sliding, no LDS, no barrier ------------
// one wave per (channel, row); lane covers x = {lane, 64+lane, 128+lane}
__global__ __launch_bounds__(256) void k_conv3x4(const float* __restrict__ in,
                                                 const float* __restrict__ w,
                                                 u16* __restrict__ out) {
  int wave = threadIdx.x >> 6, lane = threadIdx.x & 63;
  int c = blockIdx.y;
  int y = blockIdx.x * 4 + wave;
  const float* wc = w + (size_t)(4 * c) * 9;
  float wr[36];
#pragma unroll
  for (int k = 0; k < 36; k++) wr[k] = wc[k];    // uniform -> scalar loads
  float acc[4][3];
#pragma unroll
  for (int oc = 0; oc < 4; oc++)
#pragma unroll
    for (int s = 0; s < 3; s++) acc[oc][s] = 0.f;
  const float* base = in + (size_t)c * NP;
#pragma unroll
  for (int ky = 0; ky < 3; ky++) {
    int ry = y + ky - 1;
    if (ry < 0 || ry >= HW) continue;            // wave-uniform branch
    const float* rp = base + ry * HW;
    float a0 = leaky(rp[lane]);
    float a1 = leaky(rp[64 + lane]);
    float a2 = leaky(rp[128 + lane]);
    float e0 = __shfl(a0, 63), e1 = __shfl(a1, 63);
    float b1 = __shfl(a1, 0),  b2 = __shfl(a2, 0);
    float l0 = __shfl_up(a0, 1); if (lane == 0) l0 = 0.f;
    float l1 = __shfl_up(a1, 1); if (lane == 0) l1 = e0;
    float l2 = __shfl_up(a2, 1); if (lane == 0) l2 = e1;
    float r0 = __shfl_down(a0, 1); if (lane == 63) r0 = b1;
    float r1 = __shfl_down(a1, 1); if (lane == 63) r1 = b2;
    float r2 = __shfl_down(a2, 1); if (lane == 63) r2 = 0.f;
#pragma unroll
    for (int oc = 0; oc < 4; oc++) {
      float w0 = wr[oc * 9 + ky * 3], w1 = wr[oc * 9 + ky * 3 + 1], w2 = wr[oc * 9 + ky * 3 + 2];
      acc[oc][0] = fmaf(w0, l0, fmaf(w1, a0, fmaf(w2, r0, acc[oc][0])));
      acc[oc][1] = fmaf(w0, l1, fmaf(w1, a1, fmaf(w2, r1, acc[oc][1])));
      acc[oc][2] = fmaf(w0, l2, fmaf(w1, a2, fmaf(w2, r2, acc[oc][2])));
    }
  }
  size_t ob = (size_t)(4 * c) * NP + (size_t)y * HW + lane;
#pragma unroll
  for (int oc = 0; oc < 4; oc++) {
    out[ob + (size_t)oc * NP]       = f2bf(acc[oc][0]);
    out[ob + (size_t)oc * NP + 64]  = f2bf(acc[oc][1]);
    out[ob + (size_t)oc * NP + 128] = f2bf(acc[oc][2]);
  }
}

// ---------------- edge scores + dst histogram ----------------------------------
__global__ __launch_bounds__(256) void k_edge(const int* __restrict__ info,
                                              const float* __restrict__ msk,
                                              const float* __restrict__ sig,
                                              float* __restrict__ aij,
                                              int* __restrict__ counts) {
  int e = blockIdx.x * 256 + threadIdx.x;
  int4 ii = ((const int4*)info)[e];   // src, k1, dst, k2
  float s = sig[(size_t)ii.y * NP + ii.x] + sig[(size_t)ii.w * NP + ii.z];
  s = fminf(fmaxf(s, -5.f), 5.f);
  aij[e] = expf(s) * msk[e];
  atomicAdd(&counts[ii.z], 1);
}

// ---------------- counting-sort by dst -----------------------------------------
__global__ __launch_bounds__(256) void k_scan1(const int* __restrict__ counts,
                                               int* __restrict__ offsets,
                                               int* __restrict__ bsum) {
  __shared__ int sm[256];
  int t = threadIdx.x;
  int i = blockIdx.x * 256 + t;
  int v = counts[i];
  sm[t] = v;
  __syncthreads();
  for (int d = 1; d < 256; d <<= 1) {
    int add = (t >= d) ? sm[t - d] : 0;
    __syncthreads();
    sm[t] += add;
    __syncthreads();
  }
  offsets[i] = sm[t] - v;
  if (t == 255) bsum[blockIdx.x] = sm[255];
}
__global__ __launch_bounds__(256) void k_scan2(const int* __restrict__ bsum,
                                               int* __restrict__ boff) {
  __shared__ int sm[256];
  int t = threadIdx.x;
  int v = (t < 144) ? bsum[t] : 0;
  sm[t] = v;
  __syncthreads();
  for (int d = 1; d < 256; d <<= 1) {
    int add = (t >= d) ? sm[t - d] : 0;
    __syncthreads();
    sm[t] += add;
    __syncthreads();
  }
  boff[t] = sm[t] - v;
}
__global__ __launch_bounds__(256) void k_scan3(int* __restrict__ offsets,
                                               const int* __restrict__ boff,
                                               int* __restrict__ cursor) {
  int i = blockIdx.x * 256 + threadIdx.x;
  int o = offsets[i] + boff[blockIdx.x];
  offsets[i] = o;
  cursor[i] = o;
  if (i == 0) offsets[NP] = EDGES;
}
__global__ __launch_bounds__(256) void k_scatter(const int* __restrict__ info,
                                                 int* __restrict__ cursor,
                                                 int* __restrict__ sorted) {
  int e = blockIdx.x * 256 + threadIdx.x;
  int d = info[4 * e + 2];
  int pos = atomicAdd(&cursor[d], 1);
  sorted[pos] = e;
}

// ---------------- per-node aggregation (one wave per node, bf16 gather) --------
__global__ __launch_bounds__(256) void k_agg(const int* __restrict__ offsets,
                                             const int* __restrict__ sorted,
                                             const float* __restrict__ aij,
                                             const int* __restrict__ info,
                                             const u16* __restrict__ XnBf,
                                             float* __restrict__ Xtr) {
  int wave = threadIdx.x >> 6, lane = threadIdx.x & 63;
  int node = blockIdx.x * 4 + wave;
  int o0 = offsets[node], o1 = offsets[node + 1];
  float ax = 0.f, ay = 0.f, az = 0.f, aw = 0.f, asum = 0.f;
  for (int i = o0; i < o1; i++) {
    int e = sorted[i];
    float a = aij[e];
    int s = info[4 * e];
    uint2 v = ((const uint2*)(XnBf + (size_t)s * CH))[lane];
    ax = fmaf(a, bf2f(v.x & 0xffffu), ax);
    ay = fmaf(a, bf2f(v.x >> 16), ay);
    az = fmaf(a, bf2f(v.y & 0xffffu), az);
    aw = fmaf(a, bf2f(v.y >> 16), aw);
    asum += a;
  }
  float inv = 1.f / (asum + 1e-5f);
  float4 o = {ax * inv, ay * inv, az * inv, aw * inv};
  ((float4*)(Xtr + (size_t)node * CH))[lane] = o;
}

// ---------------- bn1d stats ----------------------------------------------------
__global__ __launch_bounds__(256) void k_colstats(const float* __restrict__ Xt,
                                                  float* __restrict__ sums,
                                                  float* __restrict__ sqs) {
  int c = threadIdx.x;
  float s = 0.f, q = 0.f;
  for (int n = blockIdx.x; n < NP; n += gridDim.x) {
    float v = Xt[(size_t)n * CH + c];
    s += v; q += v * v;
  }
  atomicAdd(&sums[c], s);
  atomicAdd(&sqs[c], q);
}

// ---------------- img4 = transpose(Xn + bn1d(Xtr))  (N x C -> C x N) -----------
__global__ __launch_bounds__(256) void k_mkimg4(const float* __restrict__ Xn,
                                                const float* __restrict__ Xtr,
                                                const float* __restrict__ sums,
                                                const float* __restrict__ sqs,
                                                const float* __restrict__ g,
                                                const float* __restrict__ b,
                                                float* __restrict__ img4) {
  __shared__ float tile[32][33];
  int c0 = blockIdx.x * 32, n0 = blockIdx.y * 32;
  int tx = threadIdx.x & 31, ty = threadIdx.x >> 5;
  int c = c0 + tx;
  float s, h; bnss(sums, sqs, g, b, c, s, h);
#pragma unroll
  for (int j = 0; j < 4; j++) {
    size_t idx = (size_t)(n0 + ty + 8 * j) * CH + c;
    tile[ty + 8 * j][tx] = Xn[idx] + fmaf(Xtr[idx], s, h);
  }
  __syncthreads();
#pragma unroll
  for (int j = 0; j < 4; j++) {
    int cc = c0 + ty + 8 * j;
    img4[(size_t)cc * NP + n0 + tx] = tile[tx][ty + 8 * j];
  }
}

// ---------------- out(N x C) = transpose(bn(raw5) + img4), inline stats --------
__global__ __launch_bounds__(256) void k_final(const float* __restrict__ raw5,
                                               const float* __restrict__ img4,
                                               const float* __restrict__ sums,
                                               const float* __restrict__ sqs,
                                               const float* __restrict__ g,
                                               const float* __restrict__ b,
                                               float* __restrict__ out) {
  __shared__ float tile[32][33];
  int n0 = blockIdx.x * 32, c0 = blockIdx.y * 32;
  int tx = threadIdx.x & 31, ty = threadIdx.x >> 5;
#pragma unroll
  for (int j = 0; j < 4; j++) {
    int c = c0 + ty + 8 * j;
    float s, h; bnss(sums, sqs, g, b, c, s, h);
    size_t idx = (size_t)c * NP + n0 + tx;
    tile[ty + 8 * j][tx] = fmaf(raw5[idx], s, h) + img4[idx];
  }
  __syncthreads();
#pragma unroll
  for (int j = 0; j < 4; j++) {
    int n = n0 + ty + 8 * j;
    out[(size_t)n * CH + c0 + tx] = tile[tx][ty + 8 * j];
  }
}

extern "C" void kernel_launch(void* const* d_in, const int* in_sizes, int n_in,
                              void* d_out, int out_size, void* d_ws, size_t ws_size,
                              hipStream_t stream) {
  (void)in_sizes; (void)n_in; (void)out_size; (void)ws_size;
  const float* X    = (const float*)d_in[0];
  const int*   info = (const int*)d_in[1];
  const float* msk  = (const float*)d_in[2];
  const float* pw0  = (const float*)d_in[3];
  const float* pg0  = (const float*)d_in[4];
  const float* pb0  = (const float*)d_in[5];
  const float* pw1  = (const float*)d_in[6];
  const float* pg1  = (const float*)d_in[7];
  const float* pb1  = (const float*)d_in[8];
  const float* f1w0 = (const float*)d_in[9];
  const float* f1g0 = (const float*)d_in[10];
  const float* f1b0 = (const float*)d_in[11];
  const float* f1w1 = (const float*)d_in[12];
  const float* f1g1 = (const float*)d_in[13];
  const float* f1b1 = (const float*)d_in[14];
  const float* dw1  = (const float*)d_in[15];
  const float* db1  = (const float*)d_in[16];
  const float* dw2  = (const float*)d_in[17];
  const float* db2  = (const float*)d_in[18];
  const float* bng  = (const float*)d_in[19];
  const float* bnb  = (const float*)d_in[20];
  const float* f2w0 = (const float*)d_in[21];
  const float* f2g0 = (const float*)d_in[22];
  const float* f2b0 = (const float*)d_in[23];
  const float* f2w1 = (const float*)d_in[24];
  const float* f2g1 = (const float*)d_in[25];
  const float* f2b1 = (const float*)d_in[26];
  float* out = (float*)d_out;

  float* ws = (float*)d_ws;
  // stats slots: [sum, sq] pairs
  float* sum0 = ws + 0;    float* sq0 = ws + 256;
  float* sum1 = ws + 512;  float* sq1 = ws + 768;
  float* sum2 = ws + 1024; float* sq2 = ws + 1280;
  float* sum3 = ws + 1536; float* sq3 = ws + 1792;
  float* sum5 = ws + 2048; float* sq5 = ws + 2304;
  float* sumT = ws + 2560; float* sqT = ws + 2816;   // atomic targets, zeroed
  float* sum4 = ws + 3072; float* sq4 = ws + 4096;   // 1024 each
  int* counts  = (int*)(ws + 8192);
  int* offsets = (int*)(ws + 45056);
  int* cursor  = (int*)(ws + 82176);
  int* bsum    = (int*)(ws + 119296);
  int* boff    = (int*)(ws + 119552);
  int* sorted  = (int*)(ws + 131072);
  float* aij   = ws + 425984;
  const size_t S = (size_t)NP * CH;        // 9437184 words
  float* slotD = ws + 720896;
  float* slotB = slotD + S;
  float* slotA = slotB + S;
  float* slotC = slotA + S;
  u16* bfB  = (u16*)(slotC + S);           // NP x 256 bf16
  u16* bfH  = bfB + S;                     // NP x 256 bf16
  float* sigT = (float*)(bfH + S);         // KSIG x NP fp32
  u16* bfW  = (u16*)(sigT + (size_t)KSIG * NP);
  u16* raw4bf  = (u16*)slotB;              // 1024 x NP bf16, spans slotB+slotA
  u16* bfT1024 = bfB;                      // NP x 1024 bf16, spans bfB+bfH+part sigT

  hipMemsetAsync(ws, 0, 5120 * sizeof(float), stream);
  hipMemsetAsync(counts, 0, NP * sizeof(int), stream);

  dim3 b256(256);
  k_cvtW<<<2432, b256, 0, stream>>>(pw1, f1w0, f1w1, dw1, dw2, f2w1, bfW);
  // img = X^T  -> slotA
  k_transpose<<<dim3(CH / 32, NP / 32), b256, 0, stream>>>(X, slotA, NP, CH);
  // ppm depthwise -> slotB (raw0)
  k_dwconv17<<<dim3(9, CH), b256, 0, stream>>>(slotA, pw0, slotB);
  k_stats_f32<<<CH, b256, 0, stream>>>(slotB, sum0, sq0);
  k_cvtTs<<<dim3(NP / 64, 8), b256, 0, stream>>>(slotB, bfB, sum0, sq0, pg0, pb0, CH);
  // ppm 1x1 -> slotC (raw1)
  k_mgemm<<<dim3(NP / 128, 2), b256, 0, stream>>>(bfW, bfB, slotC, nullptr, CH, CH, 0);
  k_stats_f32<<<CH, b256, 0, stream>>>(slotC, sum1, sq1);
  // img2 = img + bn(raw1) -> slotD ; bfB = leaky(img2)^T
  k_fuse1<<<dim3(NP / 64, 8), b256, 0, stream>>>(slotA, slotC, sum1, sq1, pg1, pb1, slotD, bfB);
  // ffn1 conv0 -> slotB (raw2)
  k_mgemm<<<dim3(NP / 128, 2), b256, 0, stream>>>(bfW + 65536, bfB, slotB, nullptr, CH, CH, 0);
  k_stats_f32<<<CH, b256, 0, stream>>>(slotB, sum2, sq2);
  k_cvtTs<<<dim3(NP / 64, 8), b256, 0, stream>>>(slotB, bfB, sum2, sq2, f1g0, f1b0, CH);
  // ffn1 conv1 -> slotC (raw3)
  k_mgemm<<<dim3(NP / 128, 2), b256, 0, stream>>>(bfW + 131072, bfB, slotC, nullptr, CH, CH, 0);
  k_stats_f32<<<CH, b256, 0, stream>>>(slotC, sum3, sq3);
  // Xn = img2 + bn(raw3): fp32 N x C -> slotA ; bf16 N x C -> bfB
  k_fuse2<<<dim3(NP / 64, 8), b256, 0, stream>>>(slotD, slotC, sum3, sq3, f1g1, f1b1, slotA, bfB);
  // dis: h -> slotC (bias + leaky)
  k_mgemm<<<dim3(NP / 128, 2), b256, 0, stream>>>(bfW + 196608, bfB, slotC, db1, CH, CH, 1);
  k_cvtT<<<dim3(NP / 64, 8), b256, 0, stream>>>(slotC, bfH, CH);
  k_mgemm<<<dim3(NP / 128, 3), b256, 0, stream>>>(bfW + 262144, bfH, sigT, db2, CH, KSIG, 0);
  // edges
  k_edge<<<EDGES / 256, b256, 0, stream>>>(info, msk, sigT, aij, counts);
  k_scan1<<<NP / 256, b256, 0, stream>>>(counts, offsets, bsum);
  k_scan2<<<1, b256, 0, stream>>>(bsum, boff);
  k_scan3<<<NP / 256, b256, 0, stream>>>(offsets, boff, cursor);
  k_scatter<<<EDGES / 256, b256, 0, stream>>>(info, cursor, sorted);
  // Xtr -> slotD (img2 dead)
  k_agg<<<NP / 4, b256, 0, stream>>>(offsets, sorted, aij, info, bfB, slotD);
  k_colstats<<<288, b256, 0, stream>>>(slotD, sumT, sqT);
  // img4 -> slotC (raw3/h dead)
  k_mkimg4<<<dim3(CH / 32, NP / 32), b256, 0, stream>>>(slotA, slotD, sumT, sqT, bng, bnb, slotC);
  // ffn2 grouped 3x3 -> raw4bf (slotB+slotA)
  k_conv3x4<<<dim3(48, CH), b256, 0, stream>>>(slotC, f2w0, raw4bf);
  k_stats_bf<<<1024, b256, 0, stream>>>(raw4bf, sum4, sq4);
  k_cvtT_bf<<<dim3(NP / 64, 32), b256, 0, stream>>>(raw4bf, bfT1024, sum4, sq4, f2g0, f2b0, 1024);
  // ffn2 1x1 -> slotD (raw5)
  k_mgemm<<<dim3(NP / 128, 2), b256, 0, stream>>>(bfW + 360448, bfT1024, slotD, nullptr, 1024, CH, 0);
  k_stats_f32<<<CH, b256, 0, stream>>>(slotD, sum5, sq5);
  k_final<<<dim3(NP / 32, CH / 32), b256, 0, stream>>>(slotD, slotC, sum5, sq5, f2g1, f2b1, out);
}

// Round 6
// 676.566 us; speedup vs baseline: 1.6103x; 1.0502x over previous
//
#include <hip/hip_runtime.h>
#include <cstddef>

#define HW 192
#define NP 36864          // H*W
#define CH 256
#define EDGES 294912
#define KSIG 289
#define SLOPE 0.01f
#define BNEPS 1e-5f
#define PADW 208          // padded image row (192 + 2*8)
#define PADSZ (PADW * PADW)   // 43264 u16 per channel

typedef unsigned short u16;
typedef __attribute__((ext_vector_type(8))) short bf16x8;
typedef __attribute__((ext_vector_type(4))) float f32x4;

__device__ __forceinline__ float leaky(float x) { return x >= 0.f ? x : SLOPE * x; }
__device__ __forceinline__ u16 f2bf(float x) {
  unsigned u = __float_as_uint(x);
  unsigned r = (u + 0x7fffu + ((u >> 16) & 1u)) >> 16;
  return (u16)r;
}
__device__ __forceinline__ float bf2f(unsigned h) { return __uint_as_float(h << 16); }
__device__ __forceinline__ void bnss(const float* sums, const float* sqs,
                                     const float* g, const float* b, int k,
                                     float& s, float& h) {
  float mean = sums[k] * (1.f / NP);
  float var = sqs[k] * (1.f / NP) - mean * mean;
  s = g[k] * rsqrtf(var + BNEPS);
  h = b[k] - mean * s;
}

// ---- img = X^T (fp32 CxN) + padded leaky bf16 image (borders pre-zeroed) ------
__global__ __launch_bounds__(256) void k_transpose_pad(const float* __restrict__ src,
                                                       float* __restrict__ dst,
                                                       u16* __restrict__ pad) {
  __shared__ float tile[32][33];
  int s0 = blockIdx.x * 32, r0 = blockIdx.y * 32;   // s0 = channel, r0 = node
  int tx = threadIdx.x & 31, ty = threadIdx.x >> 5;
#pragma unroll
  for (int j = 0; j < 4; j++)
    tile[ty + 8 * j][tx] = src[(size_t)(r0 + ty + 8 * j) * CH + s0 + tx];
  __syncthreads();
  int n = r0 + tx;
  int y = n / HW, x = n - y * HW;
#pragma unroll
  for (int j = 0; j < 4; j++) {
    int c = s0 + ty + 8 * j;
    float v = tile[tx][ty + 8 * j];
    dst[(size_t)c * NP + n] = v;
    pad[(size_t)c * PADSZ + (y + 8) * PADW + x + 8] = f2bf(leaky(v));
  }
}

// ---- global Toeplitz build: Tg[c][ky][n][k] = w[c][ky][k-n] (bf16) ------------
__global__ __launch_bounds__(256) void k_mkT(const float* __restrict__ w,
                                             u16* __restrict__ Tg) {
  int c = blockIdx.x;
  const float* wc = w + c * 289;
  u16* tc = Tg + (size_t)c * 8704;
  for (int i = threadIdx.x; i < 8704; i += 256) {
    int ky = i >> 9, rem = i & 511, n = rem >> 5, k = rem & 31;
    int kx = k - n;
    float v = (kx >= 0 && kx < 17) ? wc[ky * 17 + kx] : 0.f;
    tc[i] = f2bf(v);
  }
}

// ---------------- weight fp32 -> bf16 converter (dw2 zero-padded to 384 rows) --
__global__ __launch_bounds__(256) void k_cvtW(const float* __restrict__ pw1,
                                              const float* __restrict__ f1w0,
                                              const float* __restrict__ f1w1,
                                              const float* __restrict__ dw1,
                                              const float* __restrict__ dw2,
                                              const float* __restrict__ f2w1,
                                              u16* __restrict__ out) {
  int i = blockIdx.x * 256 + threadIdx.x;   // 0..622591
  float v;
  if (i < 65536) v = pw1[i];
  else if (i < 131072) v = f1w0[i - 65536];
  else if (i < 196608) v = f1w1[i - 131072];
  else if (i < 262144) v = dw1[i - 196608];
  else if (i < 360448) { int j = i - 262144; v = (j < KSIG * 256) ? dw2[j] : 0.f; }
  else v = f2w1[i - 360448];
  out[i] = f2bf(v);
}

// ---------------- per-row stats, bf16 input (one block per row) ----------------
__global__ __launch_bounds__(256) void k_stats_bf(const u16* __restrict__ Xr,
                                                  float* __restrict__ sums,
                                                  float* __restrict__ sqs) {
  int row = blockIdx.x;
  int t = threadIdx.x;
  const uint4* p = (const uint4*)(Xr + (size_t)row * NP);
  float s = 0.f, q = 0.f;
  for (int i = t; i < NP / 8; i += 256) {
    uint4 v = p[i];
    unsigned w[4] = {v.x, v.y, v.z, v.w};
#pragma unroll
    for (int j = 0; j < 4; j++) {
      float a = bf2f(w[j] & 0xffffu), c = bf2f(w[j] >> 16);
      s += a + c; q += a * a + c * c;
    }
  }
  __shared__ float ss[256], qq[256];
  ss[t] = s; qq[t] = q;
  __syncthreads();
  for (int d = 128; d > 0; d >>= 1) {
    if (t < d) { ss[t] += ss[t + d]; qq[t] += qq[t + d]; }
    __syncthreads();
  }
  if (t == 0) { sums[row] = ss[0]; sqs[row] = qq[0]; }
}

// ---- fp32 (M x NP) -> bf16 transposed (NP x M), identity ----------------------
__global__ __launch_bounds__(256) void k_cvtT(const float* __restrict__ in,
                                              u16* __restrict__ outT, int M) {
  __shared__ float tile[32][65];
  int n0 = blockIdx.x * 64, k0 = blockIdx.y * 32;
  int t = threadIdx.x;
#pragma unroll
  for (int i = 0; i < 2; i++) {
    int ci = i * 256 + t;
    int k = ci >> 4, cg = (ci & 15) * 4;
    float4 v = *(const float4*)&in[(size_t)(k0 + k) * NP + n0 + cg];
    tile[k][cg] = v.x; tile[k][cg + 1] = v.y; tile[k][cg + 2] = v.z; tile[k][cg + 3] = v.w;
  }
  __syncthreads();
  int n = t >> 2, kg = (t & 3) * 8;
  uint4 o;
  o.x = (unsigned)f2bf(tile[kg + 0][n]) | ((unsigned)f2bf(tile[kg + 1][n]) << 16);
  o.y = (unsigned)f2bf(tile[kg + 2][n]) | ((unsigned)f2bf(tile[kg + 3][n]) << 16);
  o.z = (unsigned)f2bf(tile[kg + 4][n]) | ((unsigned)f2bf(tile[kg + 5][n]) << 16);
  o.w = (unsigned)f2bf(tile[kg + 6][n]) | ((unsigned)f2bf(tile[kg + 7][n]) << 16);
  *(uint4*)&outT[(size_t)(n0 + n) * M + k0 + kg] = o;
}

// ---- bf16 (M x NP) -> bf16 transposed (NP x M), leaky(bn(x)) inline -----------
__global__ __launch_bounds__(256) void k_cvtT_bf(const u16* __restrict__ in,
                                                 u16* __restrict__ outT,
                                                 const float* __restrict__ sums,
                                                 const float* __restrict__ sqs,
                                                 const float* __restrict__ g,
                                                 const float* __restrict__ b, int M) {
  __shared__ float tile[32][65];
  int n0 = blockIdx.x * 64, k0 = blockIdx.y * 32;
  int t = threadIdx.x;
  int k = t >> 3, cg = (t & 7) * 8;
  float s, h; bnss(sums, sqs, g, b, k0 + k, s, h);
  uint4 v = *(const uint4*)&in[(size_t)(k0 + k) * NP + n0 + cg];
  unsigned w[4] = {v.x, v.y, v.z, v.w};
#pragma unroll
  for (int j = 0; j < 4; j++) {
    tile[k][cg + 2 * j]     = leaky(fmaf(bf2f(w[j] & 0xffffu), s, h));
    tile[k][cg + 2 * j + 1] = leaky(fmaf(bf2f(w[j] >> 16), s, h));
  }
  __syncthreads();
  int n = t >> 2, kg = (t & 3) * 8;
  uint4 o;
  o.x = (unsigned)f2bf(tile[kg + 0][n]) | ((unsigned)f2bf(tile[kg + 1][n]) << 16);
  o.y = (unsigned)f2bf(tile[kg + 2][n]) | ((unsigned)f2bf(tile[kg + 3][n]) << 16);
  o.z = (unsigned)f2bf(tile[kg + 4][n]) | ((unsigned)f2bf(tile[kg + 5][n]) << 16);
  o.w = (unsigned)f2bf(tile[kg + 6][n]) | ((unsigned)f2bf(tile[kg + 7][n]) << 16);
  *(uint4*)&outT[(size_t)(n0 + n) * M + k0 + kg] = o;
}

// ---- fuse1: img2 = img + bn(raw1 bf16); img2 fp32 (CxN) + leaky(img2) bf16 T --
__global__ __launch_bounds__(256) void k_fuse1(const float* __restrict__ base,
                                               const u16* __restrict__ raw,
                                               const float* __restrict__ sums,
                                               const float* __restrict__ sqs,
                                               const float* __restrict__ g,
                                               const float* __restrict__ b,
                                               float* __restrict__ img2,
                                               u16* __restrict__ outT) {
  __shared__ float tile[32][65];
  int n0 = blockIdx.x * 64, k0 = blockIdx.y * 32;
  int t = threadIdx.x;
#pragma unroll
  for (int i = 0; i < 2; i++) {
    int ci = i * 256 + t;
    int k = ci >> 4, cg = (ci & 15) * 4;
    float s, h; bnss(sums, sqs, g, b, k0 + k, s, h);
    size_t idx = (size_t)(k0 + k) * NP + n0 + cg;
    float4 bv = *(const float4*)&base[idx];
    uint2 rv = *(const uint2*)&raw[idx];
    float r0 = bf2f(rv.x & 0xffffu), r1 = bf2f(rv.x >> 16);
    float r2 = bf2f(rv.y & 0xffffu), r3 = bf2f(rv.y >> 16);
    float4 o;
    o.x = bv.x + fmaf(r0, s, h); o.y = bv.y + fmaf(r1, s, h);
    o.z = bv.z + fmaf(r2, s, h); o.w = bv.w + fmaf(r3, s, h);
    *(float4*)&img2[idx] = o;
    tile[k][cg]     = leaky(o.x);
    tile[k][cg + 1] = leaky(o.y);
    tile[k][cg + 2] = leaky(o.z);
    tile[k][cg + 3] = leaky(o.w);
  }
  __syncthreads();
  int n = t >> 2, kg = (t & 3) * 8;
  uint4 o;
  o.x = (unsigned)f2bf(tile[kg + 0][n]) | ((unsigned)f2bf(tile[kg + 1][n]) << 16);
  o.y = (unsigned)f2bf(tile[kg + 2][n]) | ((unsigned)f2bf(tile[kg + 3][n]) << 16);
  o.z = (unsigned)f2bf(tile[kg + 4][n]) | ((unsigned)f2bf(tile[kg + 5][n]) << 16);
  o.w = (unsigned)f2bf(tile[kg + 6][n]) | ((unsigned)f2bf(tile[kg + 7][n]) << 16);
  *(uint4*)&outT[(size_t)(n0 + n) * CH + k0 + kg] = o;
}

// ---- fuse2: Xn = img2 + bn(raw3 bf16); Xn fp32 (NxC) + Xn bf16 (NxC) ----------
__global__ __launch_bounds__(256) void k_fuse2(const float* __restrict__ base,
                                               const u16* __restrict__ raw,
                                               const float* __restrict__ sums,
                                               const float* __restrict__ sqs,
                                               const float* __restrict__ g,
                                               const float* __restrict__ b,
                                               float* __restrict__ XnT,
                                               u16* __restrict__ outT) {
  __shared__ float tile[32][65];
  int n0 = blockIdx.x * 64, k0 = blockIdx.y * 32;
  int t = threadIdx.x;
#pragma unroll
  for (int i = 0; i < 2; i++) {
    int ci = i * 256 + t;
    int k = ci >> 4, cg = (ci & 15) * 4;
    float s, h; bnss(sums, sqs, g, b, k0 + k, s, h);
    size_t idx = (size_t)(k0 + k) * NP + n0 + cg;
    float4 bv = *(const float4*)&base[idx];
    uint2 rv = *(const uint2*)&raw[idx];
    float r0 = bf2f(rv.x & 0xffffu), r1 = bf2f(rv.x >> 16);
    float r2 = bf2f(rv.y & 0xffffu), r3 = bf2f(rv.y >> 16);
    tile[k][cg]     = bv.x + fmaf(r0, s, h);
    tile[k][cg + 1] = bv.y + fmaf(r1, s, h);
    tile[k][cg + 2] = bv.z + fmaf(r2, s, h);
    tile[k][cg + 3] = bv.w + fmaf(r3, s, h);
  }
  __syncthreads();
  int n = t >> 2, kg = (t & 3) * 8;
  float4 f0 = {tile[kg + 0][n], tile[kg + 1][n], tile[kg + 2][n], tile[kg + 3][n]};
  float4 f1 = {tile[kg + 4][n], tile[kg + 5][n], tile[kg + 6][n], tile[kg + 7][n]};
  *(float4*)&XnT[(size_t)(n0 + n) * CH + k0 + kg] = f0;
  *(float4*)&XnT[(size_t)(n0 + n) * CH + k0 + kg + 4] = f1;
  uint4 o;
  o.x = (unsigned)f2bf(f0.x) | ((unsigned)f2bf(f0.y) << 16);
  o.y = (unsigned)f2bf(f0.z) | ((unsigned)f2bf(f0.w) << 16);
  o.z = (unsigned)f2bf(f1.x) | ((unsigned)f2bf(f1.y) << 16);
  o.w = (unsigned)f2bf(f1.z) | ((unsigned)f2bf(f1.w) << 16);
  *(uint4*)&outT[(size_t)(n0 + n) * CH + k0 + kg] = o;
}

// ---------------- MFMA GEMM: Out = A(M x K) @ Bt(NP x K)^T; fp32 or bf16 out ---
__global__ __launch_bounds__(256) void k_mgemm(const u16* __restrict__ A,
                                               const u16* __restrict__ Bt,
                                               float* __restrict__ Outf,
                                               u16* __restrict__ Outb,
                                               const float* __restrict__ bias,
                                               int K, int Mstore, int actout) {
  __shared__ u16 As[128 * 32];
  __shared__ u16 Bs[128 * 32];
  int t = threadIdx.x;
  int lane = t & 63, wave = t >> 6;
  int wm = (wave >> 1) * 64, wn = (wave & 1) * 64;
  int m0 = blockIdx.y * 128, n0 = blockIdx.x * 128;
  int r = lane & 15, q = lane >> 4;
  f32x4 acc[4][4];
#pragma unroll
  for (int a = 0; a < 4; a++)
#pragma unroll
    for (int b = 0; b < 4; b++) acc[a][b] = (f32x4){0.f, 0.f, 0.f, 0.f};

  for (int k0 = 0; k0 < K; k0 += 32) {
#pragma unroll
    for (int i = 0; i < 2; i++) {
      int cc = t + i * 256;
      int mm = cc >> 2, kq = (cc & 3) * 8;
      uint4 av = *(const uint4*)&A[(size_t)(m0 + mm) * K + k0 + kq];
      uint4 bv = *(const uint4*)&Bt[(size_t)(n0 + mm) * K + k0 + kq];
      *(uint4*)&As[mm * 32 + kq] = av;
      *(uint4*)&Bs[mm * 32 + kq] = bv;
    }
    __syncthreads();
    bf16x8 af[4], bfr[4];
#pragma unroll
    for (int mt = 0; mt < 4; mt++)
      af[mt] = *(const bf16x8*)&As[(wm + mt * 16 + r) * 32 + q * 8];
#pragma unroll
    for (int nt = 0; nt < 4; nt++)
      bfr[nt] = *(const bf16x8*)&Bs[(wn + nt * 16 + r) * 32 + q * 8];
#pragma unroll
    for (int mt = 0; mt < 4; mt++)
#pragma unroll
      for (int nt = 0; nt < 4; nt++)
        acc[mt][nt] = __builtin_amdgcn_mfma_f32_16x16x32_bf16(af[mt], bfr[nt], acc[mt][nt], 0, 0, 0);
    __syncthreads();
  }
#pragma unroll
  for (int mt = 0; mt < 4; mt++) {
    int mrow = m0 + wm + mt * 16 + q * 4;
#pragma unroll
    for (int i = 0; i < 4; i++) {
      int m = mrow + i;
      if (m >= Mstore) continue;
      float bs = bias ? bias[m] : 0.f;
#pragma unroll
      for (int nt = 0; nt < 4; nt++) {
        float v = acc[mt][nt][i] + bs;
        if (actout) v = leaky(v);
        size_t oi = (size_t)m * NP + n0 + wn + nt * 16 + r;
        if (Outb) Outb[oi] = f2bf(v); else Outf[oi] = v;
      }
    }
  }
}

// ---------------- depthwise 17x17 conv via MFMA, padded bf16 input -------------
__global__ __launch_bounds__(256) void k_dwconv17(const u16* __restrict__ pad,
                                                  const u16* __restrict__ Tg,
                                                  u16* __restrict__ outb) {
  int c = blockIdx.y;
  int tile = blockIdx.x;                  // 0..8
  int ty0 = (tile / 3) * 64, tx0 = (tile % 3) * 64;
  __shared__ u16 smIn[80 * 88];
  __shared__ u16 smT[17 * 16 * 40];
  const u16* pc = pad + (size_t)c * PADSZ;
  for (int cc = threadIdx.x; cc < 800; cc += 256) {
    int rr = cc / 10, j = cc - rr * 10;
    uint4 v = *(const uint4*)(pc + (ty0 + rr) * PADW + tx0 + j * 8);
    *(uint4*)(smIn + rr * 88 + j * 8) = v;
  }
  const u16* tc = Tg + (size_t)c * 8704;
  for (int cc = threadIdx.x; cc < 1088; cc += 256) {
    int rr = cc >> 2, j = cc & 3;
    uint4 v = *(const uint4*)(tc + rr * 32 + j * 8);
    *(uint4*)(smT + rr * 40 + j * 8) = v;
  }
  __syncthreads();
  int lane = threadIdx.x & 63, wave = threadIdx.x >> 6;
  int wy = wave * 16;
  int r = lane & 15, q = lane >> 4;
  f32x4 acc[4];
#pragma unroll
  for (int xt = 0; xt < 4; xt++) acc[xt] = (f32x4){0.f, 0.f, 0.f, 0.f};
#pragma unroll
  for (int ky = 0; ky < 17; ky++) {
    bf16x8 bfrag = *(const bf16x8*)&smT[(ky * 16 + r) * 40 + q * 8];
    int rowA = wy + r + ky;
#pragma unroll
    for (int xt = 0; xt < 4; xt++) {
      bf16x8 afrag = *(const bf16x8*)&smIn[rowA * 88 + xt * 16 + q * 8];
      acc[xt] = __builtin_amdgcn_mfma_f32_16x16x32_bf16(afrag, bfrag, acc[xt], 0, 0, 0);
    }
  }
  u16* oc = outb + (size_t)c * NP;
#pragma unroll
  for (int xt = 0; xt < 4; xt++) {
    int x = tx0 + xt * 16 + r;
#pragma unroll
    for (int i = 0; i < 4; i++) {
      int y = ty0 + wy + q * 4 + i;
      oc[y * HW + x] = f2bf(acc[xt][i]);
    }
  }
}

// ---------------- grouped 3x3 conv, row-sliding, no LDS, no barrier ------------
__global__ __launch_bounds__(256) void k_conv3x4(const float* __restrict__ in,
                                                 const float* __restrict__ w,
                                                 u16* __restrict__ out) {
  int wave = threadIdx.x >> 6, lane = threadIdx.x & 63;
  int c = blockIdx.y;
  int y = blockIdx.x * 4 + wave;
  const float* wc = w + (size_t)(4 * c) * 9;
  float wr[36];
#pragma unroll
  for (int k = 0; k < 36; k++) wr[k] = wc[k];
  float acc[4][3];
#pragma unroll
  for (int oc = 0; oc < 4; oc++)
#pragma unroll
    for (int s = 0; s < 3; s++) acc[oc][s] = 0.f;
  const float* base = in + (size_t)c * NP;
#pragma unroll
  for (int ky = 0; ky < 3; ky++) {
    int ry = y + ky - 1;
    if (ry < 0 || ry >= HW) continue;
    const float* rp = base + ry * HW;
    float a0 = leaky(rp[lane]);
    float a1 = leaky(rp[64 + lane]);
    float a2 = leaky(rp[128 + lane]);
    float e0 = __shfl(a0, 63), e1 = __shfl(a1, 63);
    float b1 = __shfl(a1, 0),  b2 = __shfl(a2, 0);
    float l0 = __shfl_up(a0, 1); if (lane == 0) l0 = 0.f;
    float l1 = __shfl_up(a1, 1); if (lane == 0) l1 = e0;
    float l2 = __shfl_up(a2, 1); if (lane == 0) l2 = e1;
    float r0 = __shfl_down(a0, 1); if (lane == 63) r0 = b1;
    float r1 = __shfl_down(a1, 1); if (lane == 63) r1 = b2;
    float r2 = __shfl_down(a2, 1); if (lane == 63) r2 = 0.f;
#pragma unroll
    for (int oc = 0; oc < 4; oc++) {
      float w0 = wr[oc * 9 + ky * 3], w1 = wr[oc * 9 + ky * 3 + 1], w2 = wr[oc * 9 + ky * 3 + 2];
      acc[oc][0] = fmaf(w0, l0, fmaf(w1, a0, fmaf(w2, r0, acc[oc][0])));
      acc[oc][1] = fmaf(w0, l1, fmaf(w1, a1, fmaf(w2, r1, acc[oc][1])));
      acc[oc][2] = fmaf(w0, l2, fmaf(w1, a2, fmaf(w2, r2, acc[oc][2])));
    }
  }
  size_t ob = (size_t)(4 * c) * NP + (size_t)y * HW + lane;
#pragma unroll
  for (int oc = 0; oc < 4; oc++) {
    out[ob + (size_t)oc * NP]       = f2bf(acc[oc][0]);
    out[ob + (size_t)oc * NP + 64]  = f2bf(acc[oc][1]);
    out[ob + (size_t)oc * NP + 128] = f2bf(acc[oc][2]);
  }
}

// ---------------- edge scores + dst histogram ----------------------------------
__global__ __launch_bounds__(256) void k_edge(const int* __restrict__ info,
                                              const float* __restrict__ msk,
                                              const float* __restrict__ sig,
                                              float* __restrict__ aij,
                                              int* __restrict__ counts) {
  int e = blockIdx.x * 256 + threadIdx.x;
  int4 ii = ((const int4*)info)[e];
  float s = sig[(size_t)ii.y * NP + ii.x] + sig[(size_t)ii.w * NP + ii.z];
  s = fminf(fmaxf(s, -5.f), 5.f);
  aij[e] = expf(s) * msk[e];
  atomicAdd(&counts[ii.z], 1);
}

// ---------------- counting-sort by dst -----------------------------------------
__global__ __launch_bounds__(256) void k_scan1(const int* __restrict__ counts,
                                               int* __restrict__ offsets,
                                               int* __restrict__ bsum) {
  __shared__ int sm[256];
  int t = threadIdx.x;
  int i = blockIdx.x * 256 + t;
  int v = counts[i];
  sm[t] = v;
  __syncthreads();
  for (int d = 1; d < 256; d <<= 1) {
    int add = (t >= d) ? sm[t - d] : 0;
    __syncthreads();
    sm[t] += add;
    __syncthreads();
  }
  offsets[i] = sm[t] - v;
  if (t == 255) bsum[blockIdx.x] = sm[255];
}
__global__ __launch_bounds__(256) void k_scan2(const int* __restrict__ bsum,
                                               int* __restrict__ boff) {
  __shared__ int sm[256];
  int t = threadIdx.x;
  int v = (t < 144) ? bsum[t] : 0;
  sm[t] = v;
  __syncthreads();
  for (int d = 1; d < 256; d <<= 1) {
    int add = (t >= d) ? sm[t - d] : 0;
    __syncthreads();
    sm[t] += add;
    __syncthreads();
  }
  boff[t] = sm[t] - v;
}
__global__ __launch_bounds__(256) void k_scan3(int* __restrict__ offsets,
                                               const int* __restrict__ boff,
                                               int* __restrict__ cursor) {
  int i = blockIdx.x * 256 + threadIdx.x;
  int o = offsets[i] + boff[blockIdx.x];
  offsets[i] = o;
  cursor[i] = o;
  if (i == 0) offsets[NP] = EDGES;
}
__global__ __launch_bounds__(256) void k_scatter(const int* __restrict__ info,
                                                 int* __restrict__ cursor,
                                                 int* __restrict__ sorted) {
  int e = blockIdx.x * 256 + threadIdx.x;
  int d = info[4 * e + 2];
  int pos = atomicAdd(&cursor[d], 1);
  sorted[pos] = e;
}

// ---------------- per-node aggregation (one wave per node, bf16 gather) --------
__global__ __launch_bounds__(256) void k_agg(const int* __restrict__ offsets,
                                             const int* __restrict__ sorted,
                                             const float* __restrict__ aij,
                                             const int* __restrict__ info,
                                             const u16* __restrict__ XnBf,
                                             float* __restrict__ Xtr) {
  int wave = threadIdx.x >> 6, lane = threadIdx.x & 63;
  int node = blockIdx.x * 4 + wave;
  int o0 = offsets[node], o1 = offsets[node + 1];
  float ax = 0.f, ay = 0.f, az = 0.f, aw = 0.f, asum = 0.f;
  for (int i = o0; i < o1; i++) {
    int e = sorted[i];
    float a = aij[e];
    int s = info[4 * e];
    uint2 v = ((const uint2*)(XnBf + (size_t)s * CH))[lane];
    ax = fmaf(a, bf2f(v.x & 0xffffu), ax);
    ay = fmaf(a, bf2f(v.x >> 16), ay);
    az = fmaf(a, bf2f(v.y & 0xffffu), az);
    aw = fmaf(a, bf2f(v.y >> 16), aw);
    asum += a;
  }
  float inv = 1.f / (asum + 1e-5f);
  float4 o = {ax * inv, ay * inv, az * inv, aw * inv};
  ((float4*)(Xtr + (size_t)node * CH))[lane] = o;
}

// ---------------- bn1d stats ----------------------------------------------------
__global__ __launch_bounds__(256) void k_colstats(const float* __restrict__ Xt,
                                                  float* __restrict__ sums,
                                                  float* __restrict__ sqs) {
  int c = threadIdx.x;
  float s = 0.f, q = 0.f;
  for (int n = blockIdx.x; n < NP; n += gridDim.x) {
    float v = Xt[(size_t)n * CH + c];
    s += v; q += v * v;
  }
  atomicAdd(&sums[c], s);
  atomicAdd(&sqs[c], q);
}

// ---------------- img4 = transpose(Xn + bn1d(Xtr))  (N x C -> C x N) -----------
__global__ __launch_bounds__(256) void k_mkimg4(const float* __restrict__ Xn,
                                                const float* __restrict__ Xtr,
                                                const float* __restrict__ sums,
                                                const float* __restrict__ sqs,
                                                const float* __restrict__ g,
                                                const float* __restrict__ b,
                                                float* __restrict__ img4) {
  __shared__ float tile[32][33];
  int c0 = blockIdx.x * 32, n0 = blockIdx.y * 32;
  int tx = threadIdx.x & 31, ty = threadIdx.x >> 5;
  int c = c0 + tx;
  float s, h; bnss(sums, sqs, g, b, c, s, h);
#pragma unroll
  for (int j = 0; j < 4; j++) {
    size_t idx = (size_t)(n0 + ty + 8 * j) * CH + c;
    tile[ty + 8 * j][tx] = Xn[idx] + fmaf(Xtr[idx], s, h);
  }
  __syncthreads();
#pragma unroll
  for (int j = 0; j < 4; j++) {
    int cc = c0 + ty + 8 * j;
    img4[(size_t)cc * NP + n0 + tx] = tile[tx][ty + 8 * j];
  }
}

// ---------------- out(N x C) = transpose(bn(raw5 bf16) + img4) -----------------
__global__ __launch_bounds__(256) void k_final(const u16* __restrict__ raw5,
                                               const float* __restrict__ img4,
                                               const float* __restrict__ sums,
                                               const float* __restrict__ sqs,
                                               const float* __restrict__ g,
                                               const float* __restrict__ b,
                                               float* __restrict__ out) {
  __shared__ float tile[32][33];
  int n0 = blockIdx.x * 32, c0 = blockIdx.y * 32;
  int tx = threadIdx.x & 31, ty = threadIdx.x >> 5;
#pragma unroll
  for (int j = 0; j < 4; j++) {
    int c = c0 + ty + 8 * j;
    float s, h; bnss(sums, sqs, g, b, c, s, h);
    size_t idx = (size_t)c * NP + n0 + tx;
    tile[ty + 8 * j][tx] = fmaf(bf2f(raw5[idx]), s, h) + img4[idx];
  }
  __syncthreads();
#pragma unroll
  for (int j = 0; j < 4; j++) {
    int n = n0 + ty + 8 * j;
    out[(size_t)n * CH + c0 + tx] = tile[tx][ty + 8 * j];
  }
}

extern "C" void kernel_launch(void* const* d_in, const int* in_sizes, int n_in,
                              void* d_out, int out_size, void* d_ws, size_t ws_size,
                              hipStream_t stream) {
  (void)in_sizes; (void)n_in; (void)out_size; (void)ws_size;
  const float* X    = (const float*)d_in[0];
  const int*   info = (const int*)d_in[1];
  const float* msk  = (const float*)d_in[2];
  const float* pw0  = (const float*)d_in[3];
  const float* pg0  = (const float*)d_in[4];
  const float* pb0  = (const float*)d_in[5];
  const float* pw1  = (const float*)d_in[6];
  const float* pg1  = (const float*)d_in[7];
  const float* pb1  = (const float*)d_in[8];
  const float* f1w0 = (const float*)d_in[9];
  const float* f1g0 = (const float*)d_in[10];
  const float* f1b0 = (const float*)d_in[11];
  const float* f1w1 = (const float*)d_in[12];
  const float* f1g1 = (const float*)d_in[13];
  const float* f1b1 = (const float*)d_in[14];
  const float* dw1  = (const float*)d_in[15];
  const float* db1  = (const float*)d_in[16];
  const float* dw2  = (const float*)d_in[17];
  const float* db2  = (const float*)d_in[18];
  const float* bng  = (const float*)d_in[19];
  const float* bnb  = (const float*)d_in[20];
  const float* f2w0 = (const float*)d_in[21];
  const float* f2g0 = (const float*)d_in[22];
  const float* f2b0 = (const float*)d_in[23];
  const float* f2w1 = (const float*)d_in[24];
  const float* f2g1 = (const float*)d_in[25];
  const float* f2b1 = (const float*)d_in[26];
  float* out = (float*)d_out;

  float* ws = (float*)d_ws;
  float* sum0 = ws + 0;    float* sq0 = ws + 256;
  float* sum1 = ws + 512;  float* sq1 = ws + 768;
  float* sum2 = ws + 1024; float* sq2 = ws + 1280;
  float* sum3 = ws + 1536; float* sq3 = ws + 1792;
  float* sum5 = ws + 2048; float* sq5 = ws + 2304;
  float* sumT = ws + 2560; float* sqT = ws + 2816;   // atomic targets, zeroed
  float* sum4 = ws + 3072; float* sq4 = ws + 4096;   // 1024 each
  int* counts  = (int*)(ws + 8192);
  int* offsets = (int*)(ws + 45056);
  int* cursor  = (int*)(ws + 82176);
  int* bsum    = (int*)(ws + 119296);
  int* boff    = (int*)(ws + 119552);
  int* sorted  = (int*)(ws + 131072);
  float* aij   = ws + 425984;
  const size_t S = (size_t)NP * CH;        // 9437184 words
  float* slotD = ws + 720896;
  float* slotB = slotD + S;
  float* slotA = slotB + S;
  float* slotC = slotA + S;
  u16* bfB  = (u16*)(slotC + S);           // NP x 256 bf16
  u16* bfH  = bfB + S;                     // raw0/raw1/raw2/raw3/h-bf16 (C x NP or NP x C)
  float* sigT = (float*)(bfH + S);         // KSIG x NP fp32
  u16* bfW  = (u16*)(sigT + (size_t)KSIG * NP);
  // early-phase aliases into dead fp32 slots:
  u16* Ppad = (u16*)slotC;                 // 256ch x 208x208 bf16 padded leaky img (dead before h)
  u16* Tg   = (u16*)slotD;                 // 256 x 8704 Toeplitz (dead before fuse1)
  u16* raw4bf  = (u16*)slotB;              // 1024 x NP bf16, spans slotB+slotA
  u16* bfT1024 = bfB;                      // NP x 1024 bf16, spans bfB+bfH+part sigT
  u16* raw5bf  = (u16*)slotD;              // C x NP bf16 (Xtr dead)

  hipMemsetAsync(ws, 0, 5120 * sizeof(float), stream);
  hipMemsetAsync(counts, 0, NP * sizeof(int), stream);
  hipMemsetAsync(Ppad, 0, (size_t)PADSZ * CH * sizeof(u16), stream);

  dim3 b256(256);
  k_cvtW<<<2432, b256, 0, stream>>>(pw1, f1w0, f1w1, dw1, dw2, f2w1, bfW);
  k_mkT<<<CH, b256, 0, stream>>>(pw0, Tg);
  // img = X^T -> slotA ; padded leaky bf16 -> Ppad
  k_transpose_pad<<<dim3(CH / 32, NP / 32), b256, 0, stream>>>(X, slotA, Ppad);
  // ppm depthwise -> raw0 bf16 (bfH)
  k_dwconv17<<<dim3(9, CH), b256, 0, stream>>>(Ppad, Tg, bfH);
  k_stats_bf<<<CH, b256, 0, stream>>>(bfH, sum0, sq0);
  k_cvtT_bf<<<dim3(NP / 64, 8), b256, 0, stream>>>(bfH, bfB, sum0, sq0, pg0, pb0, CH);
  // ppm 1x1 -> raw1 bf16 (bfH; raw0 dead)
  k_mgemm<<<dim3(NP / 128, 2), b256, 0, stream>>>(bfW, bfB, nullptr, bfH, nullptr, CH, CH, 0);
  k_stats_bf<<<CH, b256, 0, stream>>>(bfH, sum1, sq1);
  // img2 = img + bn(raw1) -> slotD (Tg dead) ; bfB = leaky(img2)^T
  k_fuse1<<<dim3(NP / 64, 8), b256, 0, stream>>>(slotA, bfH, sum1, sq1, pg1, pb1, slotD, bfB);
  // ffn1 conv0 -> raw2 bf16 (bfH)
  k_mgemm<<<dim3(NP / 128, 2), b256, 0, stream>>>(bfW + 65536, bfB, nullptr, bfH, nullptr, CH, CH, 0);
  k_stats_bf<<<CH, b256, 0, stream>>>(bfH, sum2, sq2);
  k_cvtT_bf<<<dim3(NP / 64, 8), b256, 0, stream>>>(bfH, bfB, sum2, sq2, f1g0, f1b0, CH);
  // ffn1 conv1 -> raw3 bf16 (bfH)
  k_mgemm<<<dim3(NP / 128, 2), b256, 0, stream>>>(bfW + 131072, bfB, nullptr, bfH, nullptr, CH, CH, 0);
  k_stats_bf<<<CH, b256, 0, stream>>>(bfH, sum3, sq3);
  // Xn = img2 + bn(raw3): fp32 NxC -> slotA ; bf16 NxC -> bfB
  k_fuse2<<<dim3(NP / 64, 8), b256, 0, stream>>>(slotD, bfH, sum3, sq3, f1g1, f1b1, slotA, bfB);
  // dis: h -> slotC fp32 (Ppad dead), bias + leaky
  k_mgemm<<<dim3(NP / 128, 2), b256, 0, stream>>>(bfW + 196608, bfB, slotC, nullptr, db1, CH, CH, 1);
  k_cvtT<<<dim3(NP / 64, 8), b256, 0, stream>>>(slotC, bfH, CH);   // raw3 dead
  k_mgemm<<<dim3(NP / 128, 3), b256, 0, stream>>>(bfW + 262144, bfH, sigT, nullptr, db2, CH, KSIG, 0);
  // edges
  k_edge<<<EDGES / 256, b256, 0, stream>>>(info, msk, sigT, aij, counts);
  k_scan1<<<NP / 256, b256, 0, stream>>>(counts, offsets, bsum);
  k_scan2<<<1, b256, 0, stream>>>(bsum, boff);
  k_scan3<<<NP / 256, b256, 0, stream>>>(offsets, boff, cursor);
  k_scatter<<<EDGES / 256, b256, 0, stream>>>(info, cursor, sorted);
  // Xtr -> slotD (img2 dead)
  k_agg<<<NP / 4, b256, 0, stream>>>(offsets, sorted, aij, info, bfB, slotD);
  k_colstats<<<288, b256, 0, stream>>>(slotD, sumT, sqT);
  // img4 -> slotC (h dead)
  k_mkimg4<<<dim3(CH / 32, NP / 32), b256, 0, stream>>>(slotA, slotD, sumT, sqT, bng, bnb, slotC);
  // ffn2 grouped 3x3 -> raw4bf (slotB+slotA; Xn fp32 dead)
  k_conv3x4<<<dim3(48, CH), b256, 0, stream>>>(slotC, f2w0, raw4bf);
  k_stats_bf<<<1024, b256, 0, stream>>>(raw4bf, sum4, sq4);
  k_cvtT_bf<<<dim3(NP / 64, 32), b256, 0, stream>>>(raw4bf, bfT1024, sum4, sq4, f2g0, f2b0, 1024);
  // ffn2 1x1 -> raw5 bf16 (slotD; Xtr dead)
  k_mgemm<<<dim3(NP / 128, 2), b256, 0, stream>>>(bfW + 360448, bfT1024, nullptr, raw5bf, nullptr, 1024, CH, 0);
  k_stats_bf<<<CH, b256, 0, stream>>>(raw5bf, sum5, sq5);
  k_final<<<dim3(NP / 32, CH / 32), b256, 0, stream>>>(raw5bf, slotC, sum5, sq5, f2g1, f2b1, out);
}

// Round 7
// 648.265 us; speedup vs baseline: 1.6806x; 1.0437x over previous
//
#include <hip/hip_runtime.h>
#include <cstddef>

#define HW 192
#define NP 36864          // H*W
#define CH 256
#define EDGES 294912
#define KSIG 289
#define SLOPE 0.01f
#define BNEPS 1e-5f
#define PADW 208          // padded image row (192 + 2*8)
#define PADSZ (PADW * PADW)   // 43264 u16 per channel

typedef unsigned short u16;
typedef __attribute__((ext_vector_type(8))) short bf16x8;
typedef __attribute__((ext_vector_type(4))) float f32x4;

__device__ __forceinline__ float leaky(float x) { return x >= 0.f ? x : SLOPE * x; }
__device__ __forceinline__ u16 f2bf(float x) {
  unsigned u = __float_as_uint(x);
  unsigned r = (u + 0x7fffu + ((u >> 16) & 1u)) >> 16;
  return (u16)r;
}
__device__ __forceinline__ float bf2f(unsigned h) { return __uint_as_float(h << 16); }
__device__ __forceinline__ void bnss(const float* sums, const float* sqs,
                                     const float* g, const float* b, int k,
                                     float& s, float& h) {
  float mean = sums[k] * (1.f / NP);
  float var = sqs[k] * (1.f / NP) - mean * mean;
  s = g[k] * rsqrtf(var + BNEPS);
  h = b[k] - mean * s;
}

// ---- img = X^T (fp32 CxN) + padded leaky bf16 image (borders pre-zeroed) ------
__global__ __launch_bounds__(256) void k_transpose_pad(const float* __restrict__ src,
                                                       float* __restrict__ dst,
                                                       u16* __restrict__ pad) {
  __shared__ float tile[32][33];
  int s0 = blockIdx.x * 32, r0 = blockIdx.y * 32;   // s0 = channel, r0 = node
  int tx = threadIdx.x & 31, ty = threadIdx.x >> 5;
#pragma unroll
  for (int j = 0; j < 4; j++)
    tile[ty + 8 * j][tx] = src[(size_t)(r0 + ty + 8 * j) * CH + s0 + tx];
  __syncthreads();
  int n = r0 + tx;
  int y = n / HW, x = n - y * HW;
#pragma unroll
  for (int j = 0; j < 4; j++) {
    int c = s0 + ty + 8 * j;
    float v = tile[tx][ty + 8 * j];
    dst[(size_t)c * NP + n] = v;
    pad[(size_t)c * PADSZ + (y + 8) * PADW + x + 8] = f2bf(leaky(v));
  }
}

// ---- global Toeplitz build: Tg[c][ky][n][k] = w[c][ky][k-n] (bf16) ------------
__global__ __launch_bounds__(256) void k_mkT(const float* __restrict__ w,
                                             u16* __restrict__ Tg) {
  int c = blockIdx.x;
  const float* wc = w + c * 289;
  u16* tc = Tg + (size_t)c * 8704;
  for (int i = threadIdx.x; i < 8704; i += 256) {
    int ky = i >> 9, rem = i & 511, n = rem >> 5, k = rem & 31;
    int kx = k - n;
    float v = (kx >= 0 && kx < 17) ? wc[ky * 17 + kx] : 0.f;
    tc[i] = f2bf(v);
  }
}

// ---------------- weight fp32 -> bf16 converter (dw2 zero-padded to 384 rows) --
__global__ __launch_bounds__(256) void k_cvtW(const float* __restrict__ pw1,
                                              const float* __restrict__ f1w0,
                                              const float* __restrict__ f1w1,
                                              const float* __restrict__ dw1,
                                              const float* __restrict__ dw2,
                                              const float* __restrict__ f2w1,
                                              u16* __restrict__ out) {
  int i = blockIdx.x * 256 + threadIdx.x;   // 0..622591
  float v;
  if (i < 65536) v = pw1[i];
  else if (i < 131072) v = f1w0[i - 65536];
  else if (i < 196608) v = f1w1[i - 131072];
  else if (i < 262144) v = dw1[i - 196608];
  else if (i < 360448) { int j = i - 262144; v = (j < KSIG * 256) ? dw2[j] : 0.f; }
  else v = f2w1[i - 360448];
  out[i] = f2bf(v);
}

// ---------------- per-row stats, bf16 input (one block per row) ----------------
__global__ __launch_bounds__(256) void k_stats_bf(const u16* __restrict__ Xr,
                                                  float* __restrict__ sums,
                                                  float* __restrict__ sqs) {
  int row = blockIdx.x;
  int t = threadIdx.x;
  const uint4* p = (const uint4*)(Xr + (size_t)row * NP);
  float s = 0.f, q = 0.f;
  for (int i = t; i < NP / 8; i += 256) {
    uint4 v = p[i];
    unsigned w[4] = {v.x, v.y, v.z, v.w};
#pragma unroll
    for (int j = 0; j < 4; j++) {
      float a = bf2f(w[j] & 0xffffu), c = bf2f(w[j] >> 16);
      s += a + c; q += a * a + c * c;
    }
  }
  __shared__ float ss[256], qq[256];
  ss[t] = s; qq[t] = q;
  __syncthreads();
  for (int d = 128; d > 0; d >>= 1) {
    if (t < d) { ss[t] += ss[t + d]; qq[t] += qq[t + d]; }
    __syncthreads();
  }
  if (t == 0) { sums[row] = ss[0]; sqs[row] = qq[0]; }
}

// ---- fp32 (M x NP) -> bf16 transposed (NP x M), identity ----------------------
__global__ __launch_bounds__(256) void k_cvtT(const float* __restrict__ in,
                                              u16* __restrict__ outT, int M) {
  __shared__ float tile[32][65];
  int n0 = blockIdx.x * 64, k0 = blockIdx.y * 32;
  int t = threadIdx.x;
#pragma unroll
  for (int i = 0; i < 2; i++) {
    int ci = i * 256 + t;
    int k = ci >> 4, cg = (ci & 15) * 4;
    float4 v = *(const float4*)&in[(size_t)(k0 + k) * NP + n0 + cg];
    tile[k][cg] = v.x; tile[k][cg + 1] = v.y; tile[k][cg + 2] = v.z; tile[k][cg + 3] = v.w;
  }
  __syncthreads();
  int n = t >> 2, kg = (t & 3) * 8;
  uint4 o;
  o.x = (unsigned)f2bf(tile[kg + 0][n]) | ((unsigned)f2bf(tile[kg + 1][n]) << 16);
  o.y = (unsigned)f2bf(tile[kg + 2][n]) | ((unsigned)f2bf(tile[kg + 3][n]) << 16);
  o.z = (unsigned)f2bf(tile[kg + 4][n]) | ((unsigned)f2bf(tile[kg + 5][n]) << 16);
  o.w = (unsigned)f2bf(tile[kg + 6][n]) | ((unsigned)f2bf(tile[kg + 7][n]) << 16);
  *(uint4*)&outT[(size_t)(n0 + n) * M + k0 + kg] = o;
}

// ---- bf16 (M x NP) -> bf16 transposed (NP x M), leaky(bn(x)) inline -----------
__global__ __launch_bounds__(256) void k_cvtT_bf(const u16* __restrict__ in,
                                                 u16* __restrict__ outT,
                                                 const float* __restrict__ sums,
                                                 const float* __restrict__ sqs,
                                                 const float* __restrict__ g,
                                                 const float* __restrict__ b, int M) {
  __shared__ float tile[32][65];
  int n0 = blockIdx.x * 64, k0 = blockIdx.y * 32;
  int t = threadIdx.x;
  int k = t >> 3, cg = (t & 7) * 8;
  float s, h; bnss(sums, sqs, g, b, k0 + k, s, h);
  uint4 v = *(const uint4*)&in[(size_t)(k0 + k) * NP + n0 + cg];
  unsigned w[4] = {v.x, v.y, v.z, v.w};
#pragma unroll
  for (int j = 0; j < 4; j++) {
    tile[k][cg + 2 * j]     = leaky(fmaf(bf2f(w[j] & 0xffffu), s, h));
    tile[k][cg + 2 * j + 1] = leaky(fmaf(bf2f(w[j] >> 16), s, h));
  }
  __syncthreads();
  int n = t >> 2, kg = (t & 3) * 8;
  uint4 o;
  o.x = (unsigned)f2bf(tile[kg + 0][n]) | ((unsigned)f2bf(tile[kg + 1][n]) << 16);
  o.y = (unsigned)f2bf(tile[kg + 2][n]) | ((unsigned)f2bf(tile[kg + 3][n]) << 16);
  o.z = (unsigned)f2bf(tile[kg + 4][n]) | ((unsigned)f2bf(tile[kg + 5][n]) << 16);
  o.w = (unsigned)f2bf(tile[kg + 6][n]) | ((unsigned)f2bf(tile[kg + 7][n]) << 16);
  *(uint4*)&outT[(size_t)(n0 + n) * M + k0 + kg] = o;
}

// ---- fuse1: img2 = img + bn(raw1 bf16); img2 fp32 (CxN) + leaky(img2) bf16 T --
__global__ __launch_bounds__(256) void k_fuse1(const float* __restrict__ base,
                                               const u16* __restrict__ raw,
                                               const float* __restrict__ sums,
                                               const float* __restrict__ sqs,
                                               const float* __restrict__ g,
                                               const float* __restrict__ b,
                                               float* __restrict__ img2,
                                               u16* __restrict__ outT) {
  __shared__ float tile[32][65];
  int n0 = blockIdx.x * 64, k0 = blockIdx.y * 32;
  int t = threadIdx.x;
#pragma unroll
  for (int i = 0; i < 2; i++) {
    int ci = i * 256 + t;
    int k = ci >> 4, cg = (ci & 15) * 4;
    float s, h; bnss(sums, sqs, g, b, k0 + k, s, h);
    size_t idx = (size_t)(k0 + k) * NP + n0 + cg;
    float4 bv = *(const float4*)&base[idx];
    uint2 rv = *(const uint2*)&raw[idx];
    float r0 = bf2f(rv.x & 0xffffu), r1 = bf2f(rv.x >> 16);
    float r2 = bf2f(rv.y & 0xffffu), r3 = bf2f(rv.y >> 16);
    float4 o;
    o.x = bv.x + fmaf(r0, s, h); o.y = bv.y + fmaf(r1, s, h);
    o.z = bv.z + fmaf(r2, s, h); o.w = bv.w + fmaf(r3, s, h);
    *(float4*)&img2[idx] = o;
    tile[k][cg]     = leaky(o.x);
    tile[k][cg + 1] = leaky(o.y);
    tile[k][cg + 2] = leaky(o.z);
    tile[k][cg + 3] = leaky(o.w);
  }
  __syncthreads();
  int n = t >> 2, kg = (t & 3) * 8;
  uint4 o;
  o.x = (unsigned)f2bf(tile[kg + 0][n]) | ((unsigned)f2bf(tile[kg + 1][n]) << 16);
  o.y = (unsigned)f2bf(tile[kg + 2][n]) | ((unsigned)f2bf(tile[kg + 3][n]) << 16);
  o.z = (unsigned)f2bf(tile[kg + 4][n]) | ((unsigned)f2bf(tile[kg + 5][n]) << 16);
  o.w = (unsigned)f2bf(tile[kg + 6][n]) | ((unsigned)f2bf(tile[kg + 7][n]) << 16);
  *(uint4*)&outT[(size_t)(n0 + n) * CH + k0 + kg] = o;
}

// ---- fuse2: Xn = img2 + bn(raw3 bf16); Xn fp32 (NxC) + Xn bf16 (NxC) ----------
__global__ __launch_bounds__(256) void k_fuse2(const float* __restrict__ base,
                                               const u16* __restrict__ raw,
                                               const float* __restrict__ sums,
                                               const float* __restrict__ sqs,
                                               const float* __restrict__ g,
                                               const float* __restrict__ b,
                                               float* __restrict__ XnT,
                                               u16* __restrict__ outT) {
  __shared__ float tile[32][65];
  int n0 = blockIdx.x * 64, k0 = blockIdx.y * 32;
  int t = threadIdx.x;
#pragma unroll
  for (int i = 0; i < 2; i++) {
    int ci = i * 256 + t;
    int k = ci >> 4, cg = (ci & 15) * 4;
    float s, h; bnss(sums, sqs, g, b, k0 + k, s, h);
    size_t idx = (size_t)(k0 + k) * NP + n0 + cg;
    float4 bv = *(const float4*)&base[idx];
    uint2 rv = *(const uint2*)&raw[idx];
    float r0 = bf2f(rv.x & 0xffffu), r1 = bf2f(rv.x >> 16);
    float r2 = bf2f(rv.y & 0xffffu), r3 = bf2f(rv.y >> 16);
    tile[k][cg]     = bv.x + fmaf(r0, s, h);
    tile[k][cg + 1] = bv.y + fmaf(r1, s, h);
    tile[k][cg + 2] = bv.z + fmaf(r2, s, h);
    tile[k][cg + 3] = bv.w + fmaf(r3, s, h);
  }
  __syncthreads();
  int n = t >> 2, kg = (t & 3) * 8;
  float4 f0 = {tile[kg + 0][n], tile[kg + 1][n], tile[kg + 2][n], tile[kg + 3][n]};
  float4 f1 = {tile[kg + 4][n], tile[kg + 5][n], tile[kg + 6][n], tile[kg + 7][n]};
  *(float4*)&XnT[(size_t)(n0 + n) * CH + k0 + kg] = f0;
  *(float4*)&XnT[(size_t)(n0 + n) * CH + k0 + kg + 4] = f1;
  uint4 o;
  o.x = (unsigned)f2bf(f0.x) | ((unsigned)f2bf(f0.y) << 16);
  o.y = (unsigned)f2bf(f0.z) | ((unsigned)f2bf(f0.w) << 16);
  o.z = (unsigned)f2bf(f1.x) | ((unsigned)f2bf(f1.y) << 16);
  o.w = (unsigned)f2bf(f1.z) | ((unsigned)f2bf(f1.w) << 16);
  *(uint4*)&outT[(size_t)(n0 + n) * CH + k0 + kg] = o;
}

// ---------------- MFMA GEMM: Out = A(M x K) @ Bt(NP x K)^T; fp32 or bf16 out ---
__global__ __launch_bounds__(256) void k_mgemm(const u16* __restrict__ A,
                                               const u16* __restrict__ Bt,
                                               float* __restrict__ Outf,
                                               u16* __restrict__ Outb,
                                               const float* __restrict__ bias,
                                               int K, int Mstore, int actout) {
  __shared__ u16 As[128 * 32];
  __shared__ u16 Bs[128 * 32];
  int t = threadIdx.x;
  int lane = t & 63, wave = t >> 6;
  int wm = (wave >> 1) * 64, wn = (wave & 1) * 64;
  int m0 = blockIdx.y * 128, n0 = blockIdx.x * 128;
  int r = lane & 15, q = lane >> 4;
  f32x4 acc[4][4];
#pragma unroll
  for (int a = 0; a < 4; a++)
#pragma unroll
    for (int b = 0; b < 4; b++) acc[a][b] = (f32x4){0.f, 0.f, 0.f, 0.f};

  for (int k0 = 0; k0 < K; k0 += 32) {
#pragma unroll
    for (int i = 0; i < 2; i++) {
      int cc = t + i * 256;
      int mm = cc >> 2, kq = (cc & 3) * 8;
      uint4 av = *(const uint4*)&A[(size_t)(m0 + mm) * K + k0 + kq];
      uint4 bv = *(const uint4*)&Bt[(size_t)(n0 + mm) * K + k0 + kq];
      *(uint4*)&As[mm * 32 + kq] = av;
      *(uint4*)&Bs[mm * 32 + kq] = bv;
    }
    __syncthreads();
    bf16x8 af[4], bfr[4];
#pragma unroll
    for (int mt = 0; mt < 4; mt++)
      af[mt] = *(const bf16x8*)&As[(wm + mt * 16 + r) * 32 + q * 8];
#pragma unroll
    for (int nt = 0; nt < 4; nt++)
      bfr[nt] = *(const bf16x8*)&Bs[(wn + nt * 16 + r) * 32 + q * 8];
#pragma unroll
    for (int mt = 0; mt < 4; mt++)
#pragma unroll
      for (int nt = 0; nt < 4; nt++)
        acc[mt][nt] = __builtin_amdgcn_mfma_f32_16x16x32_bf16(af[mt], bfr[nt], acc[mt][nt], 0, 0, 0);
    __syncthreads();
  }
#pragma unroll
  for (int mt = 0; mt < 4; mt++) {
    int mrow = m0 + wm + mt * 16 + q * 4;
#pragma unroll
    for (int i = 0; i < 4; i++) {
      int m = mrow + i;
      if (m >= Mstore) continue;
      float bs = bias ? bias[m] : 0.f;
#pragma unroll
      for (int nt = 0; nt < 4; nt++) {
        float v = acc[mt][nt][i] + bs;
        if (actout) v = leaky(v);
        size_t oi = (size_t)m * NP + n0 + wn + nt * 16 + r;
        if (Outb) Outb[oi] = f2bf(v); else Outf[oi] = v;
      }
    }
  }
}

// ---------------- depthwise 17x17 conv via MFMA, padded bf16 input -------------
__global__ __launch_bounds__(256) void k_dwconv17(const u16* __restrict__ pad,
                                                  const u16* __restrict__ Tg,
                                                  u16* __restrict__ outb) {
  int c = blockIdx.y;
  int tile = blockIdx.x;                  // 0..8
  int ty0 = (tile / 3) * 64, tx0 = (tile % 3) * 64;
  __shared__ u16 smIn[80 * 88];
  __shared__ u16 smT[17 * 16 * 40];
  const u16* pc = pad + (size_t)c * PADSZ;
  for (int cc = threadIdx.x; cc < 800; cc += 256) {
    int rr = cc / 10, j = cc - rr * 10;
    uint4 v = *(const uint4*)(pc + (ty0 + rr) * PADW + tx0 + j * 8);
    *(uint4*)(smIn + rr * 88 + j * 8) = v;
  }
  const u16* tc = Tg + (size_t)c * 8704;
  for (int cc = threadIdx.x; cc < 1088; cc += 256) {
    int rr = cc >> 2, j = cc & 3;
    uint4 v = *(const uint4*)(tc + rr * 32 + j * 8);
    *(uint4*)(smT + rr * 40 + j * 8) = v;
  }
  __syncthreads();
  int lane = threadIdx.x & 63, wave = threadIdx.x >> 6;
  int wy = wave * 16;
  int r = lane & 15, q = lane >> 4;
  f32x4 acc[4];
#pragma unroll
  for (int xt = 0; xt < 4; xt++) acc[xt] = (f32x4){0.f, 0.f, 0.f, 0.f};
#pragma unroll
  for (int ky = 0; ky < 17; ky++) {
    bf16x8 bfrag = *(const bf16x8*)&smT[(ky * 16 + r) * 40 + q * 8];
    int rowA = wy + r + ky;
#pragma unroll
    for (int xt = 0; xt < 4; xt++) {
      bf16x8 afrag = *(const bf16x8*)&smIn[rowA * 88 + xt * 16 + q * 8];
      acc[xt] = __builtin_amdgcn_mfma_f32_16x16x32_bf16(afrag, bfrag, acc[xt], 0, 0, 0);
    }
  }
  u16* oc = outb + (size_t)c * NP;
#pragma unroll
  for (int xt = 0; xt < 4; xt++) {
    int x = tx0 + xt * 16 + r;
#pragma unroll
    for (int i = 0; i < 4; i++) {
      int y = ty0 + wy + q * 4 + i;
      oc[y * HW + x] = f2bf(acc[xt][i]);
    }
  }
}

// ---------------- grouped 3x3 conv, row-sliding, no LDS, no barrier ------------
__global__ __launch_bounds__(256) void k_conv3x4(const float* __restrict__ in,
                                                 const float* __restrict__ w,
                                                 u16* __restrict__ out) {
  int wave = threadIdx.x >> 6, lane = threadIdx.x & 63;
  int c = blockIdx.y;
  int y = blockIdx.x * 4 + wave;
  const float* wc = w + (size_t)(4 * c) * 9;
  float wr[36];
#pragma unroll
  for (int k = 0; k < 36; k++) wr[k] = wc[k];
  float acc[4][3];
#pragma unroll
  for (int oc = 0; oc < 4; oc++)
#pragma unroll
    for (int s = 0; s < 3; s++) acc[oc][s] = 0.f;
  const float* base = in + (size_t)c * NP;
#pragma unroll
  for (int ky = 0; ky < 3; ky++) {
    int ry = y + ky - 1;
    if (ry < 0 || ry >= HW) continue;
    const float* rp = base + ry * HW;
    float a0 = leaky(rp[lane]);
    float a1 = leaky(rp[64 + lane]);
    float a2 = leaky(rp[128 + lane]);
    float e0 = __shfl(a0, 63), e1 = __shfl(a1, 63);
    float b1 = __shfl(a1, 0),  b2 = __shfl(a2, 0);
    float l0 = __shfl_up(a0, 1); if (lane == 0) l0 = 0.f;
    float l1 = __shfl_up(a1, 1); if (lane == 0) l1 = e0;
    float l2 = __shfl_up(a2, 1); if (lane == 0) l2 = e1;
    float r0 = __shfl_down(a0, 1); if (lane == 63) r0 = b1;
    float r1 = __shfl_down(a1, 1); if (lane == 63) r1 = b2;
    float r2 = __shfl_down(a2, 1); if (lane == 63) r2 = 0.f;
#pragma unroll
    for (int oc = 0; oc < 4; oc++) {
      float w0 = wr[oc * 9 + ky * 3], w1 = wr[oc * 9 + ky * 3 + 1], w2 = wr[oc * 9 + ky * 3 + 2];
      acc[oc][0] = fmaf(w0, l0, fmaf(w1, a0, fmaf(w2, r0, acc[oc][0])));
      acc[oc][1] = fmaf(w0, l1, fmaf(w1, a1, fmaf(w2, r1, acc[oc][1])));
      acc[oc][2] = fmaf(w0, l2, fmaf(w1, a2, fmaf(w2, r2, acc[oc][2])));
    }
  }
  size_t ob = (size_t)(4 * c) * NP + (size_t)y * HW + lane;
#pragma unroll
  for (int oc = 0; oc < 4; oc++) {
    out[ob + (size_t)oc * NP]       = f2bf(acc[oc][0]);
    out[ob + (size_t)oc * NP + 64]  = f2bf(acc[oc][1]);
    out[ob + (size_t)oc * NP + 128] = f2bf(acc[oc][2]);
  }
}

// ---------------- edge scores + dst histogram ----------------------------------
__global__ __launch_bounds__(256) void k_edge(const int* __restrict__ info,
                                              const float* __restrict__ msk,
                                              const float* __restrict__ sig,
                                              float* __restrict__ aij,
                                              int* __restrict__ counts) {
  int e = blockIdx.x * 256 + threadIdx.x;
  int4 ii = ((const int4*)info)[e];
  float s = sig[(size_t)ii.y * NP + ii.x] + sig[(size_t)ii.w * NP + ii.z];
  s = fminf(fmaxf(s, -5.f), 5.f);
  aij[e] = expf(s) * msk[e];
  atomicAdd(&counts[ii.z], 1);
}

// ---------------- counting-sort by dst -----------------------------------------
__global__ __launch_bounds__(256) void k_scan1(const int* __restrict__ counts,
                                               int* __restrict__ offsets,
                                               int* __restrict__ bsum) {
  __shared__ int sm[256];
  int t = threadIdx.x;
  int i = blockIdx.x * 256 + t;
  int v = counts[i];
  sm[t] = v;
  __syncthreads();
  for (int d = 1; d < 256; d <<= 1) {
    int add = (t >= d) ? sm[t - d] : 0;
    __syncthreads();
    sm[t] += add;
    __syncthreads();
  }
  offsets[i] = sm[t] - v;
  if (t == 255) bsum[blockIdx.x] = sm[255];
}
__global__ __launch_bounds__(256) void k_scan2(const int* __restrict__ bsum,
                                               int* __restrict__ boff) {
  __shared__ int sm[256];
  int t = threadIdx.x;
  int v = (t < 144) ? bsum[t] : 0;
  sm[t] = v;
  __syncthreads();
  for (int d = 1; d < 256; d <<= 1) {
    int add = (t >= d) ? sm[t - d] : 0;
    __syncthreads();
    sm[t] += add;
    __syncthreads();
  }
  boff[t] = sm[t] - v;
}
__global__ __launch_bounds__(256) void k_scan3(int* __restrict__ offsets,
                                               const int* __restrict__ boff,
                                               int* __restrict__ cursor) {
  int i = blockIdx.x * 256 + threadIdx.x;
  int o = offsets[i] + boff[blockIdx.x];
  offsets[i] = o;
  cursor[i] = o;
  if (i == 0) offsets[NP] = EDGES;
}
// scatter (src, aij) pre-sorted by dst: kills the e-indirection in k_agg
__global__ __launch_bounds__(256) void k_scatter(const int* __restrict__ info,
                                                 const float* __restrict__ aij,
                                                 int* __restrict__ cursor,
                                                 int* __restrict__ srcs,
                                                 float* __restrict__ aijw) {
  int e = blockIdx.x * 256 + threadIdx.x;
  int4 ii = ((const int4*)info)[e];
  int pos = atomicAdd(&cursor[ii.z], 1);
  srcs[pos] = ii.x;
  aijw[pos] = aij[e];
}

// ---------------- per-node aggregation: half-wave per edge stream --------------
// 32 lanes x uint4 (8 bf16 ch) cover 256 ch; halves process alternating edges,
// manual 2x unroll -> 4 gathers in flight; combine via shfl_xor(32); bf16 out.
__global__ __launch_bounds__(256) void k_agg(const int* __restrict__ offsets,
                                             const int* __restrict__ srcs,
                                             const float* __restrict__ aijw,
                                             const u16* __restrict__ XnBf,
                                             u16* __restrict__ XtrBf) {
  int wave = threadIdx.x >> 6, lane = threadIdx.x & 63;
  int node = blockIdx.x * 4 + wave;
  int o0 = offsets[node], o1 = offsets[node + 1];
  int half = lane >> 5, l32 = lane & 31;
  float acc[8] = {0.f, 0.f, 0.f, 0.f, 0.f, 0.f, 0.f, 0.f};
  float asum = 0.f;
  int i = o0 + half;
  for (; i + 2 < o1; i += 4) {
    int s0 = srcs[i], s1 = srcs[i + 2];
    float a0 = aijw[i], a1 = aijw[i + 2];
    uint4 v0 = ((const uint4*)(XnBf + (size_t)s0 * CH))[l32];
    uint4 v1 = ((const uint4*)(XnBf + (size_t)s1 * CH))[l32];
    unsigned w0[4] = {v0.x, v0.y, v0.z, v0.w};
    unsigned w1[4] = {v1.x, v1.y, v1.z, v1.w};
#pragma unroll
    for (int j = 0; j < 4; j++) {
      acc[2 * j]     = fmaf(a0, bf2f(w0[j] & 0xffffu), acc[2 * j]);
      acc[2 * j + 1] = fmaf(a0, bf2f(w0[j] >> 16),     acc[2 * j + 1]);
      acc[2 * j]     = fmaf(a1, bf2f(w1[j] & 0xffffu), acc[2 * j]);
      acc[2 * j + 1] = fmaf(a1, bf2f(w1[j] >> 16),     acc[2 * j + 1]);
    }
    asum += a0 + a1;
  }
  for (; i < o1; i += 2) {
    int s = srcs[i];
    float a = aijw[i];
    uint4 v = ((const uint4*)(XnBf + (size_t)s * CH))[l32];
    unsigned w[4] = {v.x, v.y, v.z, v.w};
#pragma unroll
    for (int j = 0; j < 4; j++) {
      acc[2 * j]     = fmaf(a, bf2f(w[j] & 0xffffu), acc[2 * j]);
      acc[2 * j + 1] = fmaf(a, bf2f(w[j] >> 16),     acc[2 * j + 1]);
    }
    asum += a;
  }
#pragma unroll
  for (int j = 0; j < 8; j++) acc[j] += __shfl_xor(acc[j], 32, 64);
  asum += __shfl_xor(asum, 32, 64);
  if (half == 0) {
    float inv = 1.f / (asum + 1e-5f);
    uint4 o;
    o.x = (unsigned)f2bf(acc[0] * inv) | ((unsigned)f2bf(acc[1] * inv) << 16);
    o.y = (unsigned)f2bf(acc[2] * inv) | ((unsigned)f2bf(acc[3] * inv) << 16);
    o.z = (unsigned)f2bf(acc[4] * inv) | ((unsigned)f2bf(acc[5] * inv) << 16);
    o.w = (unsigned)f2bf(acc[6] * inv) | ((unsigned)f2bf(acc[7] * inv) << 16);
    ((uint4*)(XtrBf + (size_t)node * CH))[l32] = o;
  }
}

// ---------------- bn1d stats (bf16 input) --------------------------------------
__global__ __launch_bounds__(256) void k_colstats(const u16* __restrict__ Xt,
                                                  float* __restrict__ sums,
                                                  float* __restrict__ sqs) {
  int c = threadIdx.x;
  float s = 0.f, q = 0.f;
  for (int n = blockIdx.x; n < NP; n += gridDim.x) {
    float v = bf2f(Xt[(size_t)n * CH + c]);
    s += v; q += v * v;
  }
  atomicAdd(&sums[c], s);
  atomicAdd(&sqs[c], q);
}

// ---------------- img4 = transpose(Xn + bn1d(Xtr bf16))  (N x C -> C x N) ------
__global__ __launch_bounds__(256) void k_mkimg4(const float* __restrict__ Xn,
                                                const u16* __restrict__ XtrBf,
                                                const float* __restrict__ sums,
                                                const float* __restrict__ sqs,
                                                const float* __restrict__ g,
                                                const float* __restrict__ b,
                                                float* __restrict__ img4) {
  __shared__ float tile[32][33];
  int c0 = blockIdx.x * 32, n0 = blockIdx.y * 32;
  int tx = threadIdx.x & 31, ty = threadIdx.x >> 5;
  int c = c0 + tx;
  float s, h; bnss(sums, sqs, g, b, c, s, h);
#pragma unroll
  for (int j = 0; j < 4; j++) {
    size_t idx = (size_t)(n0 + ty + 8 * j) * CH + c;
    tile[ty + 8 * j][tx] = Xn[idx] + fmaf(bf2f(XtrBf[idx]), s, h);
  }
  __syncthreads();
#pragma unroll
  for (int j = 0; j < 4; j++) {
    int cc = c0 + ty + 8 * j;
    img4[(size_t)cc * NP + n0 + tx] = tile[tx][ty + 8 * j];
  }
}

// ---------------- out(N x C) = transpose(bn(raw5 bf16) + img4) -----------------
__global__ __launch_bounds__(256) void k_final(const u16* __restrict__ raw5,
                                               const float* __restrict__ img4,
                                               const float* __restrict__ sums,
                                               const float* __restrict__ sqs,
                                               const float* __restrict__ g,
                                               const float* __restrict__ b,
                                               float* __restrict__ out) {
  __shared__ float tile[32][33];
  int n0 = blockIdx.x * 32, c0 = blockIdx.y * 32;
  int tx = threadIdx.x & 31, ty = threadIdx.x >> 5;
#pragma unroll
  for (int j = 0; j < 4; j++) {
    int c = c0 + ty + 8 * j;
    float s, h; bnss(sums, sqs, g, b, c, s, h);
    size_t idx = (size_t)c * NP + n0 + tx;
    tile[ty + 8 * j][tx] = fmaf(bf2f(raw5[idx]), s, h) + img4[idx];
  }
  __syncthreads();
#pragma unroll
  for (int j = 0; j < 4; j++) {
    int n = n0 + ty + 8 * j;
    out[(size_t)n * CH + c0 + tx] = tile[tx][ty + 8 * j];
  }
}

extern "C" void kernel_launch(void* const* d_in, const int* in_sizes, int n_in,
                              void* d_out, int out_size, void* d_ws, size_t ws_size,
                              hipStream_t stream) {
  (void)in_sizes; (void)n_in; (void)out_size; (void)ws_size;
  const float* X    = (const float*)d_in[0];
  const int*   info = (const int*)d_in[1];
  const float* msk  = (const float*)d_in[2];
  const float* pw0  = (const float*)d_in[3];
  const float* pg0  = (const float*)d_in[4];
  const float* pb0  = (const float*)d_in[5];
  const float* pw1  = (const float*)d_in[6];
  const float* pg1  = (const float*)d_in[7];
  const float* pb1  = (const float*)d_in[8];
  const float* f1w0 = (const float*)d_in[9];
  const float* f1g0 = (const float*)d_in[10];
  const float* f1b0 = (const float*)d_in[11];
  const float* f1w1 = (const float*)d_in[12];
  const float* f1g1 = (const float*)d_in[13];
  const float* f1b1 = (const float*)d_in[14];
  const float* dw1  = (const float*)d_in[15];
  const float* db1  = (const float*)d_in[16];
  const float* dw2  = (const float*)d_in[17];
  const float* db2  = (const float*)d_in[18];
  const float* bng  = (const float*)d_in[19];
  const float* bnb  = (const float*)d_in[20];
  const float* f2w0 = (const float*)d_in[21];
  const float* f2g0 = (const float*)d_in[22];
  const float* f2b0 = (const float*)d_in[23];
  const float* f2w1 = (const float*)d_in[24];
  const float* f2g1 = (const float*)d_in[25];
  const float* f2b1 = (const float*)d_in[26];
  float* out = (float*)d_out;

  float* ws = (float*)d_ws;
  float* sum0 = ws + 0;    float* sq0 = ws + 256;
  float* sum1 = ws + 512;  float* sq1 = ws + 768;
  float* sum2 = ws + 1024; float* sq2 = ws + 1280;
  float* sum3 = ws + 1536; float* sq3 = ws + 1792;
  float* sum5 = ws + 2048; float* sq5 = ws + 2304;
  float* sumT = ws + 2560; float* sqT = ws + 2816;   // atomic targets, zeroed
  float* sum4 = ws + 3072; float* sq4 = ws + 4096;   // 1024 each
  int* counts  = (int*)(ws + 8192);
  int* offsets = (int*)(ws + 45056);
  int* cursor  = (int*)(ws + 82176);
  int* bsum    = (int*)(ws + 119296);
  int* boff    = (int*)(ws + 119552);
  int* srcs    = (int*)(ws + 131072);      // EDGES (was 'sorted')
  float* aij   = ws + 425984;              // EDGES (unsorted)
  const size_t S = (size_t)NP * CH;        // 9437184 words
  float* slotD = ws + 720896;
  float* slotB = slotD + S;
  float* slotA = slotB + S;
  float* slotC = slotA + S;
  u16* bfB  = (u16*)(slotC + S);           // NP x 256 bf16
  u16* bfH  = bfB + S;                     // raw0/raw1/raw2/raw3/h-bf16
  float* sigT = (float*)(bfH + S);         // KSIG x NP fp32
  u16* bfW  = (u16*)(sigT + (size_t)KSIG * NP);
  float* aijw = (float*)(bfW + 622592);    // EDGES, sorted by dst
  // early-phase aliases into dead fp32 slots:
  u16* Ppad = (u16*)slotC;                 // 256ch x 208x208 bf16 padded leaky img
  u16* Tg   = (u16*)slotD;                 // 256 x 8704 Toeplitz
  u16* raw4bf  = (u16*)slotB;              // 1024 x NP bf16, spans slotB+slotA
  u16* bfT1024 = bfB;                      // NP x 1024 bf16
  u16* XtrBf   = (u16*)slotD;              // N x C bf16 (img2/Tg dead)
  u16* raw5bf  = (u16*)slotB;              // C x NP bf16 (raw4bf dead after cvtT_bf)

  hipMemsetAsync(ws, 0, 5120 * sizeof(float), stream);
  hipMemsetAsync(counts, 0, NP * sizeof(int), stream);
  hipMemsetAsync(Ppad, 0, (size_t)PADSZ * CH * sizeof(u16), stream);

  dim3 b256(256);
  k_cvtW<<<2432, b256, 0, stream>>>(pw1, f1w0, f1w1, dw1, dw2, f2w1, bfW);
  k_mkT<<<CH, b256, 0, stream>>>(pw0, Tg);
  // img = X^T -> slotA ; padded leaky bf16 -> Ppad
  k_transpose_pad<<<dim3(CH / 32, NP / 32), b256, 0, stream>>>(X, slotA, Ppad);
  // ppm depthwise -> raw0 bf16 (bfH)
  k_dwconv17<<<dim3(9, CH), b256, 0, stream>>>(Ppad, Tg, bfH);
  k_stats_bf<<<CH, b256, 0, stream>>>(bfH, sum0, sq0);
  k_cvtT_bf<<<dim3(NP / 64, 8), b256, 0, stream>>>(bfH, bfB, sum0, sq0, pg0, pb0, CH);
  // ppm 1x1 -> raw1 bf16 (bfH; raw0 dead)
  k_mgemm<<<dim3(NP / 128, 2), b256, 0, stream>>>(bfW, bfB, nullptr, bfH, nullptr, CH, CH, 0);
  k_stats_bf<<<CH, b256, 0, stream>>>(bfH, sum1, sq1);
  // img2 = img + bn(raw1) -> slotD (Tg dead) ; bfB = leaky(img2)^T
  k_fuse1<<<dim3(NP / 64, 8), b256, 0, stream>>>(slotA, bfH, sum1, sq1, pg1, pb1, slotD, bfB);
  // ffn1 conv0 -> raw2 bf16 (bfH)
  k_mgemm<<<dim3(NP / 128, 2), b256, 0, stream>>>(bfW + 65536, bfB, nullptr, bfH, nullptr, CH, CH, 0);
  k_stats_bf<<<CH, b256, 0, stream>>>(bfH, sum2, sq2);
  k_cvtT_bf<<<dim3(NP / 64, 8), b256, 0, stream>>>(bfH, bfB, sum2, sq2, f1g0, f1b0, CH);
  // ffn1 conv1 -> raw3 bf16 (bfH)
  k_mgemm<<<dim3(NP / 128, 2), b256, 0, stream>>>(bfW + 131072, bfB, nullptr, bfH, nullptr, CH, CH, 0);
  k_stats_bf<<<CH, b256, 0, stream>>>(bfH, sum3, sq3);
  // Xn = img2 + bn(raw3): fp32 NxC -> slotA ; bf16 NxC -> bfB
  k_fuse2<<<dim3(NP / 64, 8), b256, 0, stream>>>(slotD, bfH, sum3, sq3, f1g1, f1b1, slotA, bfB);
  // dis: h -> slotC fp32 (Ppad dead), bias + leaky
  k_mgemm<<<dim3(NP / 128, 2), b256, 0, stream>>>(bfW + 196608, bfB, slotC, nullptr, db1, CH, CH, 1);
  k_cvtT<<<dim3(NP / 64, 8), b256, 0, stream>>>(slotC, bfH, CH);   // raw3 dead
  k_mgemm<<<dim3(NP / 128, 3), b256, 0, stream>>>(bfW + 262144, bfH, sigT, nullptr, db2, CH, KSIG, 0);
  // edges
  k_edge<<<EDGES / 256, b256, 0, stream>>>(info, msk, sigT, aij, counts);
  k_scan1<<<NP / 256, b256, 0, stream>>>(counts, offsets, bsum);
  k_scan2<<<1, b256, 0, stream>>>(bsum, boff);
  k_scan3<<<NP / 256, b256, 0, stream>>>(offsets, boff, cursor);
  k_scatter<<<EDGES / 256, b256, 0, stream>>>(info, aij, cursor, srcs, aijw);
  // Xtr bf16 -> XtrBf (slotD; img2 dead)
  k_agg<<<NP / 4, b256, 0, stream>>>(offsets, srcs, aijw, bfB, XtrBf);
  k_colstats<<<288, b256, 0, stream>>>(XtrBf, sumT, sqT);
  // img4 -> slotC (h dead)
  k_mkimg4<<<dim3(CH / 32, NP / 32), b256, 0, stream>>>(slotA, XtrBf, sumT, sqT, bng, bnb, slotC);
  // ffn2 grouped 3x3 -> raw4bf (slotB+slotA; Xn fp32 dead)
  k_conv3x4<<<dim3(48, CH), b256, 0, stream>>>(slotC, f2w0, raw4bf);
  k_stats_bf<<<1024, b256, 0, stream>>>(raw4bf, sum4, sq4);
  k_cvtT_bf<<<dim3(NP / 64, 32), b256, 0, stream>>>(raw4bf, bfT1024, sum4, sq4, f2g0, f2b0, 1024);
  // ffn2 1x1 -> raw5 bf16 (slotB; raw4bf consumed)
  k_mgemm<<<dim3(NP / 128, 2), b256, 0, stream>>>(bfW + 360448, bfT1024, nullptr, raw5bf, nullptr, 1024, CH, 0);
  k_stats_bf<<<CH, b256, 0, stream>>>(raw5bf, sum5, sq5);
  k_final<<<dim3(NP / 32, CH / 32), b256, 0, stream>>>(raw5bf, slotC, sum5, sq5, f2g1, f2b1, out);
}

// Round 8
// 645.177 us; speedup vs baseline: 1.6886x; 1.0048x over previous
//
#include <hip/hip_runtime.h>
#include <cstddef>

#define HW 192
#define NP 36864          // H*W
#define CH 256
#define EDGES 294912
#define KSIG 289
#define SLOPE 0.01f
#define BNEPS 1e-5f
#define PADW 208          // padded image row (192 + 2*8)
#define PADSZ (PADW * PADW)   // 43264 u16 per channel

typedef unsigned short u16;
typedef __attribute__((ext_vector_type(8))) short bf16x8;
typedef __attribute__((ext_vector_type(4))) float f32x4;

__device__ __forceinline__ float leaky(float x) { return x >= 0.f ? x : SLOPE * x; }
__device__ __forceinline__ u16 f2bf(float x) {
  unsigned u = __float_as_uint(x);
  unsigned r = (u + 0x7fffu + ((u >> 16) & 1u)) >> 16;
  return (u16)r;
}
__device__ __forceinline__ float bf2f(unsigned h) { return __uint_as_float(h << 16); }
__device__ __forceinline__ void bnss(const float* sums, const float* sqs,
                                     const float* g, const float* b, int k,
                                     float& s, float& h) {
  float mean = sums[k] * (1.f / NP);
  float var = sqs[k] * (1.f / NP) - mean * mean;
  s = g[k] * rsqrtf(var + BNEPS);
  h = b[k] - mean * s;
}

// ---- img = X^T (fp32 CxN) + padded leaky bf16 image (borders pre-zeroed) ------
__global__ __launch_bounds__(256) void k_transpose_pad(const float* __restrict__ src,
                                                       float* __restrict__ dst,
                                                       u16* __restrict__ pad) {
  __shared__ float tile[32][33];
  int s0 = blockIdx.x * 32, r0 = blockIdx.y * 32;   // s0 = channel, r0 = node
  int tx = threadIdx.x & 31, ty = threadIdx.x >> 5;
#pragma unroll
  for (int j = 0; j < 4; j++)
    tile[ty + 8 * j][tx] = src[(size_t)(r0 + ty + 8 * j) * CH + s0 + tx];
  __syncthreads();
  int n = r0 + tx;
  int y = n / HW, x = n - y * HW;
#pragma unroll
  for (int j = 0; j < 4; j++) {
    int c = s0 + ty + 8 * j;
    float v = tile[tx][ty + 8 * j];
    dst[(size_t)c * NP + n] = v;
    pad[(size_t)c * PADSZ + (y + 8) * PADW + x + 8] = f2bf(leaky(v));
  }
}

// ---- global Toeplitz build: Tg[c][ky][n][k] = w[c][ky][k-n] (bf16) ------------
__global__ __launch_bounds__(256) void k_mkT(const float* __restrict__ w,
                                             u16* __restrict__ Tg) {
  int c = blockIdx.x;
  const float* wc = w + c * 289;
  u16* tc = Tg + (size_t)c * 8704;
  for (int i = threadIdx.x; i < 8704; i += 256) {
    int ky = i >> 9, rem = i & 511, n = rem >> 5, k = rem & 31;
    int kx = k - n;
    float v = (kx >= 0 && kx < 17) ? wc[ky * 17 + kx] : 0.f;
    tc[i] = f2bf(v);
  }
}

// ---------------- weight fp32 -> bf16 converter (dw2 zero-padded to 384 rows) --
__global__ __launch_bounds__(256) void k_cvtW(const float* __restrict__ pw1,
                                              const float* __restrict__ f1w0,
                                              const float* __restrict__ f1w1,
                                              const float* __restrict__ dw1,
                                              const float* __restrict__ dw2,
                                              const float* __restrict__ f2w1,
                                              u16* __restrict__ out) {
  int i = blockIdx.x * 256 + threadIdx.x;   // 0..622591
  float v;
  if (i < 65536) v = pw1[i];
  else if (i < 131072) v = f1w0[i - 65536];
  else if (i < 196608) v = f1w1[i - 131072];
  else if (i < 262144) v = dw1[i - 196608];
  else if (i < 360448) { int j = i - 262144; v = (j < KSIG * 256) ? dw2[j] : 0.f; }
  else v = f2w1[i - 360448];
  out[i] = f2bf(v);
}

// ---------------- per-row stats, bf16 input (one block per row) ----------------
__global__ __launch_bounds__(256) void k_stats_bf(const u16* __restrict__ Xr,
                                                  float* __restrict__ sums,
                                                  float* __restrict__ sqs) {
  int row = blockIdx.x;
  int t = threadIdx.x;
  const uint4* p = (const uint4*)(Xr + (size_t)row * NP);
  float s = 0.f, q = 0.f;
  for (int i = t; i < NP / 8; i += 256) {
    uint4 v = p[i];
    unsigned w[4] = {v.x, v.y, v.z, v.w};
#pragma unroll
    for (int j = 0; j < 4; j++) {
      float a = bf2f(w[j] & 0xffffu), c = bf2f(w[j] >> 16);
      s += a + c; q += a * a + c * c;
    }
  }
  __shared__ float ss[256], qq[256];
  ss[t] = s; qq[t] = q;
  __syncthreads();
  for (int d = 128; d > 0; d >>= 1) {
    if (t < d) { ss[t] += ss[t + d]; qq[t] += qq[t + d]; }
    __syncthreads();
  }
  if (t == 0) { sums[row] = ss[0]; sqs[row] = qq[0]; }
}

// ---- fp32 (M x NP) -> bf16 transposed (NP x M), identity ----------------------
__global__ __launch_bounds__(256) void k_cvtT(const float* __restrict__ in,
                                              u16* __restrict__ outT, int M) {
  __shared__ float tile[32][65];
  int n0 = blockIdx.x * 64, k0 = blockIdx.y * 32;
  int t = threadIdx.x;
#pragma unroll
  for (int i = 0; i < 2; i++) {
    int ci = i * 256 + t;
    int k = ci >> 4, cg = (ci & 15) * 4;
    float4 v = *(const float4*)&in[(size_t)(k0 + k) * NP + n0 + cg];
    tile[k][cg] = v.x; tile[k][cg + 1] = v.y; tile[k][cg + 2] = v.z; tile[k][cg + 3] = v.w;
  }
  __syncthreads();
  int n = t >> 2, kg = (t & 3) * 8;
  uint4 o;
  o.x = (unsigned)f2bf(tile[kg + 0][n]) | ((unsigned)f2bf(tile[kg + 1][n]) << 16);
  o.y = (unsigned)f2bf(tile[kg + 2][n]) | ((unsigned)f2bf(tile[kg + 3][n]) << 16);
  o.z = (unsigned)f2bf(tile[kg + 4][n]) | ((unsigned)f2bf(tile[kg + 5][n]) << 16);
  o.w = (unsigned)f2bf(tile[kg + 6][n]) | ((unsigned)f2bf(tile[kg + 7][n]) << 16);
  *(uint4*)&outT[(size_t)(n0 + n) * M + k0 + kg] = o;
}

// ---- bf16 (M x NP) -> bf16 transposed (NP x M), leaky(bn(x)) inline -----------
__global__ __launch_bounds__(256) void k_cvtT_bf(const u16* __restrict__ in,
                                                 u16* __restrict__ outT,
                                                 const float* __restrict__ sums,
                                                 const float* __restrict__ sqs,
                                                 const float* __restrict__ g,
                                                 const float* __restrict__ b, int M) {
  __shared__ float tile[32][65];
  int n0 = blockIdx.x * 64, k0 = blockIdx.y * 32;
  int t = threadIdx.x;
  int k = t >> 3, cg = (t & 7) * 8;
  float s, h; bnss(sums, sqs, g, b, k0 + k, s, h);
  uint4 v = *(const uint4*)&in[(size_t)(k0 + k) * NP + n0 + cg];
  unsigned w[4] = {v.x, v.y, v.z, v.w};
#pragma unroll
  for (int j = 0; j < 4; j++) {
    tile[k][cg + 2 * j]     = leaky(fmaf(bf2f(w[j] & 0xffffu), s, h));
    tile[k][cg + 2 * j + 1] = leaky(fmaf(bf2f(w[j] >> 16), s, h));
  }
  __syncthreads();
  int n = t >> 2, kg = (t & 3) * 8;
  uint4 o;
  o.x = (unsigned)f2bf(tile[kg + 0][n]) | ((unsigned)f2bf(tile[kg + 1][n]) << 16);
  o.y = (unsigned)f2bf(tile[kg + 2][n]) | ((unsigned)f2bf(tile[kg + 3][n]) << 16);
  o.z = (unsigned)f2bf(tile[kg + 4][n]) | ((unsigned)f2bf(tile[kg + 5][n]) << 16);
  o.w = (unsigned)f2bf(tile[kg + 6][n]) | ((unsigned)f2bf(tile[kg + 7][n]) << 16);
  *(uint4*)&outT[(size_t)(n0 + n) * M + k0 + kg] = o;
}

// ---- fuse1: img2 = img + bn(raw1 bf16); img2 fp32 (CxN) + leaky(img2) bf16 T --
__global__ __launch_bounds__(256) void k_fuse1(const float* __restrict__ base,
                                               const u16* __restrict__ raw,
                                               const float* __restrict__ sums,
                                               const float* __restrict__ sqs,
                                               const float* __restrict__ g,
                                               const float* __restrict__ b,
                                               float* __restrict__ img2,
                                               u16* __restrict__ outT) {
  __shared__ float tile[32][65];
  int n0 = blockIdx.x * 64, k0 = blockIdx.y * 32;
  int t = threadIdx.x;
#pragma unroll
  for (int i = 0; i < 2; i++) {
    int ci = i * 256 + t;
    int k = ci >> 4, cg = (ci & 15) * 4;
    float s, h; bnss(sums, sqs, g, b, k0 + k, s, h);
    size_t idx = (size_t)(k0 + k) * NP + n0 + cg;
    float4 bv = *(const float4*)&base[idx];
    uint2 rv = *(const uint2*)&raw[idx];
    float r0 = bf2f(rv.x & 0xffffu), r1 = bf2f(rv.x >> 16);
    float r2 = bf2f(rv.y & 0xffffu), r3 = bf2f(rv.y >> 16);
    float4 o;
    o.x = bv.x + fmaf(r0, s, h); o.y = bv.y + fmaf(r1, s, h);
    o.z = bv.z + fmaf(r2, s, h); o.w = bv.w + fmaf(r3, s, h);
    *(float4*)&img2[idx] = o;
    tile[k][cg]     = leaky(o.x);
    tile[k][cg + 1] = leaky(o.y);
    tile[k][cg + 2] = leaky(o.z);
    tile[k][cg + 3] = leaky(o.w);
  }
  __syncthreads();
  int n = t >> 2, kg = (t & 3) * 8;
  uint4 o;
  o.x = (unsigned)f2bf(tile[kg + 0][n]) | ((unsigned)f2bf(tile[kg + 1][n]) << 16);
  o.y = (unsigned)f2bf(tile[kg + 2][n]) | ((unsigned)f2bf(tile[kg + 3][n]) << 16);
  o.z = (unsigned)f2bf(tile[kg + 4][n]) | ((unsigned)f2bf(tile[kg + 5][n]) << 16);
  o.w = (unsigned)f2bf(tile[kg + 6][n]) | ((unsigned)f2bf(tile[kg + 7][n]) << 16);
  *(uint4*)&outT[(size_t)(n0 + n) * CH + k0 + kg] = o;
}

// ---- fuse2: Xn = img2 + bn(raw3 bf16); Xn fp32 (NxC) + Xn bf16 (NxC) ----------
__global__ __launch_bounds__(256) void k_fuse2(const float* __restrict__ base,
                                               const u16* __restrict__ raw,
                                               const float* __restrict__ sums,
                                               const float* __restrict__ sqs,
                                               const float* __restrict__ g,
                                               const float* __restrict__ b,
                                               float* __restrict__ XnT,
                                               u16* __restrict__ outT) {
  __shared__ float tile[32][65];
  int n0 = blockIdx.x * 64, k0 = blockIdx.y * 32;
  int t = threadIdx.x;
#pragma unroll
  for (int i = 0; i < 2; i++) {
    int ci = i * 256 + t;
    int k = ci >> 4, cg = (ci & 15) * 4;
    float s, h; bnss(sums, sqs, g, b, k0 + k, s, h);
    size_t idx = (size_t)(k0 + k) * NP + n0 + cg;
    float4 bv = *(const float4*)&base[idx];
    uint2 rv = *(const uint2*)&raw[idx];
    float r0 = bf2f(rv.x & 0xffffu), r1 = bf2f(rv.x >> 16);
    float r2 = bf2f(rv.y & 0xffffu), r3 = bf2f(rv.y >> 16);
    tile[k][cg]     = bv.x + fmaf(r0, s, h);
    tile[k][cg + 1] = bv.y + fmaf(r1, s, h);
    tile[k][cg + 2] = bv.z + fmaf(r2, s, h);
    tile[k][cg + 3] = bv.w + fmaf(r3, s, h);
  }
  __syncthreads();
  int n = t >> 2, kg = (t & 3) * 8;
  float4 f0 = {tile[kg + 0][n], tile[kg + 1][n], tile[kg + 2][n], tile[kg + 3][n]};
  float4 f1 = {tile[kg + 4][n], tile[kg + 5][n], tile[kg + 6][n], tile[kg + 7][n]};
  *(float4*)&XnT[(size_t)(n0 + n) * CH + k0 + kg] = f0;
  *(float4*)&XnT[(size_t)(n0 + n) * CH + k0 + kg + 4] = f1;
  uint4 o;
  o.x = (unsigned)f2bf(f0.x) | ((unsigned)f2bf(f0.y) << 16);
  o.y = (unsigned)f2bf(f0.z) | ((unsigned)f2bf(f0.w) << 16);
  o.z = (unsigned)f2bf(f1.x) | ((unsigned)f2bf(f1.y) << 16);
  o.w = (unsigned)f2bf(f1.z) | ((unsigned)f2bf(f1.w) << 16);
  *(uint4*)&outT[(size_t)(n0 + n) * CH + k0 + kg] = o;
}

// ---------------- MFMA GEMM (generic, M<=384): Out = A @ Bt^T ------------------
// LDS stride 40 u16: bank = (20r+4q) mod 32 -> 2-way only (free)
__global__ __launch_bounds__(256) void k_mgemm(const u16* __restrict__ A,
                                               const u16* __restrict__ Bt,
                                               float* __restrict__ Outf,
                                               u16* __restrict__ Outb,
                                               const float* __restrict__ bias,
                                               int K, int Mstore, int actout) {
  __shared__ u16 As[128 * 40];
  __shared__ u16 Bs[128 * 40];
  int t = threadIdx.x;
  int lane = t & 63, wave = t >> 6;
  int wm = (wave >> 1) * 64, wn = (wave & 1) * 64;
  int m0 = blockIdx.y * 128, n0 = blockIdx.x * 128;
  int r = lane & 15, q = lane >> 4;
  f32x4 acc[4][4];
#pragma unroll
  for (int a = 0; a < 4; a++)
#pragma unroll
    for (int b = 0; b < 4; b++) acc[a][b] = (f32x4){0.f, 0.f, 0.f, 0.f};

  for (int k0 = 0; k0 < K; k0 += 32) {
#pragma unroll
    for (int i = 0; i < 2; i++) {
      int cc = t + i * 256;
      int mm = cc >> 2, kq = (cc & 3) * 8;
      uint4 av = *(const uint4*)&A[(size_t)(m0 + mm) * K + k0 + kq];
      uint4 bv = *(const uint4*)&Bt[(size_t)(n0 + mm) * K + k0 + kq];
      *(uint4*)&As[mm * 40 + kq] = av;
      *(uint4*)&Bs[mm * 40 + kq] = bv;
    }
    __syncthreads();
    bf16x8 af[4], bfr[4];
#pragma unroll
    for (int mt = 0; mt < 4; mt++)
      af[mt] = *(const bf16x8*)&As[(wm + mt * 16 + r) * 40 + q * 8];
#pragma unroll
    for (int nt = 0; nt < 4; nt++)
      bfr[nt] = *(const bf16x8*)&Bs[(wn + nt * 16 + r) * 40 + q * 8];
#pragma unroll
    for (int mt = 0; mt < 4; mt++)
#pragma unroll
      for (int nt = 0; nt < 4; nt++)
        acc[mt][nt] = __builtin_amdgcn_mfma_f32_16x16x32_bf16(af[mt], bfr[nt], acc[mt][nt], 0, 0, 0);
    __syncthreads();
  }
#pragma unroll
  for (int mt = 0; mt < 4; mt++) {
    int mrow = m0 + wm + mt * 16 + q * 4;
#pragma unroll
    for (int i = 0; i < 4; i++) {
      int m = mrow + i;
      if (m >= Mstore) continue;
      float bs = bias ? bias[m] : 0.f;
#pragma unroll
      for (int nt = 0; nt < 4; nt++) {
        float v = acc[mt][nt][i] + bs;
        if (actout) v = leaky(v);
        size_t oi = (size_t)m * NP + n0 + wn + nt * 16 + r;
        if (Outb) Outb[oi] = f2bf(v); else Outf[oi] = v;
      }
    }
  }
}

// ---------------- MFMA GEMM, M=256 specialized: full-M x 128-N tile ------------
// 512 threads / 8 waves; B fetched ONCE (no m-block split); register prefetch
// of next K-tile overlaps global latency with MFMA; padded LDS (2-way only).
__global__ __launch_bounds__(512) void k_mgemm256(const u16* __restrict__ A,
                                                  const u16* __restrict__ Bt,
                                                  float* __restrict__ Outf,
                                                  u16* __restrict__ Outb,
                                                  const float* __restrict__ bias,
                                                  int K, int actout) {
  __shared__ u16 As[256 * 40];
  __shared__ u16 Bs[128 * 40];
  int t = threadIdx.x;
  int lane = t & 63, wave = t >> 6;
  int wm = (wave >> 1) * 64, wn = (wave & 1) * 64;   // wm 0..192, wn 0/64
  int n0 = blockIdx.x * 128;
  int r = lane & 15, q = lane >> 4;
  int arow0 = t >> 2, kq = (t & 3) * 8;              // A rows t>>2 and t>>2+128
  f32x4 acc[4][4];
#pragma unroll
  for (int a = 0; a < 4; a++)
#pragma unroll
    for (int b = 0; b < 4; b++) acc[a][b] = (f32x4){0.f, 0.f, 0.f, 0.f};

  uint4 pa0, pa1, pb;
  pa0 = *(const uint4*)&A[(size_t)arow0 * K + kq];
  pa1 = *(const uint4*)&A[(size_t)(arow0 + 128) * K + kq];
  pb  = *(const uint4*)&Bt[(size_t)(n0 + arow0) * K + kq];
  int kiters = K >> 5;
  for (int ki = 0; ki < kiters; ki++) {
    *(uint4*)&As[arow0 * 40 + kq] = pa0;
    *(uint4*)&As[(arow0 + 128) * 40 + kq] = pa1;
    *(uint4*)&Bs[arow0 * 40 + kq] = pb;
    __syncthreads();
    if (ki + 1 < kiters) {
      int k0 = (ki + 1) << 5;
      pa0 = *(const uint4*)&A[(size_t)arow0 * K + k0 + kq];
      pa1 = *(const uint4*)&A[(size_t)(arow0 + 128) * K + k0 + kq];
      pb  = *(const uint4*)&Bt[(size_t)(n0 + arow0) * K + k0 + kq];
    }
    bf16x8 af[4], bfr[4];
#pragma unroll
    for (int mt = 0; mt < 4; mt++)
      af[mt] = *(const bf16x8*)&As[(wm + mt * 16 + r) * 40 + q * 8];
#pragma unroll
    for (int nt = 0; nt < 4; nt++)
      bfr[nt] = *(const bf16x8*)&Bs[(wn + nt * 16 + r) * 40 + q * 8];
#pragma unroll
    for (int mt = 0; mt < 4; mt++)
#pragma unroll
      for (int nt = 0; nt < 4; nt++)
        acc[mt][nt] = __builtin_amdgcn_mfma_f32_16x16x32_bf16(af[mt], bfr[nt], acc[mt][nt], 0, 0, 0);
    __syncthreads();
  }
#pragma unroll
  for (int mt = 0; mt < 4; mt++) {
    int mrow = wm + mt * 16 + q * 4;
#pragma unroll
    for (int i = 0; i < 4; i++) {
      int m = mrow + i;
      float bs = bias ? bias[m] : 0.f;
#pragma unroll
      for (int nt = 0; nt < 4; nt++) {
        float v = acc[mt][nt][i] + bs;
        if (actout) v = leaky(v);
        size_t oi = (size_t)m * NP + n0 + wn + nt * 16 + r;
        if (Outb) Outb[oi] = f2bf(v); else Outf[oi] = v;
      }
    }
  }
}

// ---------------- depthwise 17x17 conv via MFMA, padded bf16 input -------------
__global__ __launch_bounds__(256) void k_dwconv17(const u16* __restrict__ pad,
                                                  const u16* __restrict__ Tg,
                                                  u16* __restrict__ outb) {
  int c = blockIdx.y;
  int tile = blockIdx.x;                  // 0..8
  int ty0 = (tile / 3) * 64, tx0 = (tile % 3) * 64;
  __shared__ u16 smIn[80 * 88];
  __shared__ u16 smT[17 * 16 * 40];
  const u16* pc = pad + (size_t)c * PADSZ;
  for (int cc = threadIdx.x; cc < 800; cc += 256) {
    int rr = cc / 10, j = cc - rr * 10;
    uint4 v = *(const uint4*)(pc + (ty0 + rr) * PADW + tx0 + j * 8);
    *(uint4*)(smIn + rr * 88 + j * 8) = v;
  }
  const u16* tc = Tg + (size_t)c * 8704;
  for (int cc = threadIdx.x; cc < 1088; cc += 256) {
    int rr = cc >> 2, j = cc & 3;
    uint4 v = *(const uint4*)(tc + rr * 32 + j * 8);
    *(uint4*)(smT + rr * 40 + j * 8) = v;
  }
  __syncthreads();
  int lane = threadIdx.x & 63, wave = threadIdx.x >> 6;
  int wy = wave * 16;
  int r = lane & 15, q = lane >> 4;
  f32x4 acc[4];
#pragma unroll
  for (int xt = 0; xt < 4; xt++) acc[xt] = (f32x4){0.f, 0.f, 0.f, 0.f};
#pragma unroll
  for (int ky = 0; ky < 17; ky++) {
    bf16x8 bfrag = *(const bf16x8*)&smT[(ky * 16 + r) * 40 + q * 8];
    int rowA = wy + r + ky;
#pragma unroll
    for (int xt = 0; xt < 4; xt++) {
      bf16x8 afrag = *(const bf16x8*)&smIn[rowA * 88 + xt * 16 + q * 8];
      acc[xt] = __builtin_amdgcn_mfma_f32_16x16x32_bf16(afrag, bfrag, acc[xt], 0, 0, 0);
    }
  }
  u16* oc = outb + (size_t)c * NP;
#pragma unroll
  for (int xt = 0; xt < 4; xt++) {
    int x = tx0 + xt * 16 + r;
#pragma unroll
    for (int i = 0; i < 4; i++) {
      int y = ty0 + wy + q * 4 + i;
      oc[y * HW + x] = f2bf(acc[xt][i]);
    }
  }
}

// ---------------- grouped 3x3 conv, row-sliding, no LDS, no barrier ------------
__global__ __launch_bounds__(256) void k_conv3x4(const float* __restrict__ in,
                                                 const float* __restrict__ w,
                                                 u16* __restrict__ out) {
  int wave = threadIdx.x >> 6, lane = threadIdx.x & 63;
  int c = blockIdx.y;
  int y = blockIdx.x * 4 + wave;
  const float* wc = w + (size_t)(4 * c) * 9;
  float wr[36];
#pragma unroll
  for (int k = 0; k < 36; k++) wr[k] = wc[k];
  float acc[4][3];
#pragma unroll
  for (int oc = 0; oc < 4; oc++)
#pragma unroll
    for (int s = 0; s < 3; s++) acc[oc][s] = 0.f;
  const float* base = in + (size_t)c * NP;
#pragma unroll
  for (int ky = 0; ky < 3; ky++) {
    int ry = y + ky - 1;
    if (ry < 0 || ry >= HW) continue;
    const float* rp = base + ry * HW;
    float a0 = leaky(rp[lane]);
    float a1 = leaky(rp[64 + lane]);
    float a2 = leaky(rp[128 + lane]);
    float e0 = __shfl(a0, 63), e1 = __shfl(a1, 63);
    float b1 = __shfl(a1, 0),  b2 = __shfl(a2, 0);
    float l0 = __shfl_up(a0, 1); if (lane == 0) l0 = 0.f;
    float l1 = __shfl_up(a1, 1); if (lane == 0) l1 = e0;
    float l2 = __shfl_up(a2, 1); if (lane == 0) l2 = e1;
    float r0 = __shfl_down(a0, 1); if (lane == 63) r0 = b1;
    float r1 = __shfl_down(a1, 1); if (lane == 63) r1 = b2;
    float r2 = __shfl_down(a2, 1); if (lane == 63) r2 = 0.f;
#pragma unroll
    for (int oc = 0; oc < 4; oc++) {
      float w0 = wr[oc * 9 + ky * 3], w1 = wr[oc * 9 + ky * 3 + 1], w2 = wr[oc * 9 + ky * 3 + 2];
      acc[oc][0] = fmaf(w0, l0, fmaf(w1, a0, fmaf(w2, r0, acc[oc][0])));
      acc[oc][1] = fmaf(w0, l1, fmaf(w1, a1, fmaf(w2, r1, acc[oc][1])));
      acc[oc][2] = fmaf(w0, l2, fmaf(w1, a2, fmaf(w2, r2, acc[oc][2])));
    }
  }
  size_t ob = (size_t)(4 * c) * NP + (size_t)y * HW + lane;
#pragma unroll
  for (int oc = 0; oc < 4; oc++) {
    out[ob + (size_t)oc * NP]       = f2bf(acc[oc][0]);
    out[ob + (size_t)oc * NP + 64]  = f2bf(acc[oc][1]);
    out[ob + (size_t)oc * NP + 128] = f2bf(acc[oc][2]);
  }
}

// ---------------- edge scores + dst histogram ----------------------------------
__global__ __launch_bounds__(256) void k_edge(const int* __restrict__ info,
                                              const float* __restrict__ msk,
                                              const float* __restrict__ sig,
                                              float* __restrict__ aij,
                                              int* __restrict__ counts) {
  int e = blockIdx.x * 256 + threadIdx.x;
  int4 ii = ((const int4*)info)[e];
  float s = sig[(size_t)ii.y * NP + ii.x] + sig[(size_t)ii.w * NP + ii.z];
  s = fminf(fmaxf(s, -5.f), 5.f);
  aij[e] = expf(s) * msk[e];
  atomicAdd(&counts[ii.z], 1);
}

// ---------------- counting-sort by dst -----------------------------------------
__global__ __launch_bounds__(256) void k_scan1(const int* __restrict__ counts,
                                               int* __restrict__ offsets,
                                               int* __restrict__ bsum) {
  __shared__ int sm[256];
  int t = threadIdx.x;
  int i = blockIdx.x * 256 + t;
  int v = counts[i];
  sm[t] = v;
  __syncthreads();
  for (int d = 1; d < 256; d <<= 1) {
    int add = (t >= d) ? sm[t - d] : 0;
    __syncthreads();
    sm[t] += add;
    __syncthreads();
  }
  offsets[i] = sm[t] - v;
  if (t == 255) bsum[blockIdx.x] = sm[255];
}
__global__ __launch_bounds__(256) void k_scan2(const int* __restrict__ bsum,
                                               int* __restrict__ boff) {
  __shared__ int sm[256];
  int t = threadIdx.x;
  int v = (t < 144) ? bsum[t] : 0;
  sm[t] = v;
  __syncthreads();
  for (int d = 1; d < 256; d <<= 1) {
    int add = (t >= d) ? sm[t - d] : 0;
    __syncthreads();
    sm[t] += add;
    __syncthreads();
  }
  boff[t] = sm[t] - v;
}
__global__ __launch_bounds__(256) void k_scan3(int* __restrict__ offsets,
                                               const int* __restrict__ boff,
                                               int* __restrict__ cursor) {
  int i = blockIdx.x * 256 + threadIdx.x;
  int o = offsets[i] + boff[blockIdx.x];
  offsets[i] = o;
  cursor[i] = o;
  if (i == 0) offsets[NP] = EDGES;
}
// scatter (src, aij) pre-sorted by dst
__global__ __launch_bounds__(256) void k_scatter(const int* __restrict__ info,
                                                 const float* __restrict__ aij,
                                                 int* __restrict__ cursor,
                                                 int* __restrict__ srcs,
                                                 float* __restrict__ aijw) {
  int e = blockIdx.x * 256 + threadIdx.x;
  int4 ii = ((const int4*)info)[e];
  int pos = atomicAdd(&cursor[ii.z], 1);
  srcs[pos] = ii.x;
  aijw[pos] = aij[e];
}

// ---------------- per-node aggregation: half-wave per edge stream --------------
__global__ __launch_bounds__(256) void k_agg(const int* __restrict__ offsets,
                                             const int* __restrict__ srcs,
                                             const float* __restrict__ aijw,
                                             const u16* __restrict__ XnBf,
                                             u16* __restrict__ XtrBf) {
  int wave = threadIdx.x >> 6, lane = threadIdx.x & 63;
  int node = blockIdx.x * 4 + wave;
  int o0 = offsets[node], o1 = offsets[node + 1];
  int half = lane >> 5, l32 = lane & 31;
  float acc[8] = {0.f, 0.f, 0.f, 0.f, 0.f, 0.f, 0.f, 0.f};
  float asum = 0.f;
  int i = o0 + half;
  for (; i + 2 < o1; i += 4) {
    int s0 = srcs[i], s1 = srcs[i + 2];
    float a0 = aijw[i], a1 = aijw[i + 2];
    uint4 v0 = ((const uint4*)(XnBf + (size_t)s0 * CH))[l32];
    uint4 v1 = ((const uint4*)(XnBf + (size_t)s1 * CH))[l32];
    unsigned w0[4] = {v0.x, v0.y, v0.z, v0.w};
    unsigned w1[4] = {v1.x, v1.y, v1.z, v1.w};
#pragma unroll
    for (int j = 0; j < 4; j++) {
      acc[2 * j]     = fmaf(a0, bf2f(w0[j] & 0xffffu), acc[2 * j]);
      acc[2 * j + 1] = fmaf(a0, bf2f(w0[j] >> 16),     acc[2 * j + 1]);
      acc[2 * j]     = fmaf(a1, bf2f(w1[j] & 0xffffu), acc[2 * j]);
      acc[2 * j + 1] = fmaf(a1, bf2f(w1[j] >> 16),     acc[2 * j + 1]);
    }
    asum += a0 + a1;
  }
  for (; i < o1; i += 2) {
    int s = srcs[i];
    float a = aijw[i];
    uint4 v = ((const uint4*)(XnBf + (size_t)s * CH))[l32];
    unsigned w[4] = {v.x, v.y, v.z, v.w};
#pragma unroll
    for (int j = 0; j < 4; j++) {
      acc[2 * j]     = fmaf(a, bf2f(w[j] & 0xffffu), acc[2 * j]);
      acc[2 * j + 1] = fmaf(a, bf2f(w[j] >> 16),     acc[2 * j + 1]);
    }
    asum += a;
  }
#pragma unroll
  for (int j = 0; j < 8; j++) acc[j] += __shfl_xor(acc[j], 32, 64);
  asum += __shfl_xor(asum, 32, 64);
  if (half == 0) {
    float inv = 1.f / (asum + 1e-5f);
    uint4 o;
    o.x = (unsigned)f2bf(acc[0] * inv) | ((unsigned)f2bf(acc[1] * inv) << 16);
    o.y = (unsigned)f2bf(acc[2] * inv) | ((unsigned)f2bf(acc[3] * inv) << 16);
    o.z = (unsigned)f2bf(acc[4] * inv) | ((unsigned)f2bf(acc[5] * inv) << 16);
    o.w = (unsigned)f2bf(acc[6] * inv) | ((unsigned)f2bf(acc[7] * inv) << 16);
    ((uint4*)(XtrBf + (size_t)node * CH))[l32] = o;
  }
}

// ---------------- bn1d stats (bf16 input) --------------------------------------
__global__ __launch_bounds__(256) void k_colstats(const u16* __restrict__ Xt,
                                                  float* __restrict__ sums,
                                                  float* __restrict__ sqs) {
  int c = threadIdx.x;
  float s = 0.f, q = 0.f;
  for (int n = blockIdx.x; n < NP; n += gridDim.x) {
    float v = bf2f(Xt[(size_t)n * CH + c]);
    s += v; q += v * v;
  }
  atomicAdd(&sums[c], s);
  atomicAdd(&sqs[c], q);
}

// ---------------- img4 = transpose(Xn + bn1d(Xtr bf16))  (N x C -> C x N) ------
__global__ __launch_bounds__(256) void k_mkimg4(const float* __restrict__ Xn,
                                                const u16* __restrict__ XtrBf,
                                                const float* __restrict__ sums,
                                                const float* __restrict__ sqs,
                                                const float* __restrict__ g,
                                                const float* __restrict__ b,
                                                float* __restrict__ img4) {
  __shared__ float tile[32][33];
  int c0 = blockIdx.x * 32, n0 = blockIdx.y * 32;
  int tx = threadIdx.x & 31, ty = threadIdx.x >> 5;
  int c = c0 + tx;
  float s, h; bnss(sums, sqs, g, b, c, s, h);
#pragma unroll
  for (int j = 0; j < 4; j++) {
    size_t idx = (size_t)(n0 + ty + 8 * j) * CH + c;
    tile[ty + 8 * j][tx] = Xn[idx] + fmaf(bf2f(XtrBf[idx]), s, h);
  }
  __syncthreads();
#pragma unroll
  for (int j = 0; j < 4; j++) {
    int cc = c0 + ty + 8 * j;
    img4[(size_t)cc * NP + n0 + tx] = tile[tx][ty + 8 * j];
  }
}

// ---------------- out(N x C) = transpose(bn(raw5 bf16) + img4) -----------------
__global__ __launch_bounds__(256) void k_final(const u16* __restrict__ raw5,
                                               const float* __restrict__ img4,
                                               const float* __restrict__ sums,
                                               const float* __restrict__ sqs,
                                               const float* __restrict__ g,
                                               const float* __restrict__ b,
                                               float* __restrict__ out) {
  __shared__ float tile[32][33];
  int n0 = blockIdx.x * 32, c0 = blockIdx.y * 32;
  int tx = threadIdx.x & 31, ty = threadIdx.x >> 5;
#pragma unroll
  for (int j = 0; j < 4; j++) {
    int c = c0 + ty + 8 * j;
    float s, h; bnss(sums, sqs, g, b, c, s, h);
    size_t idx = (size_t)c * NP + n0 + tx;
    tile[ty + 8 * j][tx] = fmaf(bf2f(raw5[idx]), s, h) + img4[idx];
  }
  __syncthreads();
#pragma unroll
  for (int j = 0; j < 4; j++) {
    int n = n0 + ty + 8 * j;
    out[(size_t)n * CH + c0 + tx] = tile[tx][ty + 8 * j];
  }
}

extern "C" void kernel_launch(void* const* d_in, const int* in_sizes, int n_in,
                              void* d_out, int out_size, void* d_ws, size_t ws_size,
                              hipStream_t stream) {
  (void)in_sizes; (void)n_in; (void)out_size; (void)ws_size;
  const float* X    = (const float*)d_in[0];
  const int*   info = (const int*)d_in[1];
  const float* msk  = (const float*)d_in[2];
  const float* pw0  = (const float*)d_in[3];
  const float* pg0  = (const float*)d_in[4];
  const float* pb0  = (const float*)d_in[5];
  const float* pw1  = (const float*)d_in[6];
  const float* pg1  = (const float*)d_in[7];
  const float* pb1  = (const float*)d_in[8];
  const float* f1w0 = (const float*)d_in[9];
  const float* f1g0 = (const float*)d_in[10];
  const float* f1b0 = (const float*)d_in[11];
  const float* f1w1 = (const float*)d_in[12];
  const float* f1g1 = (const float*)d_in[13];
  const float* f1b1 = (const float*)d_in[14];
  const float* dw1  = (const float*)d_in[15];
  const float* db1  = (const float*)d_in[16];
  const float* dw2  = (const float*)d_in[17];
  const float* db2  = (const float*)d_in[18];
  const float* bng  = (const float*)d_in[19];
  const float* bnb  = (const float*)d_in[20];
  const float* f2w0 = (const float*)d_in[21];
  const float* f2g0 = (const float*)d_in[22];
  const float* f2b0 = (const float*)d_in[23];
  const float* f2w1 = (const float*)d_in[24];
  const float* f2g1 = (const float*)d_in[25];
  const float* f2b1 = (const float*)d_in[26];
  float* out = (float*)d_out;

  float* ws = (float*)d_ws;
  float* sum0 = ws + 0;    float* sq0 = ws + 256;
  float* sum1 = ws + 512;  float* sq1 = ws + 768;
  float* sum2 = ws + 1024; float* sq2 = ws + 1280;
  float* sum3 = ws + 1536; float* sq3 = ws + 1792;
  float* sum5 = ws + 2048; float* sq5 = ws + 2304;
  float* sumT = ws + 2560; float* sqT = ws + 2816;   // atomic targets, zeroed
  float* sum4 = ws + 3072; float* sq4 = ws + 4096;   // 1024 each
  int* counts  = (int*)(ws + 8192);
  int* offsets = (int*)(ws + 45056);
  int* cursor  = (int*)(ws + 82176);
  int* bsum    = (int*)(ws + 119296);
  int* boff    = (int*)(ws + 119552);
  int* srcs    = (int*)(ws + 131072);      // EDGES
  float* aij   = ws + 425984;              // EDGES (unsorted)
  const size_t S = (size_t)NP * CH;        // 9437184 words
  float* slotD = ws + 720896;
  float* slotB = slotD + S;
  float* slotA = slotB + S;
  float* slotC = slotA + S;
  u16* bfB  = (u16*)(slotC + S);           // NP x 256 bf16
  u16* bfH  = bfB + S;                     // raw0/raw1/raw2/raw3/h-bf16
  float* sigT = (float*)(bfH + S);         // KSIG x NP fp32
  u16* bfW  = (u16*)(sigT + (size_t)KSIG * NP);
  float* aijw = (float*)(bfW + 622592);    // EDGES, sorted by dst
  // early-phase aliases into dead fp32 slots:
  u16* Ppad = (u16*)slotC;                 // 256ch x 208x208 bf16 padded leaky img
  u16* Tg   = (u16*)slotD;                 // 256 x 8704 Toeplitz
  u16* raw4bf  = (u16*)slotB;              // 1024 x NP bf16, spans slotB+slotA
  u16* bfT1024 = bfB;                      // NP x 1024 bf16
  u16* XtrBf   = (u16*)slotD;              // N x C bf16 (img2/Tg dead)
  u16* raw5bf  = (u16*)slotB;              // C x NP bf16 (raw4bf dead after cvtT_bf)

  hipMemsetAsync(ws, 0, 5120 * sizeof(float), stream);
  hipMemsetAsync(counts, 0, NP * sizeof(int), stream);
  hipMemsetAsync(Ppad, 0, (size_t)PADSZ * CH * sizeof(u16), stream);

  dim3 b256(256), b512(512);
  k_cvtW<<<2432, b256, 0, stream>>>(pw1, f1w0, f1w1, dw1, dw2, f2w1, bfW);
  k_mkT<<<CH, b256, 0, stream>>>(pw0, Tg);
  // img = X^T -> slotA ; padded leaky bf16 -> Ppad
  k_transpose_pad<<<dim3(CH / 32, NP / 32), b256, 0, stream>>>(X, slotA, Ppad);
  // ppm depthwise -> raw0 bf16 (bfH)
  k_dwconv17<<<dim3(9, CH), b256, 0, stream>>>(Ppad, Tg, bfH);
  k_stats_bf<<<CH, b256, 0, stream>>>(bfH, sum0, sq0);
  k_cvtT_bf<<<dim3(NP / 64, 8), b256, 0, stream>>>(bfH, bfB, sum0, sq0, pg0, pb0, CH);
  // ppm 1x1 -> raw1 bf16 (bfH; raw0 dead)
  k_mgemm256<<<NP / 128, b512, 0, stream>>>(bfW, bfB, nullptr, bfH, nullptr, CH, 0);
  k_stats_bf<<<CH, b256, 0, stream>>>(bfH, sum1, sq1);
  // img2 = img + bn(raw1) -> slotD (Tg dead) ; bfB = leaky(img2)^T
  k_fuse1<<<dim3(NP / 64, 8), b256, 0, stream>>>(slotA, bfH, sum1, sq1, pg1, pb1, slotD, bfB);
  // ffn1 conv0 -> raw2 bf16 (bfH)
  k_mgemm256<<<NP / 128, b512, 0, stream>>>(bfW + 65536, bfB, nullptr, bfH, nullptr, CH, 0);
  k_stats_bf<<<CH, b256, 0, stream>>>(bfH, sum2, sq2);
  k_cvtT_bf<<<dim3(NP / 64, 8), b256, 0, stream>>>(bfH, bfB, sum2, sq2, f1g0, f1b0, CH);
  // ffn1 conv1 -> raw3 bf16 (bfH)
  k_mgemm256<<<NP / 128, b512, 0, stream>>>(bfW + 131072, bfB, nullptr, bfH, nullptr, CH, 0);
  k_stats_bf<<<CH, b256, 0, stream>>>(bfH, sum3, sq3);
  // Xn = img2 + bn(raw3): fp32 NxC -> slotA ; bf16 NxC -> bfB
  k_fuse2<<<dim3(NP / 64, 8), b256, 0, stream>>>(slotD, bfH, sum3, sq3, f1g1, f1b1, slotA, bfB);
  // dis: h -> slotC fp32 (Ppad dead), bias + leaky
  k_mgemm256<<<NP / 128, b512, 0, stream>>>(bfW + 196608, bfB, slotC, nullptr, db1, CH, 1);
  k_cvtT<<<dim3(NP / 64, 8), b256, 0, stream>>>(slotC, bfH, CH);   // raw3 dead
  k_mgemm<<<dim3(NP / 128, 3), b256, 0, stream>>>(bfW + 262144, bfH, sigT, nullptr, db2, CH, KSIG, 0);
  // edges
  k_edge<<<EDGES / 256, b256, 0, stream>>>(info, msk, sigT, aij, counts);
  k_scan1<<<NP / 256, b256, 0, stream>>>(counts, offsets, bsum);
  k_scan2<<<1, b256, 0, stream>>>(bsum, boff);
  k_scan3<<<NP / 256, b256, 0, stream>>>(offsets, boff, cursor);
  k_scatter<<<EDGES / 256, b256, 0, stream>>>(info, aij, cursor, srcs, aijw);
  // Xtr bf16 -> XtrBf (slotD; img2 dead)
  k_agg<<<NP / 4, b256, 0, stream>>>(offsets, srcs, aijw, bfB, XtrBf);
  k_colstats<<<288, b256, 0, stream>>>(XtrBf, sumT, sqT);
  // img4 -> slotC (h dead)
  k_mkimg4<<<dim3(CH / 32, NP / 32), b256, 0, stream>>>(slotA, XtrBf, sumT, sqT, bng, bnb, slotC);
  // ffn2 grouped 3x3 -> raw4bf (slotB+slotA; Xn fp32 dead)
  k_conv3x4<<<dim3(48, CH), b256, 0, stream>>>(slotC, f2w0, raw4bf);
  k_stats_bf<<<1024, b256, 0, stream>>>(raw4bf, sum4, sq4);
  k_cvtT_bf<<<dim3(NP / 64, 32), b256, 0, stream>>>(raw4bf, bfT1024, sum4, sq4, f2g0, f2b0, 1024);
  // ffn2 1x1 -> raw5 bf16 (slotB; raw4bf consumed)
  k_mgemm256<<<NP / 128, b512, 0, stream>>>(bfW + 360448, bfT1024, nullptr, raw5bf, nullptr, 1024, 0);
  k_stats_bf<<<CH, b256, 0, stream>>>(raw5bf, sum5, sq5);
  k_final<<<dim3(NP / 32, CH / 32), b256, 0, stream>>>(raw5bf, slotC, sum5, sq5, f2g1, f2b1, out);
}